// Round 2
// baseline (730.987 us; speedup 1.0000x reference)
//
#include <hip/hip_runtime.h>
#include <hip/hip_bf16.h>
#include <math.h>

typedef __hip_bfloat16 bf16;

#define NNODES 20000
#define NEDGES 320000
#define DLEN   16
#define G      64
#define DW     300
#define DH     256
#define HD     128
#define G3     384
#define NCLS   2000
#define NB     4
#define TT     32

__device__ __forceinline__ float ld(const float* p, size_t i) { return p[i]; }
__device__ __forceinline__ float ld(const bf16* p, size_t i) { return __bfloat162float(p[i]); }
__device__ __forceinline__ void st(float* p, size_t i, float v) { p[i] = v; }
__device__ __forceinline__ void st(bf16* p, size_t i, float v) { p[i] = __float2bfloat16(v); }
// NaN-propagating relu: (NaN<0) is false -> NaN kept -> visible in output for diagnosis
__device__ __forceinline__ float relu(float x) { return (x < 0.f) ? 0.f : x; }

// ---------------- workspace layout (float words) ----------------
#define OFF_FLAG  ((size_t)0)                         // 4
#define OFF_GX    (OFF_FLAG + 4)                      // 2*4*32*384 = 98304
#define OFF_WHF   (OFF_GX   + 2*NB*TT*G3)             // Wh fp32: 2*128*384 = 98304
#define OFF_QEMB  (OFF_WHF  + 2*HD*G3)                // 1024
#define OFF_QG    (OFF_QEMB + NB*DH)                  // 256
#define OFF_NF    (OFF_QG   + NB*G)                   // 5,120,000
#define OFF_HB    (OFF_NF   + (size_t)NB*NNODES*G)    // 5,120,000
#define OFF_L2    (OFF_HB   + (size_t)NB*NNODES*G)    // 80,000
#define OFF_DEG   (OFF_L2   + (size_t)NB*NNODES)      // int 20000
#define OFF_OFFS  (OFF_DEG  + NNODES)                 // int 20008
#define OFF_CUR   (OFF_OFFS + NNODES + 8)             // int 20000
#define OFF_SSRC  (OFF_CUR  + NNODES)                 // int 320000
#define OFF_SCO   (OFF_SSRC + NEDGES)                 // float 320000
#define OFF_GMX   (OFF_SCO  + NEDGES)                 // uint 4
#define OFF_Z     (OFF_GMX  + 4)                      // 4
#define OFF_NAR   (OFF_Z    + 4)                      // 256
#define OFF_HID   (OFF_NAR  + NB*G)                   // 4096

// ---------------- init: dtype sniff + zero accumulators ----------------
__global__ void k_init(const unsigned* probe, int* flag, int* deg, unsigned* gmx,
                       float* Z, float* nar) {
    int i = blockIdx.x * 256 + threadIdx.x;
    if (i < NNODES) deg[i] = 0;
    if (i < 4) { gmx[i] = 0u; Z[i] = 0.f; }
    if (i < NB * G) nar[i] = 0.f;
    if (blockIdx.x == 0 && threadIdx.x < 64) {
        // Sniff: if data is bf16, the LOW 16-bit half of each 32-bit word is a
        // plausible bf16 value (exp field in range); if fp32, it's mantissa noise.
        int cnt = 0;
        for (int k = threadIdx.x; k < 4096; k += 64) {
            unsigned lo = probe[k] & 0xFFFFu;
            unsigned e = (lo >> 7) & 0xFFu;
            cnt += (e >= 0x66u && e <= 0x7Eu) ? 1 : 0;
        }
#pragma unroll
        for (int off = 1; off < 64; off <<= 1) cnt += __shfl_xor(cnt, off, 64);
        if (threadIdx.x == 0) *flag = (2 * cnt > 4096) ? 1 : 0;   // 1 = bf16
    }
}

// ---------------- convert Wh to fp32 in ws ----------------
template <typename T>
__device__ void cvt_body(const void* Whf_, const void* Whb_, float* whf) {
    int id = blockIdx.x * 256 + threadIdx.x;   // 2*128*384 = 98304
    if (id >= 2 * HD * G3) return;
    int d = id / (HD * G3), r = id % (HD * G3);
    const T* W = (const T*)(d ? Whb_ : Whf_);
    whf[id] = ld(W, (size_t)r);
}
__global__ void k_cvt(const int* flag, const void* Whf, const void* Whb, float* whf) {
    if (*flag) cvt_body<bf16>(Whf, Whb, whf);
    else       cvt_body<float>(Whf, Whb, whf);
}

// ---------------- gx = x @ Wx + bx, stored in scan order per direction ------
template <typename T>
__device__ void gx_body(const int* questions, const void* emb_word_,
                        const void* Wxf_, const void* bxf_,
                        const void* Wxb_, const void* bxb_, float* gx) {
    int id = blockIdx.x * 256 + threadIdx.x;   // 2*4*32*384 = 98304
    int j = id % G3;
    int step = (id / G3) % TT;
    int b = (id / (G3 * TT)) % NB;
    int d = id / (G3 * TT * NB);
    int t = d ? (TT - 1 - step) : step;
    int tok = questions[b * TT + t];
    const T* Wx = (const T*)(d ? Wxb_ : Wxf_);
    const T* bx = (const T*)(d ? bxb_ : bxf_);
    const T* row = (const T*)emb_word_ + (size_t)tok * DW;
    float acc = ld(bx, (size_t)j);
#pragma unroll 4
    for (int k = 0; k < DW; k++) acc += ld(row, (size_t)k) * ld(Wx, (size_t)k * G3 + j);
    gx[id] = acc;
}
__global__ void k_gx(const int* flag, const int* questions, const void* emb_word,
                     const void* Wxf, const void* bxf,
                     const void* Wxb, const void* bxb, float* gx) {
    if (*flag) gx_body<bf16>(questions, emb_word, Wxf, bxf, Wxb, bxb, gx);
    else       gx_body<float>(questions, emb_word, Wxf, bxf, Wxb, bxb, gx);
}

// ---------------- GRU scan: one block per (direction, batch) ----------------
template <typename T>
__device__ void gru_body(const int* questions, const float* gx, const float* whf,
                         const void* bhf_, const void* bhb_, float* qemb,
                         float* hsm, float* ghs) {
    int tid = threadIdx.x;
    int d = blockIdx.x >> 2, b = blockIdx.x & 3;
    const float* wh = whf + (size_t)d * HD * G3;
    const T* bh = (const T*)(d ? bhb_ : bhf_);
    if (tid < HD) hsm[tid] = 0.f;
    float bhj = ld(bh, (size_t)tid);
    const float* gxb = gx + ((size_t)(d * NB + b)) * TT * G3;
    __syncthreads();
    for (int step = 0; step < TT; step++) {
        float acc = bhj;
#pragma unroll 8
        for (int k = 0; k < HD; k++) acc = fmaf(hsm[k], wh[(size_t)k * G3 + tid], acc);
        ghs[tid] = acc;
        __syncthreads();
        if (tid < HD) {
            const float* gxp = gxb + step * G3;
            int t = d ? (TT - 1 - step) : step;
            bool msk = questions[b * TT + t] != 0;
            float r = 1.f / (1.f + expf(-(gxp[tid] + ghs[tid])));
            float z = 1.f / (1.f + expf(-(gxp[HD + tid] + ghs[HD + tid])));
            float n = tanhf(gxp[2 * HD + tid] + r * ghs[2 * HD + tid]);
            float hn = (1.f - z) * n + z * hsm[tid];
            if (msk) hsm[tid] = hn;
        }
        __syncthreads();
    }
    if (tid < HD) qemb[b * DH + d * HD + tid] = hsm[tid];
}
__global__ __launch_bounds__(G3) void k_gru(const int* flag, const int* questions,
                                            const float* gx, const float* whf,
                                            const void* bhf, const void* bhb, float* qemb) {
    __shared__ float hsm[HD];
    __shared__ float ghs[G3];
    if (*flag) gru_body<bf16>(questions, gx, whf, bhf, bhb, qemb, hsm, ghs);
    else       gru_body<float>(questions, gx, whf, bhf, bhb, qemb, hsm, ghs);
}

// ---------------- q_g = q_emb @ W_hg + b_hg ----------------
template <typename T>
__device__ void qg_body(const float* qemb, const void* W_hg_, const void* b_hg_, float* qg) {
    int tid = threadIdx.x;   // 256
    int b = tid >> 6, g = tid & 63;
    const T* W = (const T*)W_hg_;
    float acc = ld((const T*)b_hg_, (size_t)g);
#pragma unroll 4
    for (int i = 0; i < DH; i++) acc += qemb[b * DH + i] * ld(W, (size_t)i * G + g);
    qg[b * G + g] = acc;
}
__global__ void k_qg(const int* flag, const float* qemb, const void* W_hg,
                     const void* b_hg, float* qg) {
    if (*flag) qg_body<bf16>(qemb, W_hg, b_hg, qg);
    else       qg_body<float>(qemb, W_hg, b_hg, qg);
}

// ---------------- attn1 softmax + node features: one wave per node ----------
template <typename T>
__device__ void attn1_body(const int* node_descs, const void* emb_desc_,
                           const float* qg, float* nf,
                           float* dsm, float* attn_s, float* qgs) {
    int tid = threadIdx.x;
    if (tid < NB * G) qgs[tid] = qg[tid];
    __syncthreads();
    const T* emb_desc = (const T*)emb_desc_;
    int w = tid >> 6, lane = tid & 63;
    int n = blockIdx.x * 4 + w;
    float dreg[DLEN];
    const int* nd = node_descs + n * DLEN;
    float* dw = dsm + (size_t)w * DLEN * (G + 1);
#pragma unroll
    for (int l = 0; l < DLEN; l++) {
        int idx = nd[l];
        float v = ld(emb_desc, (size_t)idx * G + lane);
        dreg[l] = v;
        dw[l * (G + 1) + lane] = v;
    }
    // lane -> (b = lane>>4, l = lane&15)
    int lb = lane >> 4, ll = lane & 15;
    float acc = 0.f;
#pragma unroll 8
    for (int g = 0; g < G; g++) acc += dw[ll * (G + 1) + g] * qgs[lb * G + g];
    float mx = acc;
#pragma unroll
    for (int off = 1; off < 16; off <<= 1) mx = fmaxf(mx, __shfl_xor(mx, off, 64));
    float e = expf(acc - mx);
    float s = e;
#pragma unroll
    for (int off = 1; off < 16; off <<= 1) s += __shfl_xor(s, off, 64);
    attn_s[w * 64 + lane] = e / s;
#pragma unroll
    for (int b = 0; b < NB; b++) {
        float a = 0.f;
#pragma unroll
        for (int l = 0; l < DLEN; l++) a += attn_s[w * 64 + b * 16 + l] * dreg[l];
        nf[((size_t)b * NNODES + n) * G + lane] = a;
    }
}
__global__ __launch_bounds__(256) void k_attn1(const int* flag, const int* node_descs,
                                               const void* emb_desc, const float* qg, float* nf) {
    __shared__ float dsm[4 * DLEN * (G + 1)];
    __shared__ float attn_s[4 * 64];
    __shared__ float qgs[NB * G];
    if (*flag) attn1_body<bf16>(node_descs, emb_desc, qg, nf, dsm, attn_s, qgs);
    else       attn1_body<float>(node_descs, emb_desc, qg, nf, dsm, attn_s, qgs);
}

// ---------------- hb = nf @ bases[0] : one wave per (b,n) ----------------
template <typename T>
__device__ void hb_body(const float* nf, const void* bases_, float* hb, float* bsm) {
    int tid = threadIdx.x;
    const T* bases = (const T*)bases_;
    for (int i = tid; i < G * G; i += 256) bsm[(i >> 6) * (G + 1) + (i & 63)] = ld(bases, (size_t)i);
    __syncthreads();
    int w = tid >> 6, lane = tid & 63;
    int n = blockIdx.x, b = w;
    float v = nf[((size_t)b * NNODES + n) * G + lane];
    float acc = 0.f;
#pragma unroll 8
    for (int g = 0; g < G; g++) acc += __shfl(v, g, 64) * bsm[g * (G + 1) + lane];
    hb[((size_t)b * NNODES + n) * G + lane] = acc;
}
__global__ __launch_bounds__(256) void k_hb(const int* flag, const float* nf,
                                            const void* bases, float* hb) {
    __shared__ float bsm[G * (G + 1)];
    if (*flag) hb_body<bf16>(nf, bases, hb, bsm);
    else       hb_body<float>(nf, bases, hb, bsm);
}

// ---------------- CSR build: histogram, scan, scatter ----------------
__global__ void k_hist(const int* dst, int* deg) {
    int e = blockIdx.x * 256 + threadIdx.x;
    if (e < NEDGES) atomicAdd(&deg[dst[e]], 1);
}

__global__ __launch_bounds__(1024) void k_scan(const int* deg, int* offs, int* cur) {
    __shared__ int tot[1024];
    int t = threadIdx.x;
    int c[20];
    int base = t * 20;
    int run = 0;
#pragma unroll
    for (int i = 0; i < 20; i++) {
        int v = (base + i < NNODES) ? deg[base + i] : 0;
        c[i] = run;
        run += v;
    }
    tot[t] = run;
    __syncthreads();
    for (int off = 1; off < 1024; off <<= 1) {
        int v = (t >= off) ? tot[t - off] : 0;
        __syncthreads();
        tot[t] += v;
        __syncthreads();
    }
    int ebase = tot[t] - run;
#pragma unroll
    for (int i = 0; i < 20; i++) {
        if (base + i < NNODES) {
            offs[base + i] = ebase + c[i];
            cur[base + i] = ebase + c[i];
        }
    }
    if (t == 1023) offs[NNODES] = tot[1023];
}

template <typename T>
__device__ void scatter_body(const int* src, const int* dst, const int* typ,
                             const void* w_comp_, int* cur, int* ssrc, float* sco) {
    int e = blockIdx.x * 256 + threadIdx.x;
    if (e < NEDGES) {
        int dd = dst[e];
        int pos = atomicAdd(&cur[dd], 1);
        ssrc[pos] = src[e];
        sco[pos] = ld((const T*)w_comp_, (size_t)typ[e]);
    }
}
__global__ void k_scatter(const int* flag, const int* src, const int* dst, const int* typ,
                          const void* w_comp, int* cur, int* ssrc, float* sco) {
    if (*flag) scatter_body<bf16>(src, dst, typ, w_comp, cur, ssrc, sco);
    else       scatter_body<float>(src, dst, typ, w_comp, cur, ssrc, sco);
}

// ---------------- RGCN aggregate (gather over CSR) + bias + relu -----------
template <typename T>
__device__ void agg_body(const float* hb, const int* offs, const int* ssrc,
                         const float* sco, const void* bias_, float* out_nf) {
    int tid = threadIdx.x;
    int b = tid >> 6, g = tid & 63;
    int dn = blockIdx.x;
    int s0 = offs[dn], s1 = offs[dn + 1];
    const float* hbb = hb + (size_t)b * NNODES * G;
    float acc = 0.f;
    for (int p = s0; p < s1; p++) {
        int src = ssrc[p];
        acc += sco[p] * hbb[(size_t)src * G + g];
    }
    out_nf[((size_t)b * NNODES + dn) * G + g] = relu(acc + ld((const T*)bias_, (size_t)g));
}
__global__ __launch_bounds__(256) void k_agg(const int* flag, const float* hb, const int* offs,
                                             const int* ssrc, const float* sco,
                                             const void* bias, float* out_nf) {
    if (*flag) agg_body<bf16>(hb, offs, ssrc, sco, bias, out_nf);
    else       agg_body<float>(hb, offs, ssrc, sco, bias, out_nf);
}

// ---------------- attn2: logits + max ----------------
__global__ __launch_bounds__(256) void k_attn2a(const float* rg, const float* qg,
                                                float* l2, unsigned* gmx) {
    int tid = threadIdx.x;
    int b = tid >> 6, lane = tid & 63;
    float q = qg[b * G + lane];
    float lmax = -3.4e38f;
    for (int n = blockIdx.x; n < NNODES; n += gridDim.x) {
        float p = rg[((size_t)b * NNODES + n) * G + lane] * q;
#pragma unroll
        for (int off = 32; off >= 1; off >>= 1) p += __shfl_xor(p, off, 64);
        if (lane == 0) l2[b * NNODES + n] = p;
        lmax = fmaxf(lmax, p);
    }
    if (lane == 0) {
        unsigned u = __float_as_uint(lmax);
        unsigned key = (u >> 31) ? ~u : (u | 0x80000000u);
        atomicMax(&gmx[b], key);
    }
}

// ---------------- attn2: exp-sum + unnormalized weighted pooling ------------
__global__ __launch_bounds__(256) void k_attn2b(const float* rg, const float* l2,
                                                const unsigned* gmx, float* Z, float* nar) {
    int tid = threadIdx.x;
    int b = tid >> 6, lane = tid & 63;
    unsigned k = gmx[b];
    float mx = (k & 0x80000000u) ? __uint_as_float(k & 0x7fffffffu) : __uint_as_float(~k);
    float fsum = 0.f, facc = 0.f;
    for (int n = blockIdx.x; n < NNODES; n += gridDim.x) {
        float e = expf(l2[b * NNODES + n] - mx);
        fsum += e;
        facc += e * rg[((size_t)b * NNODES + n) * G + lane];
    }
    atomicAdd(&nar[b * G + lane], facc);
    if (lane == 0) atomicAdd(&Z[b], fsum);
}

// ---------------- classifier ----------------
template <typename T>
__device__ void fc1_body(const float* nar, const float* Z, const float* qemb,
                         const void* W1_, const void* b1_, float* hid) {
    int id = blockIdx.x * 256 + threadIdx.x;   // 4096
    int b = id >> 10, u = id & 1023;
    const T* W1 = (const T*)W1_;
    float acc = ld((const T*)b1_, (size_t)u);
    float invZ = 1.f / Z[b];
#pragma unroll 4
    for (int g = 0; g < G; g++) acc += nar[b * G + g] * invZ * ld(W1, (size_t)g * 1024 + u);
#pragma unroll 4
    for (int i = 0; i < DH; i++) acc += qemb[b * DH + i] * ld(W1, (size_t)(G + i) * 1024 + u);
    hid[id] = relu(acc);
}
__global__ void k_fc1(const int* flag, const float* nar, const float* Z, const float* qemb,
                      const void* W1, const void* b1, float* hid) {
    if (*flag) fc1_body<bf16>(nar, Z, qemb, W1, b1, hid);
    else       fc1_body<float>(nar, Z, qemb, W1, b1, hid);
}

template <typename T>
__device__ void fc2_body(const float* hid, const void* W2_, const void* b2_, void* out_) {
    int id = blockIdx.x * 256 + threadIdx.x;
    if (id >= NB * NCLS) return;
    int b = id / NCLS, c = id % NCLS;
    const T* W2 = (const T*)W2_;
    float acc = ld((const T*)b2_, (size_t)c);
    const float* h = hid + b * 1024;
#pragma unroll 4
    for (int u = 0; u < 1024; u++) acc += h[u] * ld(W2, (size_t)u * NCLS + c);
    st((T*)out_, (size_t)id, acc);
}
__global__ void k_fc2(const int* flag, const float* hid, const void* W2, const void* b2v,
                      void* out) {
    if (*flag) fc2_body<bf16>(hid, W2, b2v, out);
    else       fc2_body<float>(hid, W2, b2v, out);
}

extern "C" void kernel_launch(void* const* d_in, const int* in_sizes, int n_in,
                              void* d_out, int out_size, void* d_ws, size_t ws_size,
                              hipStream_t stream) {
    const int* questions  = (const int*)d_in[0];
    const int* node_descs = (const int*)d_in[1];
    const int* edge_src   = (const int*)d_in[2];
    const int* edge_dst   = (const int*)d_in[3];
    const int* edge_type  = (const int*)d_in[4];
    const void* emb_word  = d_in[5];
    const void* emb_desc  = d_in[6];
    const void* Wx_f = d_in[7];
    const void* Wh_f = d_in[8];
    const void* bx_f = d_in[9];
    const void* bh_f = d_in[10];
    const void* Wx_b = d_in[11];
    const void* Wh_b = d_in[12];
    const void* bx_b = d_in[13];
    const void* bh_b = d_in[14];
    const void* W_hg = d_in[15];
    const void* b_hg = d_in[16];
    const void* bases = d_in[17];
    const void* w_comp = d_in[18];
    const void* rgcn_bias = d_in[19];
    const void* W1 = d_in[20];
    const void* b1 = d_in[21];
    const void* W2 = d_in[22];
    const void* b2 = d_in[23];

    float* ws = (float*)d_ws;
    int*      flag = (int*)(ws + OFF_FLAG);
    float*    gx   = ws + OFF_GX;
    float*    whf  = ws + OFF_WHF;
    float*    qemb = ws + OFF_QEMB;
    float*    qg   = ws + OFF_QG;
    float*    nf   = ws + OFF_NF;
    float*    hb   = ws + OFF_HB;
    float*    l2   = ws + OFF_L2;
    int*      deg  = (int*)(ws + OFF_DEG);
    int*      offs = (int*)(ws + OFF_OFFS);
    int*      cur  = (int*)(ws + OFF_CUR);
    int*      ssrc = (int*)(ws + OFF_SSRC);
    float*    sco  = ws + OFF_SCO;
    unsigned* gmx  = (unsigned*)(ws + OFF_GMX);
    float*    Z    = ws + OFF_Z;
    float*    nar  = ws + OFF_NAR;
    float*    hid  = ws + OFF_HID;

    hipLaunchKernelGGL(k_init, dim3(80), dim3(256), 0, stream,
                       (const unsigned*)emb_word, flag, deg, gmx, Z, nar);
    hipLaunchKernelGGL(k_hist, dim3((NEDGES + 255) / 256), dim3(256), 0, stream, edge_dst, deg);
    hipLaunchKernelGGL(k_cvt, dim3((2 * HD * G3 + 255) / 256), dim3(256), 0, stream,
                       flag, Wh_f, Wh_b, whf);
    hipLaunchKernelGGL(k_gx, dim3(2 * NB * TT * G3 / 256), dim3(256), 0, stream,
                       flag, questions, emb_word, Wx_f, bx_f, Wx_b, bx_b, gx);
    hipLaunchKernelGGL(k_gru, dim3(8), dim3(G3), 0, stream,
                       flag, questions, gx, whf, bh_f, bh_b, qemb);
    hipLaunchKernelGGL(k_scan, dim3(1), dim3(1024), 0, stream, deg, offs, cur);
    hipLaunchKernelGGL(k_scatter, dim3((NEDGES + 255) / 256), dim3(256), 0, stream,
                       flag, edge_src, edge_dst, edge_type, w_comp, cur, ssrc, sco);
    hipLaunchKernelGGL(k_qg, dim3(1), dim3(256), 0, stream, flag, qemb, W_hg, b_hg, qg);
    hipLaunchKernelGGL(k_attn1, dim3(NNODES / 4), dim3(256), 0, stream,
                       flag, node_descs, emb_desc, qg, nf);
    hipLaunchKernelGGL(k_hb, dim3(NNODES), dim3(256), 0, stream, flag, nf, bases, hb);
    hipLaunchKernelGGL(k_agg, dim3(NNODES), dim3(256), 0, stream,
                       flag, hb, offs, ssrc, sco, rgcn_bias, nf);
    hipLaunchKernelGGL(k_attn2a, dim3(256), dim3(256), 0, stream, nf, qg, l2, gmx);
    hipLaunchKernelGGL(k_attn2b, dim3(256), dim3(256), 0, stream, nf, l2, gmx, Z, nar);
    hipLaunchKernelGGL(k_fc1, dim3(16), dim3(256), 0, stream, flag, nar, Z, qemb, W1, b1, hid);
    hipLaunchKernelGGL(k_fc2, dim3((NB * NCLS + 255) / 256), dim3(256), 0, stream,
                       flag, hid, W2, b2, d_out);
}

// Round 4
// 561.342 us; speedup vs baseline: 1.3022x; 1.3022x over previous
//
#include <hip/hip_runtime.h>
#include <hip/hip_bf16.h>
#include <math.h>

typedef __hip_bfloat16 bf16;

#define NNODES 20000
#define NEDGES 320000
#define DLEN   16
#define G      64
#define DW     300
#define DH     256
#define HD     128
#define G3     384
#define NCLS   2000
#define NB     4
#define TT     32

__device__ __forceinline__ float ld(const float* p, size_t i) { return p[i]; }
__device__ __forceinline__ float ld(const bf16* p, size_t i) { return __bfloat162float(p[i]); }
__device__ __forceinline__ void st(float* p, size_t i, float v) { p[i] = v; }
__device__ __forceinline__ void st(bf16* p, size_t i, float v) { p[i] = __float2bfloat16(v); }
__device__ __forceinline__ float relu(float x) { return (x < 0.f) ? 0.f : x; }

// ---------------- workspace layout (float words) ----------------
#define OFF_FLAG  ((size_t)0)                         // 4
#define OFF_GX    (OFF_FLAG + 4)                      // 2*4*32*384 = 98304
#define OFF_WHF   (OFF_GX   + 2*NB*TT*G3)             // Wh fp32: 2*128*384 = 98304
#define OFF_QEMB  (OFF_WHF  + 2*HD*G3)                // 1024
#define OFF_QG    (OFF_QEMB + NB*DH)                  // 256
#define OFF_NF    (OFF_QG   + NB*G)                   // 5,120,000
#define OFF_HB    (OFF_NF   + (size_t)NB*NNODES*G)    // 5,120,000
#define OFF_L2    (OFF_HB   + (size_t)NB*NNODES*G)    // 80,000
#define OFF_DEG   (OFF_L2   + (size_t)NB*NNODES)      // int 20000
#define OFF_OFFS  (OFF_DEG  + NNODES)                 // int 20008
#define OFF_CUR   (OFF_OFFS + NNODES + 8)             // int 20000
#define OFF_SSRC  (OFF_CUR  + NNODES)                 // int 320000
#define OFF_SCO   (OFF_SSRC + NEDGES)                 // float 320000
#define OFF_GMX   (OFF_SCO  + NEDGES)                 // uint 4
#define OFF_Z     (OFF_GMX  + 4)                      // 4
#define OFF_NAR   (OFF_Z    + 4)                      // 256
#define OFF_HID   (OFF_NAR  + NB*G)                   // 4096

// ---------------- init: dtype sniff + zero accumulators ----------------
__global__ void k_init(const unsigned* probe, int* flag, int* deg, unsigned* gmx,
                       float* Z, float* nar) {
    int i = blockIdx.x * 256 + threadIdx.x;
    if (i < NNODES) deg[i] = 0;
    if (i < 4) { gmx[i] = 0u; Z[i] = 0.f; }
    if (i < NB * G) nar[i] = 0.f;
    if (blockIdx.x == 0 && threadIdx.x < 64) {
        int cnt = 0;
        for (int k = threadIdx.x; k < 4096; k += 64) {
            unsigned lo = probe[k] & 0xFFFFu;
            unsigned e = (lo >> 7) & 0xFFu;
            cnt += (e >= 0x66u && e <= 0x7Eu) ? 1 : 0;
        }
#pragma unroll
        for (int off = 1; off < 64; off <<= 1) cnt += __shfl_xor(cnt, off, 64);
        if (threadIdx.x == 0) *flag = (2 * cnt > 4096) ? 1 : 0;   // 1 = bf16
    }
}

// ---------------- convert Wh to fp32 in ws ----------------
template <typename T>
__device__ void cvt_body(const void* Whf_, const void* Whb_, float* whf) {
    int id = blockIdx.x * 256 + threadIdx.x;   // 2*128*384 = 98304
    if (id >= 2 * HD * G3) return;
    int d = id / (HD * G3), r = id % (HD * G3);
    const T* W = (const T*)(d ? Whb_ : Whf_);
    whf[id] = ld(W, (size_t)r);
}
__global__ void k_cvt(const int* flag, const void* Whf, const void* Whb, float* whf) {
    if (*flag) cvt_body<bf16>(Whf, Whb, whf);
    else       cvt_body<float>(Whf, Whb, whf);
}

// ---------------- gx = x @ Wx + bx, stored in scan order per direction ------
template <typename T>
__device__ void gx_body(const int* questions, const void* emb_word_,
                        const void* Wxf_, const void* bxf_,
                        const void* Wxb_, const void* bxb_, float* gx) {
    int id = blockIdx.x * 256 + threadIdx.x;   // 2*4*32*384 = 98304
    int j = id % G3;
    int step = (id / G3) % TT;
    int b = (id / (G3 * TT)) % NB;
    int d = id / (G3 * TT * NB);
    int t = d ? (TT - 1 - step) : step;
    int tok = questions[b * TT + t];
    const T* Wx = (const T*)(d ? Wxb_ : Wxf_);
    const T* bx = (const T*)(d ? bxb_ : bxf_);
    const T* row = (const T*)emb_word_ + (size_t)tok * DW;
    float acc = ld(bx, (size_t)j);
#pragma unroll 4
    for (int k = 0; k < DW; k++) acc += ld(row, (size_t)k) * ld(Wx, (size_t)k * G3 + j);
    gx[id] = acc;
}
__global__ void k_gx(const int* flag, const int* questions, const void* emb_word,
                     const void* Wxf, const void* bxf,
                     const void* Wxb, const void* bxb, float* gx) {
    if (*flag) gx_body<bf16>(questions, emb_word, Wxf, bxf, Wxb, bxb, gx);
    else       gx_body<float>(questions, emb_word, Wxf, bxf, Wxb, bxb, gx);
}

// ---------------- GRU scan: block per (d,b), Wh register-resident ----------
// 768 threads: tid = half*384 + j. Thread holds wh[half*64+m][j], m=0..63 in
// 64 VGPRs (fully unrolled, const-indexed). h broadcast from LDS (float4).
template <typename T>
__device__ void gru_body(const int* questions, const float* gx, const float* whf,
                         const void* bhf_, const void* bhb_, float* qemb,
                         float* hsm, float* ghs) {
    int tid = threadIdx.x;
    int d = blockIdx.x >> 2, b = blockIdx.x & 3;
    int half = tid / G3, j = tid - half * G3;
    const float* wh = whf + (size_t)d * HD * G3 + (size_t)half * 64 * G3 + j;
    float w[64];
#pragma unroll
    for (int m = 0; m < 64; m++) w[m] = wh[(size_t)m * G3];
    const T* bh = (const T*)(d ? bhb_ : bhf_);
    float bhj = (half == 0) ? ld(bh, (size_t)j) : 0.f;
    if (tid < HD) hsm[tid] = 0.f;
    const float* gxb = gx + ((size_t)(d * NB + b)) * TT * G3;
    __syncthreads();
    const float4* h4 = (const float4*)(hsm + half * 64);
    for (int step = 0; step < TT; step++) {
        float acc = bhj;
#pragma unroll
        for (int m4 = 0; m4 < 16; m4++) {
            float4 hp = h4[m4];
            acc = fmaf(hp.x, w[4 * m4 + 0], acc);
            acc = fmaf(hp.y, w[4 * m4 + 1], acc);
            acc = fmaf(hp.z, w[4 * m4 + 2], acc);
            acc = fmaf(hp.w, w[4 * m4 + 3], acc);
        }
        ghs[half * G3 + j] = acc;
        __syncthreads();
        if (tid < HD) {
            const float* gxp = gxb + step * G3;
            int t = d ? (TT - 1 - step) : step;
            bool msk = questions[b * TT + t] != 0;
            float gr = ghs[tid] + ghs[G3 + tid];
            float gz = ghs[HD + tid] + ghs[G3 + HD + tid];
            float gn = ghs[2 * HD + tid] + ghs[G3 + 2 * HD + tid];
            float r = 1.f / (1.f + expf(-(gxp[tid] + gr)));
            float z = 1.f / (1.f + expf(-(gxp[HD + tid] + gz)));
            float n = tanhf(gxp[2 * HD + tid] + r * gn);
            float hn = (1.f - z) * n + z * hsm[tid];
            if (msk) hsm[tid] = hn;
        }
        __syncthreads();
    }
    if (tid < HD) qemb[b * DH + d * HD + tid] = hsm[tid];
}
__global__ __launch_bounds__(2 * G3) void k_gru(const int* flag, const int* questions,
                                                const float* gx, const float* whf,
                                                const void* bhf, const void* bhb, float* qemb) {
    __shared__ __align__(16) float hsm[HD];
    __shared__ float ghs[2 * G3];
    if (*flag) gru_body<bf16>(questions, gx, whf, bhf, bhb, qemb, hsm, ghs);
    else       gru_body<float>(questions, gx, whf, bhf, bhb, qemb, hsm, ghs);
}

// ---------------- q_g = q_emb @ W_hg + b_hg ----------------
template <typename T>
__device__ void qg_body(const float* qemb, const void* W_hg_, const void* b_hg_, float* qg) {
    int tid = threadIdx.x;   // 256
    int b = tid >> 6, g = tid & 63;
    const T* W = (const T*)W_hg_;
    float acc = ld((const T*)b_hg_, (size_t)g);
#pragma unroll 4
    for (int i = 0; i < DH; i++) acc += qemb[b * DH + i] * ld(W, (size_t)i * G + g);
    qg[b * G + g] = acc;
}
__global__ void k_qg(const int* flag, const float* qemb, const void* W_hg,
                     const void* b_hg, float* qg) {
    if (*flag) qg_body<bf16>(qemb, W_hg, b_hg, qg);
    else       qg_body<float>(qemb, W_hg, b_hg, qg);
}

// ---------------- attn1 softmax + node features: one wave per node ----------
template <typename T>
__device__ void attn1_body(const int* node_descs, const void* emb_desc_,
                           const float* qg, float* nf,
                           float* dsm, float* attn_s, float* qgs) {
    int tid = threadIdx.x;
    if (tid < NB * G) qgs[tid] = qg[tid];
    __syncthreads();
    const T* emb_desc = (const T*)emb_desc_;
    int w = tid >> 6, lane = tid & 63;
    int n = blockIdx.x * 4 + w;
    float dreg[DLEN];
    const int* nd = node_descs + n * DLEN;
    float* dw = dsm + (size_t)w * DLEN * (G + 1);
#pragma unroll
    for (int l = 0; l < DLEN; l++) {
        int idx = nd[l];
        float v = ld(emb_desc, (size_t)idx * G + lane);
        dreg[l] = v;
        dw[l * (G + 1) + lane] = v;
    }
    int lb = lane >> 4, ll = lane & 15;
    float acc = 0.f;
#pragma unroll 8
    for (int g = 0; g < G; g++) acc += dw[ll * (G + 1) + g] * qgs[lb * G + g];
    float mx = acc;
#pragma unroll
    for (int off = 1; off < 16; off <<= 1) mx = fmaxf(mx, __shfl_xor(mx, off, 64));
    float e = expf(acc - mx);
    float s = e;
#pragma unroll
    for (int off = 1; off < 16; off <<= 1) s += __shfl_xor(s, off, 64);
    attn_s[w * 64 + lane] = e / s;
#pragma unroll
    for (int b = 0; b < NB; b++) {
        float a = 0.f;
#pragma unroll
        for (int l = 0; l < DLEN; l++) a += attn_s[w * 64 + b * 16 + l] * dreg[l];
        nf[((size_t)b * NNODES + n) * G + lane] = a;
    }
}
__global__ __launch_bounds__(256) void k_attn1(const int* flag, const int* node_descs,
                                               const void* emb_desc, const float* qg, float* nf) {
    __shared__ float dsm[4 * DLEN * (G + 1)];
    __shared__ float attn_s[4 * 64];
    __shared__ float qgs[NB * G];
    if (*flag) attn1_body<bf16>(node_descs, emb_desc, qg, nf, dsm, attn_s, qgs);
    else       attn1_body<float>(node_descs, emb_desc, qg, nf, dsm, attn_s, qgs);
}

// ---------------- hb = nf @ bases[0] : one wave per (b,n) ----------------
template <typename T>
__device__ void hb_body(const float* nf, const void* bases_, float* hb, float* bsm) {
    int tid = threadIdx.x;
    const T* bases = (const T*)bases_;
    for (int i = tid; i < G * G; i += 256) bsm[(i >> 6) * (G + 1) + (i & 63)] = ld(bases, (size_t)i);
    __syncthreads();
    int w = tid >> 6, lane = tid & 63;
    int n = blockIdx.x, b = w;
    float v = nf[((size_t)b * NNODES + n) * G + lane];
    float acc = 0.f;
#pragma unroll 8
    for (int g = 0; g < G; g++) acc += __shfl(v, g, 64) * bsm[g * (G + 1) + lane];
    hb[((size_t)b * NNODES + n) * G + lane] = acc;
}
__global__ __launch_bounds__(256) void k_hb(const int* flag, const float* nf,
                                            const void* bases, float* hb) {
    __shared__ float bsm[G * (G + 1)];
    if (*flag) hb_body<bf16>(nf, bases, hb, bsm);
    else       hb_body<float>(nf, bases, hb, bsm);
}

// ---------------- CSR build: histogram, scan, scatter ----------------
__global__ void k_hist(const int* dst, int* deg) {
    int e = blockIdx.x * 256 + threadIdx.x;
    if (e < NEDGES) atomicAdd(&deg[dst[e]], 1);
}

__global__ __launch_bounds__(1024) void k_scan(const int* deg, int* offs, int* cur) {
    __shared__ int tot[1024];
    int t = threadIdx.x;
    int c[20];
    int base = t * 20;
    int run = 0;
#pragma unroll
    for (int i = 0; i < 20; i++) {
        int v = (base + i < NNODES) ? deg[base + i] : 0;
        c[i] = run;
        run += v;
    }
    tot[t] = run;
    __syncthreads();
    for (int off = 1; off < 1024; off <<= 1) {
        int v = (t >= off) ? tot[t - off] : 0;
        __syncthreads();
        tot[t] += v;
        __syncthreads();
    }
    int ebase = tot[t] - run;
#pragma unroll
    for (int i = 0; i < 20; i++) {
        if (base + i < NNODES) {
            offs[base + i] = ebase + c[i];
            cur[base + i] = ebase + c[i];
        }
    }
    if (t == 1023) offs[NNODES] = tot[1023];
}

template <typename T>
__device__ void scatter_body(const int* src, const int* dst, const int* typ,
                             const void* w_comp_, int* cur, int* ssrc, float* sco) {
    int e = blockIdx.x * 256 + threadIdx.x;
    if (e < NEDGES) {
        int dd = dst[e];
        int pos = atomicAdd(&cur[dd], 1);
        ssrc[pos] = src[e];
        sco[pos] = ld((const T*)w_comp_, (size_t)typ[e]);
    }
}
__global__ void k_scatter(const int* flag, const int* src, const int* dst, const int* typ,
                          const void* w_comp, int* cur, int* ssrc, float* sco) {
    if (*flag) scatter_body<bf16>(src, dst, typ, w_comp, cur, ssrc, sco);
    else       scatter_body<float>(src, dst, typ, w_comp, cur, ssrc, sco);
}

// ---------------- RGCN aggregate (gather over CSR) + bias + relu -----------
template <typename T>
__device__ void agg_body(const float* hb, const int* offs, const int* ssrc,
                         const float* sco, const void* bias_, float* out_nf) {
    int tid = threadIdx.x;
    int b = tid >> 6, g = tid & 63;
    int dn = blockIdx.x;
    int s0 = offs[dn], s1 = offs[dn + 1];
    const float* hbb = hb + (size_t)b * NNODES * G;
    float acc = 0.f;
    for (int p = s0; p < s1; p++) {
        int src = ssrc[p];
        acc += sco[p] * hbb[(size_t)src * G + g];
    }
    out_nf[((size_t)b * NNODES + dn) * G + g] = relu(acc + ld((const T*)bias_, (size_t)g));
}
__global__ __launch_bounds__(256) void k_agg(const int* flag, const float* hb, const int* offs,
                                             const int* ssrc, const float* sco,
                                             const void* bias, float* out_nf) {
    if (*flag) agg_body<bf16>(hb, offs, ssrc, sco, bias, out_nf);
    else       agg_body<float>(hb, offs, ssrc, sco, bias, out_nf);
}

// ---------------- attn2: logits + max ----------------
__global__ __launch_bounds__(256) void k_attn2a(const float* rg, const float* qg,
                                                float* l2, unsigned* gmx) {
    int tid = threadIdx.x;
    int b = tid >> 6, lane = tid & 63;
    float q = qg[b * G + lane];
    float lmax = -3.4e38f;
    for (int n = blockIdx.x; n < NNODES; n += gridDim.x) {
        float p = rg[((size_t)b * NNODES + n) * G + lane] * q;
#pragma unroll
        for (int off = 32; off >= 1; off >>= 1) p += __shfl_xor(p, off, 64);
        if (lane == 0) l2[b * NNODES + n] = p;
        lmax = fmaxf(lmax, p);
    }
    if (lane == 0) {
        unsigned u = __float_as_uint(lmax);
        unsigned key = (u >> 31) ? ~u : (u | 0x80000000u);
        atomicMax(&gmx[b], key);
    }
}

// ---------------- attn2: exp-sum + unnormalized weighted pooling ------------
__global__ __launch_bounds__(256) void k_attn2b(const float* rg, const float* l2,
                                                const unsigned* gmx, float* Z, float* nar) {
    int tid = threadIdx.x;
    int b = tid >> 6, lane = tid & 63;
    unsigned k = gmx[b];
    float mx = (k & 0x80000000u) ? __uint_as_float(k & 0x7fffffffu) : __uint_as_float(~k);
    float fsum = 0.f, facc = 0.f;
    for (int n = blockIdx.x; n < NNODES; n += gridDim.x) {
        float e = expf(l2[b * NNODES + n] - mx);
        fsum += e;
        facc += e * rg[((size_t)b * NNODES + n) * G + lane];
    }
    atomicAdd(&nar[b * G + lane], facc);
    if (lane == 0) atomicAdd(&Z[b], fsum);
}

// ---------------- classifier: fc1, parallel k-reduction ----------------
// grid = NB*16 blocks; block 256 = 64 u-lanes x 4 k-phases (K=320 -> 80 each)
template <typename T>
__device__ void fc1_body(const float* nar, const float* Z, const float* qemb,
                         const void* W1_, const void* b1_, float* hid,
                         float* feat, float* psum) {
    int tid = threadIdx.x;
    int b = blockIdx.x >> 4, tile = blockIdx.x & 15;
    // 320 feat elements, 256 threads: strided loop (round-3 bug was `if (tid<320)`)
    for (int i = tid; i < 320; i += 256) {
        feat[i] = (i < G) ? nar[b * G + i] / Z[b] : qemb[b * DH + i - G];
    }
    __syncthreads();
    int lane = tid & 63, phase = tid >> 6;
    int u = tile * 64 + lane;
    const T* W1 = (const T*)W1_;
    float acc = 0.f;
#pragma unroll 8
    for (int kk = 0; kk < 80; kk++) {
        int k = phase * 80 + kk;
        acc += feat[k] * ld(W1, (size_t)k * 1024 + u);
    }
    psum[tid] = acc;
    __syncthreads();
    if (phase == 0) {
        float tot = psum[lane] + psum[64 + lane] + psum[128 + lane] + psum[192 + lane]
                  + ld((const T*)b1_, (size_t)u);
        hid[b * 1024 + u] = relu(tot);
    }
}
__global__ __launch_bounds__(256) void k_fc1(const int* flag, const float* nar, const float* Z,
                                             const float* qemb, const void* W1, const void* b1,
                                             float* hid) {
    __shared__ float feat[320];
    __shared__ float psum[256];
    if (*flag) fc1_body<bf16>(nar, Z, qemb, W1, b1, hid, feat, psum);
    else       fc1_body<float>(nar, Z, qemb, W1, b1, hid, feat, psum);
}

// ---------------- classifier: fc2, parallel k-reduction ----------------
// grid = NB*32 blocks; block 256 = 64 c-lanes x 4 u-phases (K=1024 -> 256 each)
template <typename T>
__device__ void fc2_body(const float* hid, const void* W2_, const void* b2_, void* out_,
                         float* hs, float* psum) {
    int tid = threadIdx.x;
    int b = blockIdx.x >> 5, tile = blockIdx.x & 31;
#pragma unroll
    for (int i = 0; i < 4; i++) hs[tid + 256 * i] = hid[b * 1024 + tid + 256 * i];
    __syncthreads();
    int lane = tid & 63, phase = tid >> 6;
    int c = tile * 64 + lane;
    bool ok = (c < NCLS);
    const T* W2 = (const T*)W2_;
    float acc = 0.f;
    if (ok) {
#pragma unroll 8
        for (int uu = 0; uu < 256; uu++) {
            int u = phase * 256 + uu;
            acc += hs[u] * ld(W2, (size_t)u * NCLS + c);
        }
    }
    psum[tid] = acc;
    __syncthreads();
    if (phase == 0 && ok) {
        float tot = psum[lane] + psum[64 + lane] + psum[128 + lane] + psum[192 + lane]
                  + ld((const T*)b2_, (size_t)c);
        st((T*)out_, (size_t)b * NCLS + c, tot);
    }
}
__global__ __launch_bounds__(256) void k_fc2(const int* flag, const float* hid,
                                             const void* W2, const void* b2v, void* out) {
    __shared__ float hs[1024];
    __shared__ float psum[256];
    if (*flag) fc2_body<bf16>(hid, W2, b2v, out, hs, psum);
    else       fc2_body<float>(hid, W2, b2v, out, hs, psum);
}

extern "C" void kernel_launch(void* const* d_in, const int* in_sizes, int n_in,
                              void* d_out, int out_size, void* d_ws, size_t ws_size,
                              hipStream_t stream) {
    const int* questions  = (const int*)d_in[0];
    const int* node_descs = (const int*)d_in[1];
    const int* edge_src   = (const int*)d_in[2];
    const int* edge_dst   = (const int*)d_in[3];
    const int* edge_type  = (const int*)d_in[4];
    const void* emb_word  = d_in[5];
    const void* emb_desc  = d_in[6];
    const void* Wx_f = d_in[7];
    const void* Wh_f = d_in[8];
    const void* bx_f = d_in[9];
    const void* bh_f = d_in[10];
    const void* Wx_b = d_in[11];
    const void* Wh_b = d_in[12];
    const void* bx_b = d_in[13];
    const void* bh_b = d_in[14];
    const void* W_hg = d_in[15];
    const void* b_hg = d_in[16];
    const void* bases = d_in[17];
    const void* w_comp = d_in[18];
    const void* rgcn_bias = d_in[19];
    const void* W1 = d_in[20];
    const void* b1 = d_in[21];
    const void* W2 = d_in[22];
    const void* b2 = d_in[23];

    float* ws = (float*)d_ws;
    int*      flag = (int*)(ws + OFF_FLAG);
    float*    gx   = ws + OFF_GX;
    float*    whf  = ws + OFF_WHF;
    float*    qemb = ws + OFF_QEMB;
    float*    qg   = ws + OFF_QG;
    float*    nf   = ws + OFF_NF;
    float*    hb   = ws + OFF_HB;
    float*    l2   = ws + OFF_L2;
    int*      deg  = (int*)(ws + OFF_DEG);
    int*      offs = (int*)(ws + OFF_OFFS);
    int*      cur  = (int*)(ws + OFF_CUR);
    int*      ssrc = (int*)(ws + OFF_SSRC);
    float*    sco  = ws + OFF_SCO;
    unsigned* gmx  = (unsigned*)(ws + OFF_GMX);
    float*    Z    = ws + OFF_Z;
    float*    nar  = ws + OFF_NAR;
    float*    hid  = ws + OFF_HID;

    hipLaunchKernelGGL(k_init, dim3(80), dim3(256), 0, stream,
                       (const unsigned*)emb_word, flag, deg, gmx, Z, nar);
    hipLaunchKernelGGL(k_hist, dim3((NEDGES + 255) / 256), dim3(256), 0, stream, edge_dst, deg);
    hipLaunchKernelGGL(k_cvt, dim3((2 * HD * G3 + 255) / 256), dim3(256), 0, stream,
                       flag, Wh_f, Wh_b, whf);
    hipLaunchKernelGGL(k_gx, dim3(2 * NB * TT * G3 / 256), dim3(256), 0, stream,
                       flag, questions, emb_word, Wx_f, bx_f, Wx_b, bx_b, gx);
    hipLaunchKernelGGL(k_gru, dim3(8), dim3(2 * G3), 0, stream,
                       flag, questions, gx, whf, bh_f, bh_b, qemb);
    hipLaunchKernelGGL(k_scan, dim3(1), dim3(1024), 0, stream, deg, offs, cur);
    hipLaunchKernelGGL(k_scatter, dim3((NEDGES + 255) / 256), dim3(256), 0, stream,
                       flag, edge_src, edge_dst, edge_type, w_comp, cur, ssrc, sco);
    hipLaunchKernelGGL(k_qg, dim3(1), dim3(256), 0, stream, flag, qemb, W_hg, b_hg, qg);
    hipLaunchKernelGGL(k_attn1, dim3(NNODES / 4), dim3(256), 0, stream,
                       flag, node_descs, emb_desc, qg, nf);
    hipLaunchKernelGGL(k_hb, dim3(NNODES), dim3(256), 0, stream, flag, nf, bases, hb);
    hipLaunchKernelGGL(k_agg, dim3(NNODES), dim3(256), 0, stream,
                       flag, hb, offs, ssrc, sco, rgcn_bias, nf);
    hipLaunchKernelGGL(k_attn2a, dim3(256), dim3(256), 0, stream, nf, qg, l2, gmx);
    hipLaunchKernelGGL(k_attn2b, dim3(256), dim3(256), 0, stream, nf, l2, gmx, Z, nar);
    hipLaunchKernelGGL(k_fc1, dim3(NB * 16), dim3(256), 0, stream,
                       flag, nar, Z, qemb, W1, b1, hid);
    hipLaunchKernelGGL(k_fc2, dim3(NB * 32), dim3(256), 0, stream,
                       flag, hid, W2, b2, d_out);
}

// Round 5
// 519.358 us; speedup vs baseline: 1.4075x; 1.0808x over previous
//
#include <hip/hip_runtime.h>
#include <hip/hip_bf16.h>
#include <math.h>

typedef __hip_bfloat16 bf16;

#define NNODES 20000
#define NEDGES 320000
#define DLEN   16
#define G      64
#define DW     300
#define DH     256
#define HD     128
#define G3     384
#define NCLS   2000
#define NB     4
#define TT     32

__device__ __forceinline__ float ld(const float* p, size_t i) { return p[i]; }
__device__ __forceinline__ float ld(const bf16* p, size_t i) { return __bfloat162float(p[i]); }
__device__ __forceinline__ void st(float* p, size_t i, float v) { p[i] = v; }
__device__ __forceinline__ void st(bf16* p, size_t i, float v) { p[i] = __float2bfloat16(v); }
__device__ __forceinline__ float relu(float x) { return (x < 0.f) ? 0.f : x; }

// ---------------- workspace layout (float words) ----------------
#define OFF_FLAG  ((size_t)0)                         // 4
#define OFF_GX    (OFF_FLAG + 4)                      // 2*4*32*384 = 98304
#define OFF_WHF   (OFF_GX   + 2*NB*TT*G3)             // Wh fp32: 2*128*384 = 98304
#define OFF_QEMB  (OFF_WHF  + 2*HD*G3)                // 1024
#define OFF_QG    (OFF_QEMB + NB*DH)                  // 256
#define OFF_NF    (OFF_QG   + NB*G)                   // 5,120,000
#define OFF_HB    (OFF_NF   + (size_t)NB*NNODES*G)    // 5,120,000
#define OFF_L2    (OFF_HB   + (size_t)NB*NNODES*G)    // 80,000
#define OFF_DEG   (OFF_L2   + (size_t)NB*NNODES)      // int 20000
#define OFF_OFFS  (OFF_DEG  + NNODES)                 // int 20008
#define OFF_CUR   (OFF_OFFS + NNODES + 8)             // int 20000
#define OFF_SSRC  (OFF_CUR  + NNODES)                 // int 320000
#define OFF_SCO   (OFF_SSRC + NEDGES)                 // float 320000
#define OFF_GMX   (OFF_SCO  + NEDGES)                 // uint 4
#define OFF_Z     (OFF_GMX  + 4)                      // 4
#define OFF_NAR   (OFF_Z    + 4)                      // 256
#define OFF_HID   (OFF_NAR  + NB*G)                   // 4096

// ---------------- init: dtype sniff + zero accumulators ----------------
__global__ void k_init(const unsigned* probe, int* flag, int* deg, unsigned* gmx,
                       float* Z, float* nar) {
    int i = blockIdx.x * 256 + threadIdx.x;
    if (i < NNODES) deg[i] = 0;
    if (i < 4) { gmx[i] = 0u; Z[i] = 0.f; }
    if (i < NB * G) nar[i] = 0.f;
    if (blockIdx.x == 0 && threadIdx.x < 64) {
        int cnt = 0;
        for (int k = threadIdx.x; k < 4096; k += 64) {
            unsigned lo = probe[k] & 0xFFFFu;
            unsigned e = (lo >> 7) & 0xFFu;
            cnt += (e >= 0x66u && e <= 0x7Eu) ? 1 : 0;
        }
#pragma unroll
        for (int off = 1; off < 64; off <<= 1) cnt += __shfl_xor(cnt, off, 64);
        if (threadIdx.x == 0) *flag = (2 * cnt > 4096) ? 1 : 0;   // 1 = bf16
    }
}

// ---------------- convert Wh to fp32 in ws ----------------
template <typename T>
__device__ void cvt_body(const void* Whf_, const void* Whb_, float* whf) {
    int id = blockIdx.x * 256 + threadIdx.x;   // 2*128*384 = 98304
    if (id >= 2 * HD * G3) return;
    int d = id / (HD * G3), r = id % (HD * G3);
    const T* W = (const T*)(d ? Whb_ : Whf_);
    whf[id] = ld(W, (size_t)r);
}
__global__ void k_cvt(const int* flag, const void* Whf, const void* Whb, float* whf) {
    if (*flag) cvt_body<bf16>(Whf, Whb, whf);
    else       cvt_body<float>(Whf, Whb, whf);
}

// ---------------- gx = x @ Wx + bx, stored in scan order per direction ------
template <typename T>
__device__ void gx_body(const int* questions, const void* emb_word_,
                        const void* Wxf_, const void* bxf_,
                        const void* Wxb_, const void* bxb_, float* gx) {
    int id = blockIdx.x * 256 + threadIdx.x;   // 2*4*32*384 = 98304
    int j = id % G3;
    int step = (id / G3) % TT;
    int b = (id / (G3 * TT)) % NB;
    int d = id / (G3 * TT * NB);
    int t = d ? (TT - 1 - step) : step;
    int tok = questions[b * TT + t];
    const T* Wx = (const T*)(d ? Wxb_ : Wxf_);
    const T* bx = (const T*)(d ? bxb_ : bxf_);
    const T* row = (const T*)emb_word_ + (size_t)tok * DW;
    float acc = ld(bx, (size_t)j);
#pragma unroll 4
    for (int k = 0; k < DW; k++) acc += ld(row, (size_t)k) * ld(Wx, (size_t)k * G3 + j);
    gx[id] = acc;
}
__global__ void k_gx(const int* flag, const int* questions, const void* emb_word,
                     const void* Wxf, const void* bxf,
                     const void* Wxb, const void* bxb, float* gx) {
    if (*flag) gx_body<bf16>(questions, emb_word, Wxf, bxf, Wxb, bxb, gx);
    else       gx_body<float>(questions, emb_word, Wxf, bxf, Wxb, bxb, gx);
}

// ---------------- GRU scan: block per (d,b), Wh register-resident ----------
template <typename T>
__device__ void gru_body(const int* questions, const float* gx, const float* whf,
                         const void* bhf_, const void* bhb_, float* qemb,
                         float* hsm, float* ghs) {
    int tid = threadIdx.x;
    int d = blockIdx.x >> 2, b = blockIdx.x & 3;
    int half = tid / G3, j = tid - half * G3;
    const float* wh = whf + (size_t)d * HD * G3 + (size_t)half * 64 * G3 + j;
    float w[64];
#pragma unroll
    for (int m = 0; m < 64; m++) w[m] = wh[(size_t)m * G3];
    const T* bh = (const T*)(d ? bhb_ : bhf_);
    float bhj = (half == 0) ? ld(bh, (size_t)j) : 0.f;
    if (tid < HD) hsm[tid] = 0.f;
    const float* gxb = gx + ((size_t)(d * NB + b)) * TT * G3;
    __syncthreads();
    const float4* h4 = (const float4*)(hsm + half * 64);
    for (int step = 0; step < TT; step++) {
        float acc = bhj;
#pragma unroll
        for (int m4 = 0; m4 < 16; m4++) {
            float4 hp = h4[m4];
            acc = fmaf(hp.x, w[4 * m4 + 0], acc);
            acc = fmaf(hp.y, w[4 * m4 + 1], acc);
            acc = fmaf(hp.z, w[4 * m4 + 2], acc);
            acc = fmaf(hp.w, w[4 * m4 + 3], acc);
        }
        ghs[half * G3 + j] = acc;
        __syncthreads();
        if (tid < HD) {
            const float* gxp = gxb + step * G3;
            int t = d ? (TT - 1 - step) : step;
            bool msk = questions[b * TT + t] != 0;
            float gr = ghs[tid] + ghs[G3 + tid];
            float gz = ghs[HD + tid] + ghs[G3 + HD + tid];
            float gn = ghs[2 * HD + tid] + ghs[G3 + 2 * HD + tid];
            float r = 1.f / (1.f + expf(-(gxp[tid] + gr)));
            float z = 1.f / (1.f + expf(-(gxp[HD + tid] + gz)));
            float n = tanhf(gxp[2 * HD + tid] + r * gn);
            float hn = (1.f - z) * n + z * hsm[tid];
            if (msk) hsm[tid] = hn;
        }
        __syncthreads();
    }
    if (tid < HD) qemb[b * DH + d * HD + tid] = hsm[tid];
}
__global__ __launch_bounds__(2 * G3) void k_gru(const int* flag, const int* questions,
                                                const float* gx, const float* whf,
                                                const void* bhf, const void* bhb, float* qemb) {
    __shared__ __align__(16) float hsm[HD];
    __shared__ float ghs[2 * G3];
    if (*flag) gru_body<bf16>(questions, gx, whf, bhf, bhb, qemb, hsm, ghs);
    else       gru_body<float>(questions, gx, whf, bhf, bhb, qemb, hsm, ghs);
}

// ---------------- q_g = q_emb @ W_hg + b_hg ----------------
template <typename T>
__device__ void qg_body(const float* qemb, const void* W_hg_, const void* b_hg_, float* qg) {
    int tid = threadIdx.x;   // 256
    int b = tid >> 6, g = tid & 63;
    const T* W = (const T*)W_hg_;
    float acc = ld((const T*)b_hg_, (size_t)g);
#pragma unroll 4
    for (int i = 0; i < DH; i++) acc += qemb[b * DH + i] * ld(W, (size_t)i * G + g);
    qg[b * G + g] = acc;
}
__global__ void k_qg(const int* flag, const float* qemb, const void* W_hg,
                     const void* b_hg, float* qg) {
    if (*flag) qg_body<bf16>(qemb, W_hg, b_hg, qg);
    else       qg_body<float>(qemb, W_hg, b_hg, qg);
}

// ---------------- attn1 softmax + node features: one wave per node ----------
template <typename T>
__device__ void attn1_body(const int* node_descs, const void* emb_desc_,
                           const float* qg, float* nf,
                           float* dsm, float* attn_s, float* qgs) {
    int tid = threadIdx.x;
    if (tid < NB * G) qgs[tid] = qg[tid];
    __syncthreads();
    const T* emb_desc = (const T*)emb_desc_;
    int w = tid >> 6, lane = tid & 63;
    int n = blockIdx.x * 4 + w;
    float dreg[DLEN];
    const int* nd = node_descs + n * DLEN;
    float* dw = dsm + (size_t)w * DLEN * (G + 1);
#pragma unroll
    for (int l = 0; l < DLEN; l++) {
        int idx = nd[l];
        float v = ld(emb_desc, (size_t)idx * G + lane);
        dreg[l] = v;
        dw[l * (G + 1) + lane] = v;
    }
    int lb = lane >> 4, ll = lane & 15;
    float acc = 0.f;
#pragma unroll 8
    for (int g = 0; g < G; g++) acc += dw[ll * (G + 1) + g] * qgs[lb * G + g];
    float mx = acc;
#pragma unroll
    for (int off = 1; off < 16; off <<= 1) mx = fmaxf(mx, __shfl_xor(mx, off, 64));
    float e = expf(acc - mx);
    float s = e;
#pragma unroll
    for (int off = 1; off < 16; off <<= 1) s += __shfl_xor(s, off, 64);
    attn_s[w * 64 + lane] = e / s;
#pragma unroll
    for (int b = 0; b < NB; b++) {
        float a = 0.f;
#pragma unroll
        for (int l = 0; l < DLEN; l++) a += attn_s[w * 64 + b * 16 + l] * dreg[l];
        nf[((size_t)b * NNODES + n) * G + lane] = a;
    }
}
__global__ __launch_bounds__(256) void k_attn1(const int* flag, const int* node_descs,
                                               const void* emb_desc, const float* qg, float* nf) {
    __shared__ float dsm[4 * DLEN * (G + 1)];
    __shared__ float attn_s[4 * 64];
    __shared__ float qgs[NB * G];
    if (*flag) attn1_body<bf16>(node_descs, emb_desc, qg, nf, dsm, attn_s, qgs);
    else       attn1_body<float>(node_descs, emb_desc, qg, nf, dsm, attn_s, qgs);
}

// ---------------- hb = nf @ bases[0] : tiled register GEMM ----------------
// C[80000x64] = A[80000x64] * B[64x64]. Block 256 = 16tx x 16ty; thread does
// 4 rows x 4 cols; A-tile + B in LDS (stride 68: 16B-aligned, bank-offset 4).
// Accumulation over g ascending -> bit-identical to previous shfl version.
template <typename T>
__device__ void hbg_body(const float* nf, const void* bases_, float* hb,
                         float* as, float* bs) {
    int tid = threadIdx.x;
    const T* bases = (const T*)bases_;
    for (int i = tid; i < G * G; i += 256) bs[(i >> 6) * 68 + (i & 63)] = ld(bases, (size_t)i);
    size_t r0 = (size_t)blockIdx.x * 64;
    const float4* gA = (const float4*)(nf + r0 * G);
#pragma unroll
    for (int i = 0; i < 4; i++) {
        int c = tid + i * 256;               // 0..1023, linear float4 index
        int row = c >> 4, col4 = c & 15;     // 4c = row*64 + col4*4
        float4 v = gA[c];
        *(float4*)&as[row * 68 + col4 * 4] = v;
    }
    __syncthreads();
    int tx = tid & 15, ty = tid >> 4;
    float acc[4][4];
#pragma unroll
    for (int i = 0; i < 4; i++)
#pragma unroll
        for (int j = 0; j < 4; j++) acc[i][j] = 0.f;
#pragma unroll 4
    for (int g4 = 0; g4 < 16; g4++) {
        float4 b0 = *(const float4*)&bs[(4 * g4 + 0) * 68 + tx * 4];
        float4 b1 = *(const float4*)&bs[(4 * g4 + 1) * 68 + tx * 4];
        float4 b2 = *(const float4*)&bs[(4 * g4 + 2) * 68 + tx * 4];
        float4 b3 = *(const float4*)&bs[(4 * g4 + 3) * 68 + tx * 4];
#pragma unroll
        for (int i = 0; i < 4; i++) {
            float4 a = *(const float4*)&as[(ty * 4 + i) * 68 + g4 * 4];
            acc[i][0] = fmaf(a.x, b0.x, acc[i][0]);
            acc[i][0] = fmaf(a.y, b1.x, acc[i][0]);
            acc[i][0] = fmaf(a.z, b2.x, acc[i][0]);
            acc[i][0] = fmaf(a.w, b3.x, acc[i][0]);
            acc[i][1] = fmaf(a.x, b0.y, acc[i][1]);
            acc[i][1] = fmaf(a.y, b1.y, acc[i][1]);
            acc[i][1] = fmaf(a.z, b2.y, acc[i][1]);
            acc[i][1] = fmaf(a.w, b3.y, acc[i][1]);
            acc[i][2] = fmaf(a.x, b0.z, acc[i][2]);
            acc[i][2] = fmaf(a.y, b1.z, acc[i][2]);
            acc[i][2] = fmaf(a.z, b2.z, acc[i][2]);
            acc[i][2] = fmaf(a.w, b3.z, acc[i][2]);
            acc[i][3] = fmaf(a.x, b0.w, acc[i][3]);
            acc[i][3] = fmaf(a.y, b1.w, acc[i][3]);
            acc[i][3] = fmaf(a.z, b2.w, acc[i][3]);
            acc[i][3] = fmaf(a.w, b3.w, acc[i][3]);
        }
    }
#pragma unroll
    for (int i = 0; i < 4; i++) {
        float4 o;
        o.x = acc[i][0]; o.y = acc[i][1]; o.z = acc[i][2]; o.w = acc[i][3];
        *(float4*)&hb[(r0 + ty * 4 + i) * G + tx * 4] = o;
    }
}
__global__ __launch_bounds__(256) void k_hbg(const int* flag, const float* nf,
                                             const void* bases, float* hb) {
    __shared__ __align__(16) float as[64 * 68];
    __shared__ __align__(16) float bs[64 * 68];
    if (*flag) hbg_body<bf16>(nf, bases, hb, as, bs);
    else       hbg_body<float>(nf, bases, hb, as, bs);
}

// ---------------- CSR build: histogram, scan, scatter ----------------
__global__ void k_hist(const int* dst, int* deg) {
    int e = blockIdx.x * 256 + threadIdx.x;
    if (e < NEDGES) atomicAdd(&deg[dst[e]], 1);
}

__global__ __launch_bounds__(1024) void k_scan(const int* deg, int* offs, int* cur) {
    __shared__ int tot[1024];
    int t = threadIdx.x;
    int c[20];
    int base = t * 20;
    int run = 0;
#pragma unroll
    for (int i = 0; i < 20; i++) {
        int v = (base + i < NNODES) ? deg[base + i] : 0;
        c[i] = run;
        run += v;
    }
    tot[t] = run;
    __syncthreads();
    for (int off = 1; off < 1024; off <<= 1) {
        int v = (t >= off) ? tot[t - off] : 0;
        __syncthreads();
        tot[t] += v;
        __syncthreads();
    }
    int ebase = tot[t] - run;
#pragma unroll
    for (int i = 0; i < 20; i++) {
        if (base + i < NNODES) {
            offs[base + i] = ebase + c[i];
            cur[base + i] = ebase + c[i];
        }
    }
    if (t == 1023) offs[NNODES] = tot[1023];
}

template <typename T>
__device__ void scatter_body(const int* src, const int* dst, const int* typ,
                             const void* w_comp_, int* cur, int* ssrc, float* sco) {
    int e = blockIdx.x * 256 + threadIdx.x;
    if (e < NEDGES) {
        int dd = dst[e];
        int pos = atomicAdd(&cur[dd], 1);
        ssrc[pos] = src[e];
        sco[pos] = ld((const T*)w_comp_, (size_t)typ[e]);
    }
}
__global__ void k_scatter(const int* flag, const int* src, const int* dst, const int* typ,
                          const void* w_comp, int* cur, int* ssrc, float* sco) {
    if (*flag) scatter_body<bf16>(src, dst, typ, w_comp, cur, ssrc, sco);
    else       scatter_body<float>(src, dst, typ, w_comp, cur, ssrc, sco);
}

// ---------------- RGCN aggregate (gather over CSR) + bias + relu -----------
// 4x unrolled edge loop: 4 independent gathers in flight; sequential adds
// preserve accumulation order (bit-identical).
template <typename T>
__device__ void agg_body(const float* hb, const int* offs, const int* ssrc,
                         const float* sco, const void* bias_, float* out_nf) {
    int tid = threadIdx.x;
    int b = tid >> 6, g = tid & 63;
    int dn = blockIdx.x;
    int s0 = offs[dn], s1 = offs[dn + 1];
    const float* hbb = hb + (size_t)b * NNODES * G;
    float acc = 0.f;
    int p = s0;
    for (; p + 3 < s1; p += 4) {
        int i0 = ssrc[p], i1 = ssrc[p + 1], i2 = ssrc[p + 2], i3 = ssrc[p + 3];
        float c0 = sco[p], c1 = sco[p + 1], c2 = sco[p + 2], c3 = sco[p + 3];
        float x0 = hbb[(size_t)i0 * G + g];
        float x1 = hbb[(size_t)i1 * G + g];
        float x2 = hbb[(size_t)i2 * G + g];
        float x3 = hbb[(size_t)i3 * G + g];
        acc += c0 * x0;
        acc += c1 * x1;
        acc += c2 * x2;
        acc += c3 * x3;
    }
    for (; p < s1; p++) acc += sco[p] * hbb[(size_t)ssrc[p] * G + g];
    out_nf[((size_t)b * NNODES + dn) * G + g] = relu(acc + ld((const T*)bias_, (size_t)g));
}
__global__ __launch_bounds__(256) void k_agg(const int* flag, const float* hb, const int* offs,
                                             const int* ssrc, const float* sco,
                                             const void* bias, float* out_nf) {
    if (*flag) agg_body<bf16>(hb, offs, ssrc, sco, bias, out_nf);
    else       agg_body<float>(hb, offs, ssrc, sco, bias, out_nf);
}

// ---------------- attn2: logits + max ----------------
__global__ __launch_bounds__(256) void k_attn2a(const float* rg, const float* qg,
                                                float* l2, unsigned* gmx) {
    int tid = threadIdx.x;
    int b = tid >> 6, lane = tid & 63;
    float q = qg[b * G + lane];
    float lmax = -3.4e38f;
    for (int n = blockIdx.x; n < NNODES; n += gridDim.x) {
        float p = rg[((size_t)b * NNODES + n) * G + lane] * q;
#pragma unroll
        for (int off = 32; off >= 1; off >>= 1) p += __shfl_xor(p, off, 64);
        if (lane == 0) l2[b * NNODES + n] = p;
        lmax = fmaxf(lmax, p);
    }
    if (lane == 0) {
        unsigned u = __float_as_uint(lmax);
        unsigned key = (u >> 31) ? ~u : (u | 0x80000000u);
        atomicMax(&gmx[b], key);
    }
}

// ---------------- attn2: exp-sum + unnormalized weighted pooling ------------
__global__ __launch_bounds__(256) void k_attn2b(const float* rg, const float* l2,
                                                const unsigned* gmx, float* Z, float* nar) {
    int tid = threadIdx.x;
    int b = tid >> 6, lane = tid & 63;
    unsigned k = gmx[b];
    float mx = (k & 0x80000000u) ? __uint_as_float(k & 0x7fffffffu) : __uint_as_float(~k);
    float fsum = 0.f, facc = 0.f;
    for (int n = blockIdx.x; n < NNODES; n += gridDim.x) {
        float e = expf(l2[b * NNODES + n] - mx);
        fsum += e;
        facc += e * rg[((size_t)b * NNODES + n) * G + lane];
    }
    atomicAdd(&nar[b * G + lane], facc);
    if (lane == 0) atomicAdd(&Z[b], fsum);
}

// ---------------- classifier: fc1, parallel k-reduction ----------------
template <typename T>
__device__ void fc1_body(const float* nar, const float* Z, const float* qemb,
                         const void* W1_, const void* b1_, float* hid,
                         float* feat, float* psum) {
    int tid = threadIdx.x;
    int b = blockIdx.x >> 4, tile = blockIdx.x & 15;
    for (int i = tid; i < 320; i += 256) {
        feat[i] = (i < G) ? nar[b * G + i] / Z[b] : qemb[b * DH + i - G];
    }
    __syncthreads();
    int lane = tid & 63, phase = tid >> 6;
    int u = tile * 64 + lane;
    const T* W1 = (const T*)W1_;
    float acc = 0.f;
#pragma unroll 8
    for (int kk = 0; kk < 80; kk++) {
        int k = phase * 80 + kk;
        acc += feat[k] * ld(W1, (size_t)k * 1024 + u);
    }
    psum[tid] = acc;
    __syncthreads();
    if (phase == 0) {
        float tot = psum[lane] + psum[64 + lane] + psum[128 + lane] + psum[192 + lane]
                  + ld((const T*)b1_, (size_t)u);
        hid[b * 1024 + u] = relu(tot);
    }
}
__global__ __launch_bounds__(256) void k_fc1(const int* flag, const float* nar, const float* Z,
                                             const float* qemb, const void* W1, const void* b1,
                                             float* hid) {
    __shared__ float feat[320];
    __shared__ float psum[256];
    if (*flag) fc1_body<bf16>(nar, Z, qemb, W1, b1, hid, feat, psum);
    else       fc1_body<float>(nar, Z, qemb, W1, b1, hid, feat, psum);
}

// ---------------- classifier: fc2, parallel k-reduction ----------------
template <typename T>
__device__ void fc2_body(const float* hid, const void* W2_, const void* b2_, void* out_,
                         float* hs, float* psum) {
    int tid = threadIdx.x;
    int b = blockIdx.x >> 5, tile = blockIdx.x & 31;
#pragma unroll
    for (int i = 0; i < 4; i++) hs[tid + 256 * i] = hid[b * 1024 + tid + 256 * i];
    __syncthreads();
    int lane = tid & 63, phase = tid >> 6;
    int c = tile * 64 + lane;
    bool ok = (c < NCLS);
    const T* W2 = (const T*)W2_;
    float acc = 0.f;
    if (ok) {
#pragma unroll 8
        for (int uu = 0; uu < 256; uu++) {
            int u = phase * 256 + uu;
            acc += hs[u] * ld(W2, (size_t)u * NCLS + c);
        }
    }
    psum[tid] = acc;
    __syncthreads();
    if (phase == 0 && ok) {
        float tot = psum[lane] + psum[64 + lane] + psum[128 + lane] + psum[192 + lane]
                  + ld((const T*)b2_, (size_t)c);
        st((T*)out_, (size_t)b * NCLS + c, tot);
    }
}
__global__ __launch_bounds__(256) void k_fc2(const int* flag, const float* hid,
                                             const void* W2, const void* b2v, void* out) {
    __shared__ float hs[1024];
    __shared__ float psum[256];
    if (*flag) fc2_body<bf16>(hid, W2, b2v, out, hs, psum);
    else       fc2_body<float>(hid, W2, b2v, out, hs, psum);
}

extern "C" void kernel_launch(void* const* d_in, const int* in_sizes, int n_in,
                              void* d_out, int out_size, void* d_ws, size_t ws_size,
                              hipStream_t stream) {
    const int* questions  = (const int*)d_in[0];
    const int* node_descs = (const int*)d_in[1];
    const int* edge_src   = (const int*)d_in[2];
    const int* edge_dst   = (const int*)d_in[3];
    const int* edge_type  = (const int*)d_in[4];
    const void* emb_word  = d_in[5];
    const void* emb_desc  = d_in[6];
    const void* Wx_f = d_in[7];
    const void* Wh_f = d_in[8];
    const void* bx_f = d_in[9];
    const void* bh_f = d_in[10];
    const void* Wx_b = d_in[11];
    const void* Wh_b = d_in[12];
    const void* bx_b = d_in[13];
    const void* bh_b = d_in[14];
    const void* W_hg = d_in[15];
    const void* b_hg = d_in[16];
    const void* bases = d_in[17];
    const void* w_comp = d_in[18];
    const void* rgcn_bias = d_in[19];
    const void* W1 = d_in[20];
    const void* b1 = d_in[21];
    const void* W2 = d_in[22];
    const void* b2 = d_in[23];

    float* ws = (float*)d_ws;
    int*      flag = (int*)(ws + OFF_FLAG);
    float*    gx   = ws + OFF_GX;
    float*    whf  = ws + OFF_WHF;
    float*    qemb = ws + OFF_QEMB;
    float*    qg   = ws + OFF_QG;
    float*    nf   = ws + OFF_NF;
    float*    hb   = ws + OFF_HB;
    float*    l2   = ws + OFF_L2;
    int*      deg  = (int*)(ws + OFF_DEG);
    int*      offs = (int*)(ws + OFF_OFFS);
    int*      cur  = (int*)(ws + OFF_CUR);
    int*      ssrc = (int*)(ws + OFF_SSRC);
    float*    sco  = ws + OFF_SCO;
    unsigned* gmx  = (unsigned*)(ws + OFF_GMX);
    float*    Z    = ws + OFF_Z;
    float*    nar  = ws + OFF_NAR;
    float*    hid  = ws + OFF_HID;

    hipLaunchKernelGGL(k_init, dim3(80), dim3(256), 0, stream,
                       (const unsigned*)emb_word, flag, deg, gmx, Z, nar);
    hipLaunchKernelGGL(k_hist, dim3((NEDGES + 255) / 256), dim3(256), 0, stream, edge_dst, deg);
    hipLaunchKernelGGL(k_cvt, dim3((2 * HD * G3 + 255) / 256), dim3(256), 0, stream,
                       flag, Wh_f, Wh_b, whf);
    hipLaunchKernelGGL(k_gx, dim3(2 * NB * TT * G3 / 256), dim3(256), 0, stream,
                       flag, questions, emb_word, Wx_f, bx_f, Wx_b, bx_b, gx);
    hipLaunchKernelGGL(k_gru, dim3(8), dim3(2 * G3), 0, stream,
                       flag, questions, gx, whf, bh_f, bh_b, qemb);
    hipLaunchKernelGGL(k_scan, dim3(1), dim3(1024), 0, stream, deg, offs, cur);
    hipLaunchKernelGGL(k_scatter, dim3((NEDGES + 255) / 256), dim3(256), 0, stream,
                       flag, edge_src, edge_dst, edge_type, w_comp, cur, ssrc, sco);
    hipLaunchKernelGGL(k_qg, dim3(1), dim3(256), 0, stream, flag, qemb, W_hg, b_hg, qg);
    hipLaunchKernelGGL(k_attn1, dim3(NNODES / 4), dim3(256), 0, stream,
                       flag, node_descs, emb_desc, qg, nf);
    hipLaunchKernelGGL(k_hbg, dim3(NB * NNODES / 64), dim3(256), 0, stream,
                       flag, nf, bases, hb);
    hipLaunchKernelGGL(k_agg, dim3(NNODES), dim3(256), 0, stream,
                       flag, hb, offs, ssrc, sco, rgcn_bias, nf);
    hipLaunchKernelGGL(k_attn2a, dim3(1024), dim3(256), 0, stream, nf, qg, l2, gmx);
    hipLaunchKernelGGL(k_attn2b, dim3(1024), dim3(256), 0, stream, nf, l2, gmx, Z, nar);
    hipLaunchKernelGGL(k_fc1, dim3(NB * 16), dim3(256), 0, stream,
                       flag, nar, Z, qemb, W1, b1, hid);
    hipLaunchKernelGGL(k_fc2, dim3(NB * 32), dim3(256), 0, stream,
                       flag, hid, W2, b2, d_out);
}

// Round 6
// 467.735 us; speedup vs baseline: 1.5628x; 1.1104x over previous
//
#include <hip/hip_runtime.h>
#include <hip/hip_bf16.h>
#include <math.h>

typedef __hip_bfloat16 bf16;

#define NNODES 20000
#define NEDGES 320000
#define DLEN   16
#define G      64
#define DW     300
#define DH     256
#define HD     128
#define G3     384
#define NCLS   2000
#define NB     4
#define TT     32
#define A2BLK  256   // attn2 partial blocks

__device__ __forceinline__ float ld(const float* p, size_t i) { return p[i]; }
__device__ __forceinline__ float ld(const bf16* p, size_t i) { return __bfloat162float(p[i]); }
__device__ __forceinline__ void st(float* p, size_t i, float v) { p[i] = v; }
__device__ __forceinline__ void st(bf16* p, size_t i, float v) { p[i] = __float2bfloat16(v); }
__device__ __forceinline__ float relu(float x) { return (x < 0.f) ? 0.f : x; }

// ---------------- workspace layout (float words) ----------------
#define OFF_FLAG  ((size_t)0)                         // 4
#define OFF_GX    (OFF_FLAG + 4)                      // 98304
#define OFF_WHF   (OFF_GX   + 2*NB*TT*G3)             // 98304
#define OFF_QEMB  (OFF_WHF  + 2*HD*G3)                // 1024
#define OFF_QG    (OFF_QEMB + NB*DH)                  // 256
#define OFF_NF    (OFF_QG   + NB*G)                   // 5,120,000
#define OFF_HB    (OFF_NF   + (size_t)NB*NNODES*G)    // 5,120,000
#define OFF_PART  (OFF_HB   + (size_t)NB*NNODES*G)    // 256*4*66 = 67584
#define OFF_DEG   (OFF_PART + (size_t)A2BLK*NB*66)    // int 20000
#define OFF_OFFS  (OFF_DEG  + NNODES)                 // int 20008
#define OFF_CUR   (OFF_OFFS + NNODES + 8)             // int 20000
#define OFF_SSRC  (OFF_CUR  + NNODES)                 // int 320000
#define OFF_SCO   (OFF_SSRC + NEDGES)                 // float 320000
#define OFF_Z     (OFF_SCO  + NEDGES)                 // 4
#define OFF_NAR   (OFF_Z    + 4)                      // 256
#define OFF_HID   (OFF_NAR  + NB*G)                   // 4096

// ---------------- init: dtype sniff + zero deg ----------------
__global__ void k_init(const unsigned* probe, int* flag, int* deg) {
    int i = blockIdx.x * 256 + threadIdx.x;
    if (i < NNODES) deg[i] = 0;
    if (blockIdx.x == 0 && threadIdx.x < 64) {
        int cnt = 0;
        for (int k = threadIdx.x; k < 4096; k += 64) {
            unsigned lo = probe[k] & 0xFFFFu;
            unsigned e = (lo >> 7) & 0xFFu;
            cnt += (e >= 0x66u && e <= 0x7Eu) ? 1 : 0;
        }
#pragma unroll
        for (int off = 1; off < 64; off <<= 1) cnt += __shfl_xor(cnt, off, 64);
        if (threadIdx.x == 0) *flag = (2 * cnt > 4096) ? 1 : 0;   // 1 = bf16
    }
}

// ---------------- convert Wh to fp32 in ws ----------------
template <typename T>
__device__ void cvt_body(const void* Whf_, const void* Whb_, float* whf) {
    int id = blockIdx.x * 256 + threadIdx.x;
    if (id >= 2 * HD * G3) return;
    int d = id / (HD * G3), r = id % (HD * G3);
    const T* W = (const T*)(d ? Whb_ : Whf_);
    whf[id] = ld(W, (size_t)r);
}
__global__ void k_cvt(const int* flag, const void* Whf, const void* Whb, float* whf) {
    if (*flag) cvt_body<bf16>(Whf, Whb, whf);
    else       cvt_body<float>(Whf, Whb, whf);
}

// ---------------- gx = x @ Wx + bx ----------------
template <typename T>
__device__ void gx_body(const int* questions, const void* emb_word_,
                        const void* Wxf_, const void* bxf_,
                        const void* Wxb_, const void* bxb_, float* gx) {
    int id = blockIdx.x * 256 + threadIdx.x;
    int j = id % G3;
    int step = (id / G3) % TT;
    int b = (id / (G3 * TT)) % NB;
    int d = id / (G3 * TT * NB);
    int t = d ? (TT - 1 - step) : step;
    int tok = questions[b * TT + t];
    const T* Wx = (const T*)(d ? Wxb_ : Wxf_);
    const T* bx = (const T*)(d ? bxb_ : bxf_);
    const T* row = (const T*)emb_word_ + (size_t)tok * DW;
    float acc = ld(bx, (size_t)j);
#pragma unroll 4
    for (int k = 0; k < DW; k++) acc += ld(row, (size_t)k) * ld(Wx, (size_t)k * G3 + j);
    gx[id] = acc;
}
__global__ void k_gx(const int* flag, const int* questions, const void* emb_word,
                     const void* Wxf, const void* bxf,
                     const void* Wxb, const void* bxb, float* gx) {
    if (*flag) gx_body<bf16>(questions, emb_word, Wxf, bxf, Wxb, bxb, gx);
    else       gx_body<float>(questions, emb_word, Wxf, bxf, Wxb, bxb, gx);
}

// ---------------- GRU scan: block per (d,b), Wh register-resident ----------
template <typename T>
__device__ void gru_body(const int* questions, const float* gx, const float* whf,
                         const void* bhf_, const void* bhb_, float* qemb,
                         float* hsm, float* ghs) {
    int tid = threadIdx.x;
    int d = blockIdx.x >> 2, b = blockIdx.x & 3;
    int half = tid / G3, j = tid - half * G3;
    const float* wh = whf + (size_t)d * HD * G3 + (size_t)half * 64 * G3 + j;
    float w[64];
#pragma unroll
    for (int m = 0; m < 64; m++) w[m] = wh[(size_t)m * G3];
    const T* bh = (const T*)(d ? bhb_ : bhf_);
    float bhj = (half == 0) ? ld(bh, (size_t)j) : 0.f;
    if (tid < HD) hsm[tid] = 0.f;
    const float* gxb = gx + ((size_t)(d * NB + b)) * TT * G3;
    __syncthreads();
    const float4* h4 = (const float4*)(hsm + half * 64);
    for (int step = 0; step < TT; step++) {
        float acc = bhj;
#pragma unroll
        for (int m4 = 0; m4 < 16; m4++) {
            float4 hp = h4[m4];
            acc = fmaf(hp.x, w[4 * m4 + 0], acc);
            acc = fmaf(hp.y, w[4 * m4 + 1], acc);
            acc = fmaf(hp.z, w[4 * m4 + 2], acc);
            acc = fmaf(hp.w, w[4 * m4 + 3], acc);
        }
        ghs[half * G3 + j] = acc;
        __syncthreads();
        if (tid < HD) {
            const float* gxp = gxb + step * G3;
            int t = d ? (TT - 1 - step) : step;
            bool msk = questions[b * TT + t] != 0;
            float gr = ghs[tid] + ghs[G3 + tid];
            float gz = ghs[HD + tid] + ghs[G3 + HD + tid];
            float gn = ghs[2 * HD + tid] + ghs[G3 + 2 * HD + tid];
            float r = 1.f / (1.f + expf(-(gxp[tid] + gr)));
            float z = 1.f / (1.f + expf(-(gxp[HD + tid] + gz)));
            float n = tanhf(gxp[2 * HD + tid] + r * gn);
            float hn = (1.f - z) * n + z * hsm[tid];
            if (msk) hsm[tid] = hn;
        }
        __syncthreads();
    }
    if (tid < HD) qemb[b * DH + d * HD + tid] = hsm[tid];
}
__global__ __launch_bounds__(2 * G3) void k_gru(const int* flag, const int* questions,
                                                const float* gx, const float* whf,
                                                const void* bhf, const void* bhb, float* qemb) {
    __shared__ __align__(16) float hsm[HD];
    __shared__ float ghs[2 * G3];
    if (*flag) gru_body<bf16>(questions, gx, whf, bhf, bhb, qemb, hsm, ghs);
    else       gru_body<float>(questions, gx, whf, bhf, bhb, qemb, hsm, ghs);
}

// ---------------- q_g = q_emb @ W_hg + b_hg ----------------
template <typename T>
__device__ void qg_body(const float* qemb, const void* W_hg_, const void* b_hg_, float* qg) {
    int tid = threadIdx.x;
    int b = tid >> 6, g = tid & 63;
    const T* W = (const T*)W_hg_;
    float acc = ld((const T*)b_hg_, (size_t)g);
#pragma unroll 4
    for (int i = 0; i < DH; i++) acc += qemb[b * DH + i] * ld(W, (size_t)i * G + g);
    qg[b * G + g] = acc;
}
__global__ void k_qg(const int* flag, const float* qemb, const void* W_hg,
                     const void* b_hg, float* qg) {
    if (*flag) qg_body<bf16>(qemb, W_hg, b_hg, qg);
    else       qg_body<float>(qemb, W_hg, b_hg, qg);
}

// ---------------- attn1 softmax + node features: one wave per node ----------
template <typename T>
__device__ void attn1_body(const int* node_descs, const void* emb_desc_,
                           const float* qg, float* nf,
                           float* dsm, float* attn_s, float* qgs) {
    int tid = threadIdx.x;
    if (tid < NB * G) qgs[tid] = qg[tid];
    __syncthreads();
    const T* emb_desc = (const T*)emb_desc_;
    int w = tid >> 6, lane = tid & 63;
    int n = blockIdx.x * 4 + w;
    float dreg[DLEN];
    const int* nd = node_descs + n * DLEN;
    float* dw = dsm + (size_t)w * DLEN * (G + 1);
#pragma unroll
    for (int l = 0; l < DLEN; l++) {
        int idx = nd[l];
        float v = ld(emb_desc, (size_t)idx * G + lane);
        dreg[l] = v;
        dw[l * (G + 1) + lane] = v;
    }
    int lb = lane >> 4, ll = lane & 15;
    float acc = 0.f;
#pragma unroll 8
    for (int g = 0; g < G; g++) acc += dw[ll * (G + 1) + g] * qgs[lb * G + g];
    float mx = acc;
#pragma unroll
    for (int off = 1; off < 16; off <<= 1) mx = fmaxf(mx, __shfl_xor(mx, off, 64));
    float e = expf(acc - mx);
    float s = e;
#pragma unroll
    for (int off = 1; off < 16; off <<= 1) s += __shfl_xor(s, off, 64);
    attn_s[w * 64 + lane] = e / s;
#pragma unroll
    for (int b = 0; b < NB; b++) {
        float a = 0.f;
#pragma unroll
        for (int l = 0; l < DLEN; l++) a += attn_s[w * 64 + b * 16 + l] * dreg[l];
        nf[((size_t)b * NNODES + n) * G + lane] = a;
    }
}
__global__ __launch_bounds__(256) void k_attn1(const int* flag, const int* node_descs,
                                               const void* emb_desc, const float* qg, float* nf) {
    __shared__ float dsm[4 * DLEN * (G + 1)];
    __shared__ float attn_s[4 * 64];
    __shared__ float qgs[NB * G];
    if (*flag) attn1_body<bf16>(node_descs, emb_desc, qg, nf, dsm, attn_s, qgs);
    else       attn1_body<float>(node_descs, emb_desc, qg, nf, dsm, attn_s, qgs);
}

// ---------------- hb = nf @ bases[0] : tiled register GEMM ----------------
template <typename T>
__device__ void hbg_body(const float* nf, const void* bases_, float* hb,
                         float* as, float* bs) {
    int tid = threadIdx.x;
    const T* bases = (const T*)bases_;
    for (int i = tid; i < G * G; i += 256) bs[(i >> 6) * 68 + (i & 63)] = ld(bases, (size_t)i);
    size_t r0 = (size_t)blockIdx.x * 64;
    const float4* gA = (const float4*)(nf + r0 * G);
#pragma unroll
    for (int i = 0; i < 4; i++) {
        int c = tid + i * 256;
        int row = c >> 4, col4 = c & 15;
        float4 v = gA[c];
        *(float4*)&as[row * 68 + col4 * 4] = v;
    }
    __syncthreads();
    int tx = tid & 15, ty = tid >> 4;
    float acc[4][4];
#pragma unroll
    for (int i = 0; i < 4; i++)
#pragma unroll
        for (int j = 0; j < 4; j++) acc[i][j] = 0.f;
#pragma unroll 4
    for (int g4 = 0; g4 < 16; g4++) {
        float4 b0 = *(const float4*)&bs[(4 * g4 + 0) * 68 + tx * 4];
        float4 b1 = *(const float4*)&bs[(4 * g4 + 1) * 68 + tx * 4];
        float4 b2 = *(const float4*)&bs[(4 * g4 + 2) * 68 + tx * 4];
        float4 b3 = *(const float4*)&bs[(4 * g4 + 3) * 68 + tx * 4];
#pragma unroll
        for (int i = 0; i < 4; i++) {
            float4 a = *(const float4*)&as[(ty * 4 + i) * 68 + g4 * 4];
            acc[i][0] = fmaf(a.x, b0.x, acc[i][0]);
            acc[i][0] = fmaf(a.y, b1.x, acc[i][0]);
            acc[i][0] = fmaf(a.z, b2.x, acc[i][0]);
            acc[i][0] = fmaf(a.w, b3.x, acc[i][0]);
            acc[i][1] = fmaf(a.x, b0.y, acc[i][1]);
            acc[i][1] = fmaf(a.y, b1.y, acc[i][1]);
            acc[i][1] = fmaf(a.z, b2.y, acc[i][1]);
            acc[i][1] = fmaf(a.w, b3.y, acc[i][1]);
            acc[i][2] = fmaf(a.x, b0.z, acc[i][2]);
            acc[i][2] = fmaf(a.y, b1.z, acc[i][2]);
            acc[i][2] = fmaf(a.z, b2.z, acc[i][2]);
            acc[i][2] = fmaf(a.w, b3.z, acc[i][2]);
            acc[i][3] = fmaf(a.x, b0.w, acc[i][3]);
            acc[i][3] = fmaf(a.y, b1.w, acc[i][3]);
            acc[i][3] = fmaf(a.z, b2.w, acc[i][3]);
            acc[i][3] = fmaf(a.w, b3.w, acc[i][3]);
        }
    }
#pragma unroll
    for (int i = 0; i < 4; i++) {
        float4 o;
        o.x = acc[i][0]; o.y = acc[i][1]; o.z = acc[i][2]; o.w = acc[i][3];
        *(float4*)&hb[(r0 + ty * 4 + i) * G + tx * 4] = o;
    }
}
__global__ __launch_bounds__(256) void k_hbg(const int* flag, const float* nf,
                                             const void* bases, float* hb) {
    __shared__ __align__(16) float as[64 * 68];
    __shared__ __align__(16) float bs[64 * 68];
    if (*flag) hbg_body<bf16>(nf, bases, hb, as, bs);
    else       hbg_body<float>(nf, bases, hb, as, bs);
}

// ---------------- CSR build: histogram, scan, scatter ----------------
__global__ void k_hist(const int* dst, int* deg) {
    int e = blockIdx.x * 256 + threadIdx.x;
    if (e < NEDGES) atomicAdd(&deg[dst[e]], 1);
}

__global__ __launch_bounds__(1024) void k_scan(const int* deg, int* offs, int* cur) {
    __shared__ int tot[1024];
    int t = threadIdx.x;
    int c[20];
    int base = t * 20;
    int run = 0;
#pragma unroll
    for (int i = 0; i < 20; i++) {
        int v = (base + i < NNODES) ? deg[base + i] : 0;
        c[i] = run;
        run += v;
    }
    tot[t] = run;
    __syncthreads();
    for (int off = 1; off < 1024; off <<= 1) {
        int v = (t >= off) ? tot[t - off] : 0;
        __syncthreads();
        tot[t] += v;
        __syncthreads();
    }
    int ebase = tot[t] - run;
#pragma unroll
    for (int i = 0; i < 20; i++) {
        if (base + i < NNODES) {
            offs[base + i] = ebase + c[i];
            cur[base + i] = ebase + c[i];
        }
    }
    if (t == 1023) offs[NNODES] = tot[1023];
}

template <typename T>
__device__ void scatter_body(const int* src, const int* dst, const int* typ,
                             const void* w_comp_, int* cur, int* ssrc, float* sco) {
    int e = blockIdx.x * 256 + threadIdx.x;
    if (e < NEDGES) {
        int dd = dst[e];
        int pos = atomicAdd(&cur[dd], 1);
        ssrc[pos] = src[e];
        sco[pos] = ld((const T*)w_comp_, (size_t)typ[e]);
    }
}
__global__ void k_scatter(const int* flag, const int* src, const int* dst, const int* typ,
                          const void* w_comp, int* cur, int* ssrc, float* sco) {
    if (*flag) scatter_body<bf16>(src, dst, typ, w_comp, cur, ssrc, sco);
    else       scatter_body<float>(src, dst, typ, w_comp, cur, ssrc, sco);
}

// ---------------- RGCN aggregate (gather over CSR) + bias + relu -----------
template <typename T>
__device__ void agg_body(const float* hb, const int* offs, const int* ssrc,
                         const float* sco, const void* bias_, float* out_nf) {
    int tid = threadIdx.x;
    int b = tid >> 6, g = tid & 63;
    int dn = blockIdx.x;
    int s0 = offs[dn], s1 = offs[dn + 1];
    const float* hbb = hb + (size_t)b * NNODES * G;
    float acc = 0.f;
    int p = s0;
    for (; p + 3 < s1; p += 4) {
        int i0 = ssrc[p], i1 = ssrc[p + 1], i2 = ssrc[p + 2], i3 = ssrc[p + 3];
        float c0 = sco[p], c1 = sco[p + 1], c2 = sco[p + 2], c3 = sco[p + 3];
        float x0 = hbb[(size_t)i0 * G + g];
        float x1 = hbb[(size_t)i1 * G + g];
        float x2 = hbb[(size_t)i2 * G + g];
        float x3 = hbb[(size_t)i3 * G + g];
        acc += c0 * x0;
        acc += c1 * x1;
        acc += c2 * x2;
        acc += c3 * x3;
    }
    for (; p < s1; p++) acc += sco[p] * hbb[(size_t)ssrc[p] * G + g];
    out_nf[((size_t)b * NNODES + dn) * G + g] = relu(acc + ld((const T*)bias_, (size_t)g));
}
__global__ __launch_bounds__(256) void k_agg(const int* flag, const float* hb, const int* offs,
                                             const int* ssrc, const float* sco,
                                             const void* bias, float* out_nf) {
    if (*flag) agg_body<bf16>(hb, offs, ssrc, sco, bias, out_nf);
    else       agg_body<float>(hb, offs, ssrc, sco, bias, out_nf);
}

// ---------------- attn2: single-pass online softmax, NO atomics ------------
// 256 blocks x 256 thr; wave = batch b, lane = feature g. Each block scans a
// contiguous node chunk keeping running (m, l, acc[64]); writes a 66-float
// partial per (block,b). Partials merged by k_attn2m (1 block).
__global__ __launch_bounds__(256) void k_attn2(const float* rg, const float* qg, float* part) {
    int tid = threadIdx.x;
    int b = tid >> 6, lane = tid & 63;
    float q = qg[b * G + lane];
    int chunk = (NNODES + A2BLK - 1) / A2BLK;
    int n0 = blockIdx.x * chunk;
    int n1 = min(n0 + chunk, NNODES);
    float M = -3.4e38f, L = 0.f, A = 0.f;
    for (int n = n0; n < n1; n++) {
        float v = rg[((size_t)b * NNODES + n) * G + lane];
        float p = v * q;
#pragma unroll
        for (int off = 32; off >= 1; off >>= 1) p += __shfl_xor(p, off, 64);
        if (p > M) {
            float s = expf(M - p);
            A *= s; L *= s; M = p;
        }
        float e = expf(p - M);
        L += e;
        A = fmaf(e, v, A);
    }
    float* pp = part + ((size_t)blockIdx.x * NB + b) * 66;
    if (lane == 0) { pp[0] = M; pp[1] = L; }
    pp[2 + lane] = A;
}

__global__ void k_attn2m(const float* part, float* nar, float* Z) {
    int tid = threadIdx.x;   // 256
    int b = tid >> 6, lane = tid & 63;
    float M = -3.4e38f, L = 0.f, A = 0.f;
    for (int p = 0; p < A2BLK; p++) {
        const float* pp = part + ((size_t)p * NB + b) * 66;
        float m = pp[0], l = pp[1], a = pp[2 + lane];
        float mn = fmaxf(M, m);
        float e1 = expf(M - mn), e2 = expf(m - mn);
        A = A * e1 + a * e2;
        L = L * e1 + l * e2;
        M = mn;
    }
    nar[b * G + lane] = A;
    if (lane == 0) Z[b] = L;
}

// ---------------- classifier: fc1, parallel k-reduction ----------------
template <typename T>
__device__ void fc1_body(const float* nar, const float* Z, const float* qemb,
                         const void* W1_, const void* b1_, float* hid,
                         float* feat, float* psum) {
    int tid = threadIdx.x;
    int b = blockIdx.x >> 4, tile = blockIdx.x & 15;
    for (int i = tid; i < 320; i += 256) {
        feat[i] = (i < G) ? nar[b * G + i] / Z[b] : qemb[b * DH + i - G];
    }
    __syncthreads();
    int lane = tid & 63, phase = tid >> 6;
    int u = tile * 64 + lane;
    const T* W1 = (const T*)W1_;
    float acc = 0.f;
#pragma unroll 8
    for (int kk = 0; kk < 80; kk++) {
        int k = phase * 80 + kk;
        acc += feat[k] * ld(W1, (size_t)k * 1024 + u);
    }
    psum[tid] = acc;
    __syncthreads();
    if (phase == 0) {
        float tot = psum[lane] + psum[64 + lane] + psum[128 + lane] + psum[192 + lane]
                  + ld((const T*)b1_, (size_t)u);
        hid[b * 1024 + u] = relu(tot);
    }
}
__global__ __launch_bounds__(256) void k_fc1(const int* flag, const float* nar, const float* Z,
                                             const float* qemb, const void* W1, const void* b1,
                                             float* hid) {
    __shared__ float feat[320];
    __shared__ float psum[256];
    if (*flag) fc1_body<bf16>(nar, Z, qemb, W1, b1, hid, feat, psum);
    else       fc1_body<float>(nar, Z, qemb, W1, b1, hid, feat, psum);
}

// ---------------- classifier: fc2, parallel k-reduction ----------------
template <typename T>
__device__ void fc2_body(const float* hid, const void* W2_, const void* b2_, void* out_,
                         float* hs, float* psum) {
    int tid = threadIdx.x;
    int b = blockIdx.x >> 5, tile = blockIdx.x & 31;
#pragma unroll
    for (int i = 0; i < 4; i++) hs[tid + 256 * i] = hid[b * 1024 + tid + 256 * i];
    __syncthreads();
    int lane = tid & 63, phase = tid >> 6;
    int c = tile * 64 + lane;
    bool ok = (c < NCLS);
    const T* W2 = (const T*)W2_;
    float acc = 0.f;
    if (ok) {
#pragma unroll 8
        for (int uu = 0; uu < 256; uu++) {
            int u = phase * 256 + uu;
            acc += hs[u] * ld(W2, (size_t)u * NCLS + c);
        }
    }
    psum[tid] = acc;
    __syncthreads();
    if (phase == 0 && ok) {
        float tot = psum[lane] + psum[64 + lane] + psum[128 + lane] + psum[192 + lane]
                  + ld((const T*)b2_, (size_t)c);
        st((T*)out_, (size_t)b * NCLS + c, tot);
    }
}
__global__ __launch_bounds__(256) void k_fc2(const int* flag, const float* hid,
                                             const void* W2, const void* b2v, void* out) {
    __shared__ float hs[1024];
    __shared__ float psum[256];
    if (*flag) fc2_body<bf16>(hid, W2, b2v, out, hs, psum);
    else       fc2_body<float>(hid, W2, b2v, out, hs, psum);
}

extern "C" void kernel_launch(void* const* d_in, const int* in_sizes, int n_in,
                              void* d_out, int out_size, void* d_ws, size_t ws_size,
                              hipStream_t stream) {
    const int* questions  = (const int*)d_in[0];
    const int* node_descs = (const int*)d_in[1];
    const int* edge_src   = (const int*)d_in[2];
    const int* edge_dst   = (const int*)d_in[3];
    const int* edge_type  = (const int*)d_in[4];
    const void* emb_word  = d_in[5];
    const void* emb_desc  = d_in[6];
    const void* Wx_f = d_in[7];
    const void* Wh_f = d_in[8];
    const void* bx_f = d_in[9];
    const void* bh_f = d_in[10];
    const void* Wx_b = d_in[11];
    const void* Wh_b = d_in[12];
    const void* bx_b = d_in[13];
    const void* bh_b = d_in[14];
    const void* W_hg = d_in[15];
    const void* b_hg = d_in[16];
    const void* bases = d_in[17];
    const void* w_comp = d_in[18];
    const void* rgcn_bias = d_in[19];
    const void* W1 = d_in[20];
    const void* b1 = d_in[21];
    const void* W2 = d_in[22];
    const void* b2 = d_in[23];

    float* ws = (float*)d_ws;
    int*      flag = (int*)(ws + OFF_FLAG);
    float*    gx   = ws + OFF_GX;
    float*    whf  = ws + OFF_WHF;
    float*    qemb = ws + OFF_QEMB;
    float*    qg   = ws + OFF_QG;
    float*    nf   = ws + OFF_NF;
    float*    hb   = ws + OFF_HB;
    float*    part = ws + OFF_PART;
    int*      deg  = (int*)(ws + OFF_DEG);
    int*      offs = (int*)(ws + OFF_OFFS);
    int*      cur  = (int*)(ws + OFF_CUR);
    int*      ssrc = (int*)(ws + OFF_SSRC);
    float*    sco  = ws + OFF_SCO;
    float*    Z    = ws + OFF_Z;
    float*    nar  = ws + OFF_NAR;
    float*    hid  = ws + OFF_HID;

    hipLaunchKernelGGL(k_init, dim3(80), dim3(256), 0, stream,
                       (const unsigned*)emb_word, flag, deg);
    hipLaunchKernelGGL(k_hist, dim3((NEDGES + 255) / 256), dim3(256), 0, stream, edge_dst, deg);
    hipLaunchKernelGGL(k_cvt, dim3((2 * HD * G3 + 255) / 256), dim3(256), 0, stream,
                       flag, Wh_f, Wh_b, whf);
    hipLaunchKernelGGL(k_gx, dim3(2 * NB * TT * G3 / 256), dim3(256), 0, stream,
                       flag, questions, emb_word, Wx_f, bx_f, Wx_b, bx_b, gx);
    hipLaunchKernelGGL(k_gru, dim3(8), dim3(2 * G3), 0, stream,
                       flag, questions, gx, whf, bh_f, bh_b, qemb);
    hipLaunchKernelGGL(k_scan, dim3(1), dim3(1024), 0, stream, deg, offs, cur);
    hipLaunchKernelGGL(k_scatter, dim3((NEDGES + 255) / 256), dim3(256), 0, stream,
                       flag, edge_src, edge_dst, edge_type, w_comp, cur, ssrc, sco);
    hipLaunchKernelGGL(k_qg, dim3(1), dim3(256), 0, stream, flag, qemb, W_hg, b_hg, qg);
    hipLaunchKernelGGL(k_attn1, dim3(NNODES / 4), dim3(256), 0, stream,
                       flag, node_descs, emb_desc, qg, nf);
    hipLaunchKernelGGL(k_hbg, dim3(NB * NNODES / 64), dim3(256), 0, stream,
                       flag, nf, bases, hb);
    hipLaunchKernelGGL(k_agg, dim3(NNODES), dim3(256), 0, stream,
                       flag, hb, offs, ssrc, sco, rgcn_bias, nf);
    hipLaunchKernelGGL(k_attn2, dim3(A2BLK), dim3(256), 0, stream, nf, qg, part);
    hipLaunchKernelGGL(k_attn2m, dim3(1), dim3(256), 0, stream, part, nar, Z);
    hipLaunchKernelGGL(k_fc1, dim3(NB * 16), dim3(256), 0, stream,
                       flag, nar, Z, qemb, W1, b1, hid);
    hipLaunchKernelGGL(k_fc2, dim3(NB * 32), dim3(256), 0, stream,
                       flag, hid, W2, b2, d_out);
}

// Round 7
// 446.676 us; speedup vs baseline: 1.6365x; 1.0471x over previous
//
#include <hip/hip_runtime.h>
#include <hip/hip_bf16.h>
#include <math.h>

typedef __hip_bfloat16 bf16;

#define NNODES 20000
#define NEDGES 320000
#define DLEN   16
#define G      64
#define DW     300
#define DH     256
#define HD     128
#define G3     384
#define NCLS   2000
#define NB     4
#define TT     32
#define A2BLK  256   // attn2 partial blocks

__device__ __forceinline__ float ld(const float* p, size_t i) { return p[i]; }
__device__ __forceinline__ float ld(const bf16* p, size_t i) { return __bfloat162float(p[i]); }
__device__ __forceinline__ void st(float* p, size_t i, float v) { p[i] = v; }
__device__ __forceinline__ void st(bf16* p, size_t i, float v) { p[i] = __float2bfloat16(v); }
__device__ __forceinline__ float relu(float x) { return (x < 0.f) ? 0.f : x; }

struct __align__(8) bf4 { bf16 x, y, z, w; };

// ---------------- workspace layout (float words) ----------------
#define OFF_FLAG  ((size_t)0)                         // 4
#define OFF_GX    (OFF_FLAG + 4)                      // 98304
#define OFF_WHF   (OFF_GX   + 2*NB*TT*G3)             // 98304
#define OFF_QEMB  (OFF_WHF  + 2*HD*G3)                // 1024
#define OFF_QG    (OFF_QEMB + NB*DH)                  // 256
#define OFF_NF    (OFF_QG   + NB*G)                   // 5,120,000
#define OFF_HB    (OFF_NF   + (size_t)NB*NNODES*G)    // bf16 [n][b][g]: 5.12M ushorts
#define OFF_PART  (OFF_HB   + (size_t)NB*NNODES*G)    // 256*4*66 = 67584
#define OFF_DEG   (OFF_PART + (size_t)A2BLK*NB*66)    // int 20000
#define OFF_OFFS  (OFF_DEG  + NNODES)                 // int 20008
#define OFF_CUR   (OFF_OFFS + NNODES + 8)             // int 20000
#define OFF_SSRC  (OFF_CUR  + NNODES)                 // int 320000
#define OFF_SCO   (OFF_SSRC + NEDGES)                 // float 320000
#define OFF_Z     (OFF_SCO  + NEDGES)                 // 4
#define OFF_NAR   (OFF_Z    + 4)                      // 256
#define OFF_HID   (OFF_NAR  + NB*G)                   // 4096

// ---------------- init: dtype sniff + zero deg ----------------
__global__ void k_init(const unsigned* probe, int* flag, int* deg) {
    int i = blockIdx.x * 256 + threadIdx.x;
    if (i < NNODES) deg[i] = 0;
    if (blockIdx.x == 0 && threadIdx.x < 64) {
        int cnt = 0;
        for (int k = threadIdx.x; k < 4096; k += 64) {
            unsigned lo = probe[k] & 0xFFFFu;
            unsigned e = (lo >> 7) & 0xFFu;
            cnt += (e >= 0x66u && e <= 0x7Eu) ? 1 : 0;
        }
#pragma unroll
        for (int off = 1; off < 64; off <<= 1) cnt += __shfl_xor(cnt, off, 64);
        if (threadIdx.x == 0) *flag = (2 * cnt > 4096) ? 1 : 0;   // 1 = bf16
    }
}

// ---------------- convert Wh to fp32 in ws ----------------
template <typename T>
__device__ void cvt_body(const void* Whf_, const void* Whb_, float* whf) {
    int id = blockIdx.x * 256 + threadIdx.x;
    if (id >= 2 * HD * G3) return;
    int d = id / (HD * G3), r = id % (HD * G3);
    const T* W = (const T*)(d ? Whb_ : Whf_);
    whf[id] = ld(W, (size_t)r);
}
__global__ void k_cvt(const int* flag, const void* Whf, const void* Whb, float* whf) {
    if (*flag) cvt_body<bf16>(Whf, Whb, whf);
    else       cvt_body<float>(Whf, Whb, whf);
}

// ---------------- gx = x @ Wx + bx ----------------
template <typename T>
__device__ void gx_body(const int* questions, const void* emb_word_,
                        const void* Wxf_, const void* bxf_,
                        const void* Wxb_, const void* bxb_, float* gx) {
    int id = blockIdx.x * 256 + threadIdx.x;
    int j = id % G3;
    int step = (id / G3) % TT;
    int b = (id / (G3 * TT)) % NB;
    int d = id / (G3 * TT * NB);
    int t = d ? (TT - 1 - step) : step;
    int tok = questions[b * TT + t];
    const T* Wx = (const T*)(d ? Wxb_ : Wxf_);
    const T* bx = (const T*)(d ? bxb_ : bxf_);
    const T* row = (const T*)emb_word_ + (size_t)tok * DW;
    float acc = ld(bx, (size_t)j);
#pragma unroll 4
    for (int k = 0; k < DW; k++) acc += ld(row, (size_t)k) * ld(Wx, (size_t)k * G3 + j);
    gx[id] = acc;
}
__global__ void k_gx(const int* flag, const int* questions, const void* emb_word,
                     const void* Wxf, const void* bxf,
                     const void* Wxb, const void* bxb, float* gx) {
    if (*flag) gx_body<bf16>(questions, emb_word, Wxf, bxf, Wxb, bxb, gx);
    else       gx_body<float>(questions, emb_word, Wxf, bxf, Wxb, bxb, gx);
}

// ---------------- GRU scan: block per (d,b), Wh register-resident ----------
template <typename T>
__device__ void gru_body(const int* questions, const float* gx, const float* whf,
                         const void* bhf_, const void* bhb_, float* qemb,
                         float* hsm, float* ghs) {
    int tid = threadIdx.x;
    int d = blockIdx.x >> 2, b = blockIdx.x & 3;
    int half = tid / G3, j = tid - half * G3;
    const float* wh = whf + (size_t)d * HD * G3 + (size_t)half * 64 * G3 + j;
    float w[64];
#pragma unroll
    for (int m = 0; m < 64; m++) w[m] = wh[(size_t)m * G3];
    const T* bh = (const T*)(d ? bhb_ : bhf_);
    float bhj = (half == 0) ? ld(bh, (size_t)j) : 0.f;
    if (tid < HD) hsm[tid] = 0.f;
    const float* gxb = gx + ((size_t)(d * NB + b)) * TT * G3;
    __syncthreads();
    const float4* h4 = (const float4*)(hsm + half * 64);
    for (int step = 0; step < TT; step++) {
        float acc = bhj;
#pragma unroll
        for (int m4 = 0; m4 < 16; m4++) {
            float4 hp = h4[m4];
            acc = fmaf(hp.x, w[4 * m4 + 0], acc);
            acc = fmaf(hp.y, w[4 * m4 + 1], acc);
            acc = fmaf(hp.z, w[4 * m4 + 2], acc);
            acc = fmaf(hp.w, w[4 * m4 + 3], acc);
        }
        ghs[half * G3 + j] = acc;
        __syncthreads();
        if (tid < HD) {
            const float* gxp = gxb + step * G3;
            int t = d ? (TT - 1 - step) : step;
            bool msk = questions[b * TT + t] != 0;
            float gr = ghs[tid] + ghs[G3 + tid];
            float gz = ghs[HD + tid] + ghs[G3 + HD + tid];
            float gn = ghs[2 * HD + tid] + ghs[G3 + 2 * HD + tid];
            float r = 1.f / (1.f + expf(-(gxp[tid] + gr)));
            float z = 1.f / (1.f + expf(-(gxp[HD + tid] + gz)));
            float n = tanhf(gxp[2 * HD + tid] + r * gn);
            float hn = (1.f - z) * n + z * hsm[tid];
            if (msk) hsm[tid] = hn;
        }
        __syncthreads();
    }
    if (tid < HD) qemb[b * DH + d * HD + tid] = hsm[tid];
}
__global__ __launch_bounds__(2 * G3) void k_gru(const int* flag, const int* questions,
                                                const float* gx, const float* whf,
                                                const void* bhf, const void* bhb, float* qemb) {
    __shared__ __align__(16) float hsm[HD];
    __shared__ float ghs[2 * G3];
    if (*flag) gru_body<bf16>(questions, gx, whf, bhf, bhb, qemb, hsm, ghs);
    else       gru_body<float>(questions, gx, whf, bhf, bhb, qemb, hsm, ghs);
}

// ---------------- q_g = q_emb @ W_hg + b_hg ----------------
template <typename T>
__device__ void qg_body(const float* qemb, const void* W_hg_, const void* b_hg_, float* qg) {
    int tid = threadIdx.x;
    int b = tid >> 6, g = tid & 63;
    const T* W = (const T*)W_hg_;
    float acc = ld((const T*)b_hg_, (size_t)g);
#pragma unroll 4
    for (int i = 0; i < DH; i++) acc += qemb[b * DH + i] * ld(W, (size_t)i * G + g);
    qg[b * G + g] = acc;
}
__global__ void k_qg(const int* flag, const float* qemb, const void* W_hg,
                     const void* b_hg, float* qg) {
    if (*flag) qg_body<bf16>(qemb, W_hg, b_hg, qg);
    else       qg_body<float>(qemb, W_hg, b_hg, qg);
}

// ---------------- attn1 softmax + node features: one wave per node ----------
template <typename T>
__device__ void attn1_body(const int* node_descs, const void* emb_desc_,
                           const float* qg, float* nf,
                           float* dsm, float* attn_s, float* qgs) {
    int tid = threadIdx.x;
    if (tid < NB * G) qgs[tid] = qg[tid];
    __syncthreads();
    const T* emb_desc = (const T*)emb_desc_;
    int w = tid >> 6, lane = tid & 63;
    int n = blockIdx.x * 4 + w;
    float dreg[DLEN];
    const int* nd = node_descs + n * DLEN;
    float* dw = dsm + (size_t)w * DLEN * (G + 1);
#pragma unroll
    for (int l = 0; l < DLEN; l++) {
        int idx = nd[l];
        float v = ld(emb_desc, (size_t)idx * G + lane);
        dreg[l] = v;
        dw[l * (G + 1) + lane] = v;
    }
    int lb = lane >> 4, ll = lane & 15;
    float acc = 0.f;
#pragma unroll 8
    for (int g = 0; g < G; g++) acc += dw[ll * (G + 1) + g] * qgs[lb * G + g];
    float mx = acc;
#pragma unroll
    for (int off = 1; off < 16; off <<= 1) mx = fmaxf(mx, __shfl_xor(mx, off, 64));
    float e = expf(acc - mx);
    float s = e;
#pragma unroll
    for (int off = 1; off < 16; off <<= 1) s += __shfl_xor(s, off, 64);
    attn_s[w * 64 + lane] = e / s;
#pragma unroll
    for (int b = 0; b < NB; b++) {
        float a = 0.f;
#pragma unroll
        for (int l = 0; l < DLEN; l++) a += attn_s[w * 64 + b * 16 + l] * dreg[l];
        nf[((size_t)b * NNODES + n) * G + lane] = a;
    }
}
__global__ __launch_bounds__(256) void k_attn1(const int* flag, const int* node_descs,
                                               const void* emb_desc, const float* qg, float* nf) {
    __shared__ float dsm[4 * DLEN * (G + 1)];
    __shared__ float attn_s[4 * 64];
    __shared__ float qgs[NB * G];
    if (*flag) attn1_body<bf16>(node_descs, emb_desc, qg, nf, dsm, attn_s, qgs);
    else       attn1_body<float>(node_descs, emb_desc, qg, nf, dsm, attn_s, qgs);
}

// ---------------- hb = nf @ bases[0] : tiled register GEMM, bf16 out -------
// Output layout: hb16[n][b][g] (bf16) so one edge's 4-batch data is one
// contiguous 512B region for the gather.
template <typename T>
__device__ void hbg_body(const float* nf, const void* bases_, bf16* hb16,
                         float* as, float* bs) {
    int tid = threadIdx.x;
    const T* bases = (const T*)bases_;
    for (int i = tid; i < G * G; i += 256) bs[(i >> 6) * 68 + (i & 63)] = ld(bases, (size_t)i);
    size_t r0 = (size_t)blockIdx.x * 64;
    const float4* gA = (const float4*)(nf + r0 * G);
#pragma unroll
    for (int i = 0; i < 4; i++) {
        int c = tid + i * 256;
        int row = c >> 4, col4 = c & 15;
        float4 v = gA[c];
        *(float4*)&as[row * 68 + col4 * 4] = v;
    }
    __syncthreads();
    int tx = tid & 15, ty = tid >> 4;
    float acc[4][4];
#pragma unroll
    for (int i = 0; i < 4; i++)
#pragma unroll
        for (int j = 0; j < 4; j++) acc[i][j] = 0.f;
#pragma unroll 4
    for (int g4 = 0; g4 < 16; g4++) {
        float4 b0 = *(const float4*)&bs[(4 * g4 + 0) * 68 + tx * 4];
        float4 b1 = *(const float4*)&bs[(4 * g4 + 1) * 68 + tx * 4];
        float4 b2 = *(const float4*)&bs[(4 * g4 + 2) * 68 + tx * 4];
        float4 b3 = *(const float4*)&bs[(4 * g4 + 3) * 68 + tx * 4];
#pragma unroll
        for (int i = 0; i < 4; i++) {
            float4 a = *(const float4*)&as[(ty * 4 + i) * 68 + g4 * 4];
            acc[i][0] = fmaf(a.x, b0.x, acc[i][0]);
            acc[i][0] = fmaf(a.y, b1.x, acc[i][0]);
            acc[i][0] = fmaf(a.z, b2.x, acc[i][0]);
            acc[i][0] = fmaf(a.w, b3.x, acc[i][0]);
            acc[i][1] = fmaf(a.x, b0.y, acc[i][1]);
            acc[i][1] = fmaf(a.y, b1.y, acc[i][1]);
            acc[i][1] = fmaf(a.z, b2.y, acc[i][1]);
            acc[i][1] = fmaf(a.w, b3.y, acc[i][1]);
            acc[i][2] = fmaf(a.x, b0.z, acc[i][2]);
            acc[i][2] = fmaf(a.y, b1.z, acc[i][2]);
            acc[i][2] = fmaf(a.z, b2.z, acc[i][2]);
            acc[i][2] = fmaf(a.w, b3.z, acc[i][2]);
            acc[i][3] = fmaf(a.x, b0.w, acc[i][3]);
            acc[i][3] = fmaf(a.y, b1.w, acc[i][3]);
            acc[i][3] = fmaf(a.z, b2.w, acc[i][3]);
            acc[i][3] = fmaf(a.w, b3.w, acc[i][3]);
        }
    }
#pragma unroll
    for (int i = 0; i < 4; i++) {
        size_t r = r0 + ty * 4 + i;          // flat row in [b*NNODES+n]
        int b = (int)(r / NNODES);
        int n = (int)(r - (size_t)b * NNODES);
        bf4 o;
        o.x = __float2bfloat16(acc[i][0]);
        o.y = __float2bfloat16(acc[i][1]);
        o.z = __float2bfloat16(acc[i][2]);
        o.w = __float2bfloat16(acc[i][3]);
        *(bf4*)&hb16[((size_t)n * NB + b) * G + tx * 4] = o;
    }
}
__global__ __launch_bounds__(256) void k_hbg(const int* flag, const float* nf,
                                             const void* bases, bf16* hb16) {
    __shared__ __align__(16) float as[64 * 68];
    __shared__ __align__(16) float bs[64 * 68];
    if (*flag) hbg_body<bf16>(nf, bases, hb16, as, bs);
    else       hbg_body<float>(nf, bases, hb16, as, bs);
}

// ---------------- CSR build: histogram, scan, scatter ----------------
__global__ void k_hist(const int* dst, int* deg) {
    int e = blockIdx.x * 256 + threadIdx.x;
    if (e < NEDGES) atomicAdd(&deg[dst[e]], 1);
}

__global__ __launch_bounds__(1024) void k_scan(const int* deg, int* offs, int* cur) {
    __shared__ int tot[1024];
    int t = threadIdx.x;
    int c[20];
    int base = t * 20;
    int run = 0;
#pragma unroll
    for (int i = 0; i < 20; i++) {
        int v = (base + i < NNODES) ? deg[base + i] : 0;
        c[i] = run;
        run += v;
    }
    tot[t] = run;
    __syncthreads();
    for (int off = 1; off < 1024; off <<= 1) {
        int v = (t >= off) ? tot[t - off] : 0;
        __syncthreads();
        tot[t] += v;
        __syncthreads();
    }
    int ebase = tot[t] - run;
#pragma unroll
    for (int i = 0; i < 20; i++) {
        if (base + i < NNODES) {
            offs[base + i] = ebase + c[i];
            cur[base + i] = ebase + c[i];
        }
    }
    if (t == 1023) offs[NNODES] = tot[1023];
}

template <typename T>
__device__ void scatter_body(const int* src, const int* dst, const int* typ,
                             const void* w_comp_, int* cur, int* ssrc, float* sco) {
    int e = blockIdx.x * 256 + threadIdx.x;
    if (e < NEDGES) {
        int dd = dst[e];
        int pos = atomicAdd(&cur[dd], 1);
        ssrc[pos] = src[e];
        sco[pos] = ld((const T*)w_comp_, (size_t)typ[e]);
    }
}
__global__ void k_scatter(const int* flag, const int* src, const int* dst, const int* typ,
                          const void* w_comp, int* cur, int* ssrc, float* sco) {
    if (*flag) scatter_body<bf16>(src, dst, typ, w_comp, cur, ssrc, sco);
    else       scatter_body<float>(src, dst, typ, w_comp, cur, ssrc, sco);
}

// ---------------- RGCN aggregate (gather bf16 over CSR) + bias + relu ------
template <typename T>
__device__ void agg_body(const bf16* hb16, const int* offs, const int* ssrc,
                         const float* sco, const void* bias_, float* out_nf) {
    int tid = threadIdx.x;
    int b = tid >> 6, g = tid & 63;
    int dn = blockIdx.x;
    int s0 = offs[dn], s1 = offs[dn + 1];
    int boff = b * G + g;
    float acc = 0.f;
    int p = s0;
    for (; p + 3 < s1; p += 4) {
        int i0 = ssrc[p], i1 = ssrc[p + 1], i2 = ssrc[p + 2], i3 = ssrc[p + 3];
        float c0 = sco[p], c1 = sco[p + 1], c2 = sco[p + 2], c3 = sco[p + 3];
        float x0 = __bfloat162float(hb16[(size_t)i0 * (NB * G) + boff]);
        float x1 = __bfloat162float(hb16[(size_t)i1 * (NB * G) + boff]);
        float x2 = __bfloat162float(hb16[(size_t)i2 * (NB * G) + boff]);
        float x3 = __bfloat162float(hb16[(size_t)i3 * (NB * G) + boff]);
        acc += c0 * x0;
        acc += c1 * x1;
        acc += c2 * x2;
        acc += c3 * x3;
    }
    for (; p < s1; p++)
        acc += sco[p] * __bfloat162float(hb16[(size_t)ssrc[p] * (NB * G) + boff]);
    out_nf[((size_t)b * NNODES + dn) * G + g] = relu(acc + ld((const T*)bias_, (size_t)g));
}
__global__ __launch_bounds__(256) void k_agg(const int* flag, const bf16* hb16, const int* offs,
                                             const int* ssrc, const float* sco,
                                             const void* bias, float* out_nf) {
    if (*flag) agg_body<bf16>(hb16, offs, ssrc, sco, bias, out_nf);
    else       agg_body<float>(hb16, offs, ssrc, sco, bias, out_nf);
}

// ---------------- attn2: single-pass online softmax, NO atomics ------------
__global__ __launch_bounds__(256) void k_attn2(const float* rg, const float* qg, float* part) {
    int tid = threadIdx.x;
    int b = tid >> 6, lane = tid & 63;
    float q = qg[b * G + lane];
    int chunk = (NNODES + A2BLK - 1) / A2BLK;
    int n0 = blockIdx.x * chunk;
    int n1 = min(n0 + chunk, NNODES);
    float M = -3.4e38f, L = 0.f, A = 0.f;
    for (int n = n0; n < n1; n++) {
        float v = rg[((size_t)b * NNODES + n) * G + lane];
        float p = v * q;
#pragma unroll
        for (int off = 32; off >= 1; off >>= 1) p += __shfl_xor(p, off, 64);
        if (p > M) {
            float s = expf(M - p);
            A *= s; L *= s; M = p;
        }
        float e = expf(p - M);
        L += e;
        A = fmaf(e, v, A);
    }
    float* pp = part + ((size_t)blockIdx.x * NB + b) * 66;
    if (lane == 0) { pp[0] = M; pp[1] = L; }
    pp[2 + lane] = A;
}

__global__ void k_attn2m(const float* part, float* nar, float* Z) {
    int tid = threadIdx.x;   // 256
    int b = tid >> 6, lane = tid & 63;
    float M = -3.4e38f, L = 0.f, A = 0.f;
    for (int p = 0; p < A2BLK; p++) {
        const float* pp = part + ((size_t)p * NB + b) * 66;
        float m = pp[0], l = pp[1], a = pp[2 + lane];
        float mn = fmaxf(M, m);
        float e1 = expf(M - mn), e2 = expf(m - mn);
        A = A * e1 + a * e2;
        L = L * e1 + l * e2;
        M = mn;
    }
    nar[b * G + lane] = A;
    if (lane == 0) Z[b] = L;
}

// ---------------- classifier: fc1, parallel k-reduction ----------------
template <typename T>
__device__ void fc1_body(const float* nar, const float* Z, const float* qemb,
                         const void* W1_, const void* b1_, float* hid,
                         float* feat, float* psum) {
    int tid = threadIdx.x;
    int b = blockIdx.x >> 4, tile = blockIdx.x & 15;
    for (int i = tid; i < 320; i += 256) {
        feat[i] = (i < G) ? nar[b * G + i] / Z[b] : qemb[b * DH + i - G];
    }
    __syncthreads();
    int lane = tid & 63, phase = tid >> 6;
    int u = tile * 64 + lane;
    const T* W1 = (const T*)W1_;
    float acc = 0.f;
#pragma unroll 8
    for (int kk = 0; kk < 80; kk++) {
        int k = phase * 80 + kk;
        acc += feat[k] * ld(W1, (size_t)k * 1024 + u);
    }
    psum[tid] = acc;
    __syncthreads();
    if (phase == 0) {
        float tot = psum[lane] + psum[64 + lane] + psum[128 + lane] + psum[192 + lane]
                  + ld((const T*)b1_, (size_t)u);
        hid[b * 1024 + u] = relu(tot);
    }
}
__global__ __launch_bounds__(256) void k_fc1(const int* flag, const float* nar, const float* Z,
                                             const float* qemb, const void* W1, const void* b1,
                                             float* hid) {
    __shared__ float feat[320];
    __shared__ float psum[256];
    if (*flag) fc1_body<bf16>(nar, Z, qemb, W1, b1, hid, feat, psum);
    else       fc1_body<float>(nar, Z, qemb, W1, b1, hid, feat, psum);
}

// ---------------- classifier: fc2, parallel k-reduction ----------------
template <typename T>
__device__ void fc2_body(const float* hid, const void* W2_, const void* b2_, void* out_,
                         float* hs, float* psum) {
    int tid = threadIdx.x;
    int b = blockIdx.x >> 5, tile = blockIdx.x & 31;
#pragma unroll
    for (int i = 0; i < 4; i++) hs[tid + 256 * i] = hid[b * 1024 + tid + 256 * i];
    __syncthreads();
    int lane = tid & 63, phase = tid >> 6;
    int c = tile * 64 + lane;
    bool ok = (c < NCLS);
    const T* W2 = (const T*)W2_;
    float acc = 0.f;
    if (ok) {
#pragma unroll 8
        for (int uu = 0; uu < 256; uu++) {
            int u = phase * 256 + uu;
            acc += hs[u] * ld(W2, (size_t)u * NCLS + c);
        }
    }
    psum[tid] = acc;
    __syncthreads();
    if (phase == 0 && ok) {
        float tot = psum[lane] + psum[64 + lane] + psum[128 + lane] + psum[192 + lane]
                  + ld((const T*)b2_, (size_t)c);
        st((T*)out_, (size_t)b * NCLS + c, tot);
    }
}
__global__ __launch_bounds__(256) void k_fc2(const int* flag, const float* hid,
                                             const void* W2, const void* b2v, void* out) {
    __shared__ float hs[1024];
    __shared__ float psum[256];
    if (*flag) fc2_body<bf16>(hid, W2, b2v, out, hs, psum);
    else       fc2_body<float>(hid, W2, b2v, out, hs, psum);
}

extern "C" void kernel_launch(void* const* d_in, const int* in_sizes, int n_in,
                              void* d_out, int out_size, void* d_ws, size_t ws_size,
                              hipStream_t stream) {
    const int* questions  = (const int*)d_in[0];
    const int* node_descs = (const int*)d_in[1];
    const int* edge_src   = (const int*)d_in[2];
    const int* edge_dst   = (const int*)d_in[3];
    const int* edge_type  = (const int*)d_in[4];
    const void* emb_word  = d_in[5];
    const void* emb_desc  = d_in[6];
    const void* Wx_f = d_in[7];
    const void* Wh_f = d_in[8];
    const void* bx_f = d_in[9];
    const void* bh_f = d_in[10];
    const void* Wx_b = d_in[11];
    const void* Wh_b = d_in[12];
    const void* bx_b = d_in[13];
    const void* bh_b = d_in[14];
    const void* W_hg = d_in[15];
    const void* b_hg = d_in[16];
    const void* bases = d_in[17];
    const void* w_comp = d_in[18];
    const void* rgcn_bias = d_in[19];
    const void* W1 = d_in[20];
    const void* b1 = d_in[21];
    const void* W2 = d_in[22];
    const void* b2 = d_in[23];

    float* ws = (float*)d_ws;
    int*      flag = (int*)(ws + OFF_FLAG);
    float*    gx   = ws + OFF_GX;
    float*    whf  = ws + OFF_WHF;
    float*    qemb = ws + OFF_QEMB;
    float*    qg   = ws + OFF_QG;
    float*    nf   = ws + OFF_NF;
    bf16*     hb16 = (bf16*)(ws + OFF_HB);
    float*    part = ws + OFF_PART;
    int*      deg  = (int*)(ws + OFF_DEG);
    int*      offs = (int*)(ws + OFF_OFFS);
    int*      cur  = (int*)(ws + OFF_CUR);
    int*      ssrc = (int*)(ws + OFF_SSRC);
    float*    sco  = ws + OFF_SCO;
    float*    Z    = ws + OFF_Z;
    float*    nar  = ws + OFF_NAR;
    float*    hid  = ws + OFF_HID;

    hipLaunchKernelGGL(k_init, dim3(80), dim3(256), 0, stream,
                       (const unsigned*)emb_word, flag, deg);
    hipLaunchKernelGGL(k_hist, dim3((NEDGES + 255) / 256), dim3(256), 0, stream, edge_dst, deg);
    hipLaunchKernelGGL(k_cvt, dim3((2 * HD * G3 + 255) / 256), dim3(256), 0, stream,
                       flag, Wh_f, Wh_b, whf);
    hipLaunchKernelGGL(k_gx, dim3(2 * NB * TT * G3 / 256), dim3(256), 0, stream,
                       flag, questions, emb_word, Wx_f, bx_f, Wx_b, bx_b, gx);
    hipLaunchKernelGGL(k_gru, dim3(8), dim3(2 * G3), 0, stream,
                       flag, questions, gx, whf, bh_f, bh_b, qemb);
    hipLaunchKernelGGL(k_scan, dim3(1), dim3(1024), 0, stream, deg, offs, cur);
    hipLaunchKernelGGL(k_scatter, dim3((NEDGES + 255) / 256), dim3(256), 0, stream,
                       flag, edge_src, edge_dst, edge_type, w_comp, cur, ssrc, sco);
    hipLaunchKernelGGL(k_qg, dim3(1), dim3(256), 0, stream, flag, qemb, W_hg, b_hg, qg);
    hipLaunchKernelGGL(k_attn1, dim3(NNODES / 4), dim3(256), 0, stream,
                       flag, node_descs, emb_desc, qg, nf);
    hipLaunchKernelGGL(k_hbg, dim3(NB * NNODES / 64), dim3(256), 0, stream,
                       flag, nf, bases, hb16);
    hipLaunchKernelGGL(k_agg, dim3(NNODES), dim3(256), 0, stream,
                       flag, hb16, offs, ssrc, sco, rgcn_bias, nf);
    hipLaunchKernelGGL(k_attn2, dim3(A2BLK), dim3(256), 0, stream, nf, qg, part);
    hipLaunchKernelGGL(k_attn2m, dim3(1), dim3(256), 0, stream, part, nar, Z);
    hipLaunchKernelGGL(k_fc1, dim3(NB * 16), dim3(256), 0, stream,
                       flag, nar, Z, qemb, W1, b1, hid);
    hipLaunchKernelGGL(k_fc2, dim3(NB * 32), dim3(256), 0, stream,
                       flag, hid, W2, b2, d_out);
}

// Round 8
// 417.652 us; speedup vs baseline: 1.7502x; 1.0695x over previous
//
#include <hip/hip_runtime.h>
#include <hip/hip_bf16.h>
#include <math.h>

typedef __hip_bfloat16 bf16;

#define NNODES 20000
#define NEDGES 320000
#define DLEN   16
#define G      64
#define DW     300
#define DH     256
#define HD     128
#define G3     384
#define NCLS   2000
#define NB     4
#define TT     32
#define A2BLK  256   // attn2 partial blocks

__device__ __forceinline__ float ld(const float* p, size_t i) { return p[i]; }
__device__ __forceinline__ float ld(const bf16* p, size_t i) { return __bfloat162float(p[i]); }
__device__ __forceinline__ void st(float* p, size_t i, float v) { p[i] = v; }
__device__ __forceinline__ void st(bf16* p, size_t i, float v) { p[i] = __float2bfloat16(v); }
__device__ __forceinline__ float relu(float x) { return (x < 0.f) ? 0.f : x; }

struct __align__(8) bf4 { bf16 x, y, z, w; };

// ---------------- workspace layout (float words) ----------------
#define OFF_FLAG  ((size_t)0)                         // 4
#define OFF_GX    (OFF_FLAG + 4)                      // 98304
#define OFF_WHF   (OFF_GX   + 2*NB*TT*G3)             // 98304
#define OFF_QEMB  (OFF_WHF  + 2*HD*G3)                // 1024
#define OFF_QG    (OFF_QEMB + NB*DH)                  // 256
#define OFF_NF    (OFF_QG   + NB*G)                   // 5,120,000
#define OFF_HB    (OFF_NF   + (size_t)NB*NNODES*G)    // bf16 [n][b][g]: 5.12M ushorts
#define OFF_PART  (OFF_HB   + (size_t)NB*NNODES*G)    // 256*4*66 = 67584
#define OFF_DEG   (OFF_PART + (size_t)A2BLK*NB*66)    // int 20000
#define OFF_OFFS  (OFF_DEG  + NNODES)                 // int 20008
#define OFF_CUR   (OFF_OFFS + NNODES + 8)             // int 20000
#define OFF_SSRC  (OFF_CUR  + NNODES)                 // int 320000
#define OFF_SCO   (OFF_SSRC + NEDGES)                 // float 320000
#define OFF_Z     (OFF_SCO  + NEDGES)                 // 4
#define OFF_NAR   (OFF_Z    + 4)                      // 256
#define OFF_HID   (OFF_NAR  + NB*G)                   // 4096

// ---------------- init: dtype sniff + zero deg ----------------
__global__ void k_init(const unsigned* probe, int* flag, int* deg) {
    int i = blockIdx.x * 256 + threadIdx.x;
    if (i < NNODES) deg[i] = 0;
    if (blockIdx.x == 0 && threadIdx.x < 64) {
        int cnt = 0;
        for (int k = threadIdx.x; k < 4096; k += 64) {
            unsigned lo = probe[k] & 0xFFFFu;
            unsigned e = (lo >> 7) & 0xFFu;
            cnt += (e >= 0x66u && e <= 0x7Eu) ? 1 : 0;
        }
#pragma unroll
        for (int off = 1; off < 64; off <<= 1) cnt += __shfl_xor(cnt, off, 64);
        if (threadIdx.x == 0) *flag = (2 * cnt > 4096) ? 1 : 0;   // 1 = bf16
    }
}

// ---------------- convert Wh to fp32 in ws ----------------
template <typename T>
__device__ void cvt_body(const void* Whf_, const void* Whb_, float* whf) {
    int id = blockIdx.x * 256 + threadIdx.x;
    if (id >= 2 * HD * G3) return;
    int d = id / (HD * G3), r = id % (HD * G3);
    const T* W = (const T*)(d ? Whb_ : Whf_);
    whf[id] = ld(W, (size_t)r);
}
__global__ void k_cvt(const int* flag, const void* Whf, const void* Whb, float* whf) {
    if (*flag) cvt_body<bf16>(Whf, Whb, whf);
    else       cvt_body<float>(Whf, Whb, whf);
}

// ---------------- gx = x @ Wx + bx ----------------
template <typename T>
__device__ void gx_body(const int* questions, const void* emb_word_,
                        const void* Wxf_, const void* bxf_,
                        const void* Wxb_, const void* bxb_, float* gx) {
    int id = blockIdx.x * 256 + threadIdx.x;
    int j = id % G3;
    int step = (id / G3) % TT;
    int b = (id / (G3 * TT)) % NB;
    int d = id / (G3 * TT * NB);
    int t = d ? (TT - 1 - step) : step;
    int tok = questions[b * TT + t];
    const T* Wx = (const T*)(d ? Wxb_ : Wxf_);
    const T* bx = (const T*)(d ? bxb_ : bxf_);
    const T* row = (const T*)emb_word_ + (size_t)tok * DW;
    float acc = ld(bx, (size_t)j);
#pragma unroll 4
    for (int k = 0; k < DW; k++) acc += ld(row, (size_t)k) * ld(Wx, (size_t)k * G3 + j);
    gx[id] = acc;
}
__global__ void k_gx(const int* flag, const int* questions, const void* emb_word,
                     const void* Wxf, const void* bxf,
                     const void* Wxb, const void* bxb, float* gx) {
    if (*flag) gx_body<bf16>(questions, emb_word, Wxf, bxf, Wxb, bxb, gx);
    else       gx_body<float>(questions, emb_word, Wxf, bxf, Wxb, bxb, gx);
}

// ---------------- GRU scan: block per (d,b), Wh register-resident ----------
template <typename T>
__device__ void gru_body(const int* questions, const float* gx, const float* whf,
                         const void* bhf_, const void* bhb_, float* qemb,
                         float* hsm, float* ghs) {
    int tid = threadIdx.x;
    int d = blockIdx.x >> 2, b = blockIdx.x & 3;
    int half = tid / G3, j = tid - half * G3;
    const float* wh = whf + (size_t)d * HD * G3 + (size_t)half * 64 * G3 + j;
    float w[64];
#pragma unroll
    for (int m = 0; m < 64; m++) w[m] = wh[(size_t)m * G3];
    const T* bh = (const T*)(d ? bhb_ : bhf_);
    float bhj = (half == 0) ? ld(bh, (size_t)j) : 0.f;
    if (tid < HD) hsm[tid] = 0.f;
    const float* gxb = gx + ((size_t)(d * NB + b)) * TT * G3;
    __syncthreads();
    const float4* h4 = (const float4*)(hsm + half * 64);
    for (int step = 0; step < TT; step++) {
        float acc = bhj;
#pragma unroll
        for (int m4 = 0; m4 < 16; m4++) {
            float4 hp = h4[m4];
            acc = fmaf(hp.x, w[4 * m4 + 0], acc);
            acc = fmaf(hp.y, w[4 * m4 + 1], acc);
            acc = fmaf(hp.z, w[4 * m4 + 2], acc);
            acc = fmaf(hp.w, w[4 * m4 + 3], acc);
        }
        ghs[half * G3 + j] = acc;
        __syncthreads();
        if (tid < HD) {
            const float* gxp = gxb + step * G3;
            int t = d ? (TT - 1 - step) : step;
            bool msk = questions[b * TT + t] != 0;
            float gr = ghs[tid] + ghs[G3 + tid];
            float gz = ghs[HD + tid] + ghs[G3 + HD + tid];
            float gn = ghs[2 * HD + tid] + ghs[G3 + 2 * HD + tid];
            float r = 1.f / (1.f + expf(-(gxp[tid] + gr)));
            float z = 1.f / (1.f + expf(-(gxp[HD + tid] + gz)));
            float n = tanhf(gxp[2 * HD + tid] + r * gn);
            float hn = (1.f - z) * n + z * hsm[tid];
            if (msk) hsm[tid] = hn;
        }
        __syncthreads();
    }
    if (tid < HD) qemb[b * DH + d * HD + tid] = hsm[tid];
}
__global__ __launch_bounds__(2 * G3) void k_gru(const int* flag, const int* questions,
                                                const float* gx, const float* whf,
                                                const void* bhf, const void* bhb, float* qemb) {
    __shared__ __align__(16) float hsm[HD];
    __shared__ float ghs[2 * G3];
    if (*flag) gru_body<bf16>(questions, gx, whf, bhf, bhb, qemb, hsm, ghs);
    else       gru_body<float>(questions, gx, whf, bhf, bhb, qemb, hsm, ghs);
}

// ---------------- q_g = q_emb @ W_hg + b_hg ----------------
template <typename T>
__device__ void qg_body(const float* qemb, const void* W_hg_, const void* b_hg_, float* qg) {
    int tid = threadIdx.x;
    int b = tid >> 6, g = tid & 63;
    const T* W = (const T*)W_hg_;
    float acc = ld((const T*)b_hg_, (size_t)g);
#pragma unroll 4
    for (int i = 0; i < DH; i++) acc += qemb[b * DH + i] * ld(W, (size_t)i * G + g);
    qg[b * G + g] = acc;
}
__global__ void k_qg(const int* flag, const float* qemb, const void* W_hg,
                     const void* b_hg, float* qg) {
    if (*flag) qg_body<bf16>(qemb, W_hg, b_hg, qg);
    else       qg_body<float>(qemb, W_hg, b_hg, qg);
}

// ---------------- attn1 softmax + node features: one wave per node ----------
template <typename T>
__device__ void attn1_body(const int* node_descs, const void* emb_desc_,
                           const float* qg, float* nf,
                           float* dsm, float* attn_s, float* qgs) {
    int tid = threadIdx.x;
    if (tid < NB * G) qgs[tid] = qg[tid];
    __syncthreads();
    const T* emb_desc = (const T*)emb_desc_;
    int w = tid >> 6, lane = tid & 63;
    int n = blockIdx.x * 4 + w;
    float dreg[DLEN];
    const int* nd = node_descs + n * DLEN;
    float* dw = dsm + (size_t)w * DLEN * (G + 1);
#pragma unroll
    for (int l = 0; l < DLEN; l++) {
        int idx = nd[l];
        float v = ld(emb_desc, (size_t)idx * G + lane);
        dreg[l] = v;
        dw[l * (G + 1) + lane] = v;
    }
    int lb = lane >> 4, ll = lane & 15;
    float acc = 0.f;
#pragma unroll 8
    for (int g = 0; g < G; g++) acc += dw[ll * (G + 1) + g] * qgs[lb * G + g];
    float mx = acc;
#pragma unroll
    for (int off = 1; off < 16; off <<= 1) mx = fmaxf(mx, __shfl_xor(mx, off, 64));
    float e = expf(acc - mx);
    float s = e;
#pragma unroll
    for (int off = 1; off < 16; off <<= 1) s += __shfl_xor(s, off, 64);
    attn_s[w * 64 + lane] = e / s;
#pragma unroll
    for (int b = 0; b < NB; b++) {
        float a = 0.f;
#pragma unroll
        for (int l = 0; l < DLEN; l++) a += attn_s[w * 64 + b * 16 + l] * dreg[l];
        nf[((size_t)b * NNODES + n) * G + lane] = a;
    }
}
__global__ __launch_bounds__(256) void k_attn1(const int* flag, const int* node_descs,
                                               const void* emb_desc, const float* qg, float* nf) {
    __shared__ float dsm[4 * DLEN * (G + 1)];
    __shared__ float attn_s[4 * 64];
    __shared__ float qgs[NB * G];
    if (*flag) attn1_body<bf16>(node_descs, emb_desc, qg, nf, dsm, attn_s, qgs);
    else       attn1_body<float>(node_descs, emb_desc, qg, nf, dsm, attn_s, qgs);
}

// ---------------- hb = nf @ bases[0] : tiled register GEMM, bf16 out -------
template <typename T>
__device__ void hbg_body(const float* nf, const void* bases_, bf16* hb16,
                         float* as, float* bs) {
    int tid = threadIdx.x;
    const T* bases = (const T*)bases_;
    for (int i = tid; i < G * G; i += 256) bs[(i >> 6) * 68 + (i & 63)] = ld(bases, (size_t)i);
    size_t r0 = (size_t)blockIdx.x * 64;
    const float4* gA = (const float4*)(nf + r0 * G);
#pragma unroll
    for (int i = 0; i < 4; i++) {
        int c = tid + i * 256;
        int row = c >> 4, col4 = c & 15;
        float4 v = gA[c];
        *(float4*)&as[row * 68 + col4 * 4] = v;
    }
    __syncthreads();
    int tx = tid & 15, ty = tid >> 4;
    float acc[4][4];
#pragma unroll
    for (int i = 0; i < 4; i++)
#pragma unroll
        for (int j = 0; j < 4; j++) acc[i][j] = 0.f;
#pragma unroll 4
    for (int g4 = 0; g4 < 16; g4++) {
        float4 b0 = *(const float4*)&bs[(4 * g4 + 0) * 68 + tx * 4];
        float4 b1 = *(const float4*)&bs[(4 * g4 + 1) * 68 + tx * 4];
        float4 b2 = *(const float4*)&bs[(4 * g4 + 2) * 68 + tx * 4];
        float4 b3 = *(const float4*)&bs[(4 * g4 + 3) * 68 + tx * 4];
#pragma unroll
        for (int i = 0; i < 4; i++) {
            float4 a = *(const float4*)&as[(ty * 4 + i) * 68 + g4 * 4];
            acc[i][0] = fmaf(a.x, b0.x, acc[i][0]);
            acc[i][0] = fmaf(a.y, b1.x, acc[i][0]);
            acc[i][0] = fmaf(a.z, b2.x, acc[i][0]);
            acc[i][0] = fmaf(a.w, b3.x, acc[i][0]);
            acc[i][1] = fmaf(a.x, b0.y, acc[i][1]);
            acc[i][1] = fmaf(a.y, b1.y, acc[i][1]);
            acc[i][1] = fmaf(a.z, b2.y, acc[i][1]);
            acc[i][1] = fmaf(a.w, b3.y, acc[i][1]);
            acc[i][2] = fmaf(a.x, b0.z, acc[i][2]);
            acc[i][2] = fmaf(a.y, b1.z, acc[i][2]);
            acc[i][2] = fmaf(a.z, b2.z, acc[i][2]);
            acc[i][2] = fmaf(a.w, b3.z, acc[i][2]);
            acc[i][3] = fmaf(a.x, b0.w, acc[i][3]);
            acc[i][3] = fmaf(a.y, b1.w, acc[i][3]);
            acc[i][3] = fmaf(a.z, b2.w, acc[i][3]);
            acc[i][3] = fmaf(a.w, b3.w, acc[i][3]);
        }
    }
#pragma unroll
    for (int i = 0; i < 4; i++) {
        size_t r = r0 + ty * 4 + i;          // flat row in [b*NNODES+n]
        int b = (int)(r / NNODES);
        int n = (int)(r - (size_t)b * NNODES);
        bf4 o;
        o.x = __float2bfloat16(acc[i][0]);
        o.y = __float2bfloat16(acc[i][1]);
        o.z = __float2bfloat16(acc[i][2]);
        o.w = __float2bfloat16(acc[i][3]);
        *(bf4*)&hb16[((size_t)n * NB + b) * G + tx * 4] = o;
    }
}
__global__ __launch_bounds__(256) void k_hbg(const int* flag, const float* nf,
                                             const void* bases, bf16* hb16) {
    __shared__ __align__(16) float as[64 * 68];
    __shared__ __align__(16) float bs[64 * 68];
    if (*flag) hbg_body<bf16>(nf, bases, hb16, as, bs);
    else       hbg_body<float>(nf, bases, hb16, as, bs);
}

// ---------------- CSR build: histogram, scan, scatter ----------------
__global__ void k_hist(const int* dst, int* deg) {
    int e = blockIdx.x * 256 + threadIdx.x;
    if (e < NEDGES) atomicAdd(&deg[dst[e]], 1);
}

__global__ __launch_bounds__(1024) void k_scan(const int* deg, int* offs, int* cur) {
    __shared__ int tot[1024];
    int t = threadIdx.x;
    int c[20];
    int base = t * 20;
    int run = 0;
#pragma unroll
    for (int i = 0; i < 20; i++) {
        int v = (base + i < NNODES) ? deg[base + i] : 0;
        c[i] = run;
        run += v;
    }
    tot[t] = run;
    __syncthreads();
    for (int off = 1; off < 1024; off <<= 1) {
        int v = (t >= off) ? tot[t - off] : 0;
        __syncthreads();
        tot[t] += v;
        __syncthreads();
    }
    int ebase = tot[t] - run;
#pragma unroll
    for (int i = 0; i < 20; i++) {
        if (base + i < NNODES) {
            offs[base + i] = ebase + c[i];
            cur[base + i] = ebase + c[i];
        }
    }
    if (t == 1023) offs[NNODES] = tot[1023];
}

template <typename T>
__device__ void scatter_body(const int* src, const int* dst, const int* typ,
                             const void* w_comp_, int* cur, int* ssrc, float* sco) {
    int e = blockIdx.x * 256 + threadIdx.x;
    if (e < NEDGES) {
        int dd = dst[e];
        int pos = atomicAdd(&cur[dd], 1);
        ssrc[pos] = src[e];
        sco[pos] = ld((const T*)w_comp_, (size_t)typ[e]);
    }
}
__global__ void k_scatter(const int* flag, const int* src, const int* dst, const int* typ,
                          const void* w_comp, int* cur, int* ssrc, float* sco) {
    if (*flag) scatter_body<bf16>(src, dst, typ, w_comp, cur, ssrc, sco);
    else       scatter_body<float>(src, dst, typ, w_comp, cur, ssrc, sco);
}

// ---------------- RGCN aggregate (gather bf16 over CSR) + bias + relu ------
template <typename T>
__device__ void agg_body(const bf16* hb16, const int* offs, const int* ssrc,
                         const float* sco, const void* bias_, float* out_nf) {
    int tid = threadIdx.x;
    int b = tid >> 6, g = tid & 63;
    int dn = blockIdx.x;
    int s0 = offs[dn], s1 = offs[dn + 1];
    int boff = b * G + g;
    float acc = 0.f;
    int p = s0;
    for (; p + 3 < s1; p += 4) {
        int i0 = ssrc[p], i1 = ssrc[p + 1], i2 = ssrc[p + 2], i3 = ssrc[p + 3];
        float c0 = sco[p], c1 = sco[p + 1], c2 = sco[p + 2], c3 = sco[p + 3];
        float x0 = __bfloat162float(hb16[(size_t)i0 * (NB * G) + boff]);
        float x1 = __bfloat162float(hb16[(size_t)i1 * (NB * G) + boff]);
        float x2 = __bfloat162float(hb16[(size_t)i2 * (NB * G) + boff]);
        float x3 = __bfloat162float(hb16[(size_t)i3 * (NB * G) + boff]);
        acc += c0 * x0;
        acc += c1 * x1;
        acc += c2 * x2;
        acc += c3 * x3;
    }
    for (; p < s1; p++)
        acc += sco[p] * __bfloat162float(hb16[(size_t)ssrc[p] * (NB * G) + boff]);
    out_nf[((size_t)b * NNODES + dn) * G + g] = relu(acc + ld((const T*)bias_, (size_t)g));
}
__global__ __launch_bounds__(256) void k_agg(const int* flag, const bf16* hb16, const int* offs,
                                             const int* ssrc, const float* sco,
                                             const void* bias, float* out_nf) {
    if (*flag) agg_body<bf16>(hb16, offs, ssrc, sco, bias, out_nf);
    else       agg_body<float>(hb16, offs, ssrc, sco, bias, out_nf);
}

// ---------------- attn2: single-pass online softmax, NO atomics ------------
// 4-way ILP: 4 independent loads + 4 independent shuffle-reduction chains per
// group; the M/L/A online update is applied sequentially in node order, so
// the result is bit-identical to the 1-node-per-iter version.
__device__ __forceinline__ void a2_update(float& M, float& L, float& A, float p, float v) {
    if (p > M) {
        float s = expf(M - p);
        A *= s; L *= s; M = p;
    }
    float e = expf(p - M);
    L += e;
    A = fmaf(e, v, A);
}

__global__ __launch_bounds__(256) void k_attn2(const float* rg, const float* qg, float* part) {
    int tid = threadIdx.x;
    int b = tid >> 6, lane = tid & 63;
    float q = qg[b * G + lane];
    int chunk = (NNODES + A2BLK - 1) / A2BLK;
    int n0 = blockIdx.x * chunk;
    int n1 = min(n0 + chunk, NNODES);
    const float* base = rg + (size_t)b * NNODES * G + lane;
    float M = -3.4e38f, L = 0.f, A = 0.f;
    int n = n0;
    for (; n + 3 < n1; n += 4) {
        float v0 = base[(size_t)(n + 0) * G];
        float v1 = base[(size_t)(n + 1) * G];
        float v2 = base[(size_t)(n + 2) * G];
        float v3 = base[(size_t)(n + 3) * G];
        float p0 = v0 * q, p1 = v1 * q, p2 = v2 * q, p3 = v3 * q;
#pragma unroll
        for (int off = 32; off >= 1; off >>= 1) {
            p0 += __shfl_xor(p0, off, 64);
            p1 += __shfl_xor(p1, off, 64);
            p2 += __shfl_xor(p2, off, 64);
            p3 += __shfl_xor(p3, off, 64);
        }
        a2_update(M, L, A, p0, v0);
        a2_update(M, L, A, p1, v1);
        a2_update(M, L, A, p2, v2);
        a2_update(M, L, A, p3, v3);
    }
    for (; n < n1; n++) {
        float v = base[(size_t)n * G];
        float p = v * q;
#pragma unroll
        for (int off = 32; off >= 1; off >>= 1) p += __shfl_xor(p, off, 64);
        a2_update(M, L, A, p, v);
    }
    float* pp = part + ((size_t)blockIdx.x * NB + b) * 66;
    if (lane == 0) { pp[0] = M; pp[1] = L; }
    pp[2 + lane] = A;
}

__global__ void k_attn2m(const float* part, float* nar, float* Z) {
    int tid = threadIdx.x;   // 256
    int b = tid >> 6, lane = tid & 63;
    float M = -3.4e38f, L = 0.f, A = 0.f;
    for (int p = 0; p < A2BLK; p++) {
        const float* pp = part + ((size_t)p * NB + b) * 66;
        float m = pp[0], l = pp[1], a = pp[2 + lane];
        float mn = fmaxf(M, m);
        float e1 = expf(M - mn), e2 = expf(m - mn);
        A = A * e1 + a * e2;
        L = L * e1 + l * e2;
        M = mn;
    }
    nar[b * G + lane] = A;
    if (lane == 0) Z[b] = L;
}

// ---------------- classifier: fc1, parallel k-reduction ----------------
template <typename T>
__device__ void fc1_body(const float* nar, const float* Z, const float* qemb,
                         const void* W1_, const void* b1_, float* hid,
                         float* feat, float* psum) {
    int tid = threadIdx.x;
    int b = blockIdx.x >> 4, tile = blockIdx.x & 15;
    for (int i = tid; i < 320; i += 256) {
        feat[i] = (i < G) ? nar[b * G + i] / Z[b] : qemb[b * DH + i - G];
    }
    __syncthreads();
    int lane = tid & 63, phase = tid >> 6;
    int u = tile * 64 + lane;
    const T* W1 = (const T*)W1_;
    float acc = 0.f;
#pragma unroll 8
    for (int kk = 0; kk < 80; kk++) {
        int k = phase * 80 + kk;
        acc += feat[k] * ld(W1, (size_t)k * 1024 + u);
    }
    psum[tid] = acc;
    __syncthreads();
    if (phase == 0) {
        float tot = psum[lane] + psum[64 + lane] + psum[128 + lane] + psum[192 + lane]
                  + ld((const T*)b1_, (size_t)u);
        hid[b * 1024 + u] = relu(tot);
    }
}
__global__ __launch_bounds__(256) void k_fc1(const int* flag, const float* nar, const float* Z,
                                             const float* qemb, const void* W1, const void* b1,
                                             float* hid) {
    __shared__ float feat[320];
    __shared__ float psum[256];
    if (*flag) fc1_body<bf16>(nar, Z, qemb, W1, b1, hid, feat, psum);
    else       fc1_body<float>(nar, Z, qemb, W1, b1, hid, feat, psum);
}

// ---------------- classifier: fc2, parallel k-reduction ----------------
template <typename T>
__device__ void fc2_body(const float* hid, const void* W2_, const void* b2_, void* out_,
                         float* hs, float* psum) {
    int tid = threadIdx.x;
    int b = blockIdx.x >> 5, tile = blockIdx.x & 31;
#pragma unroll
    for (int i = 0; i < 4; i++) hs[tid + 256 * i] = hid[b * 1024 + tid + 256 * i];
    __syncthreads();
    int lane = tid & 63, phase = tid >> 6;
    int c = tile * 64 + lane;
    bool ok = (c < NCLS);
    const T* W2 = (const T*)W2_;
    float acc = 0.f;
    if (ok) {
#pragma unroll 8
        for (int uu = 0; uu < 256; uu++) {
            int u = phase * 256 + uu;
            acc += hs[u] * ld(W2, (size_t)u * NCLS + c);
        }
    }
    psum[tid] = acc;
    __syncthreads();
    if (phase == 0 && ok) {
        float tot = psum[lane] + psum[64 + lane] + psum[128 + lane] + psum[192 + lane]
                  + ld((const T*)b2_, (size_t)c);
        st((T*)out_, (size_t)b * NCLS + c, tot);
    }
}
__global__ __launch_bounds__(256) void k_fc2(const int* flag, const float* hid,
                                             const void* W2, const void* b2v, void* out) {
    __shared__ float hs[1024];
    __shared__ float psum[256];
    if (*flag) fc2_body<bf16>(hid, W2, b2v, out, hs, psum);
    else       fc2_body<float>(hid, W2, b2v, out, hs, psum);
}

extern "C" void kernel_launch(void* const* d_in, const int* in_sizes, int n_in,
                              void* d_out, int out_size, void* d_ws, size_t ws_size,
                              hipStream_t stream) {
    const int* questions  = (const int*)d_in[0];
    const int* node_descs = (const int*)d_in[1];
    const int* edge_src   = (const int*)d_in[2];
    const int* edge_dst   = (const int*)d_in[3];
    const int* edge_type  = (const int*)d_in[4];
    const void* emb_word  = d_in[5];
    const void* emb_desc  = d_in[6];
    const void* Wx_f = d_in[7];
    const void* Wh_f = d_in[8];
    const void* bx_f = d_in[9];
    const void* bh_f = d_in[10];
    const void* Wx_b = d_in[11];
    const void* Wh_b = d_in[12];
    const void* bx_b = d_in[13];
    const void* bh_b = d_in[14];
    const void* W_hg = d_in[15];
    const void* b_hg = d_in[16];
    const void* bases = d_in[17];
    const void* w_comp = d_in[18];
    const void* rgcn_bias = d_in[19];
    const void* W1 = d_in[20];
    const void* b1 = d_in[21];
    const void* W2 = d_in[22];
    const void* b2 = d_in[23];

    float* ws = (float*)d_ws;
    int*      flag = (int*)(ws + OFF_FLAG);
    float*    gx   = ws + OFF_GX;
    float*    whf  = ws + OFF_WHF;
    float*    qemb = ws + OFF_QEMB;
    float*    qg   = ws + OFF_QG;
    float*    nf   = ws + OFF_NF;
    bf16*     hb16 = (bf16*)(ws + OFF_HB);
    float*    part = ws + OFF_PART;
    int*      deg  = (int*)(ws + OFF_DEG);
    int*      offs = (int*)(ws + OFF_OFFS);
    int*      cur  = (int*)(ws + OFF_CUR);
    int*      ssrc = (int*)(ws + OFF_SSRC);
    float*    sco  = ws + OFF_SCO;
    float*    Z    = ws + OFF_Z;
    float*    nar  = ws + OFF_NAR;
    float*    hid  = ws + OFF_HID;

    hipLaunchKernelGGL(k_init, dim3(80), dim3(256), 0, stream,
                       (const unsigned*)emb_word, flag, deg);
    hipLaunchKernelGGL(k_hist, dim3((NEDGES + 255) / 256), dim3(256), 0, stream, edge_dst, deg);
    hipLaunchKernelGGL(k_cvt, dim3((2 * HD * G3 + 255) / 256), dim3(256), 0, stream,
                       flag, Wh_f, Wh_b, whf);
    hipLaunchKernelGGL(k_gx, dim3(2 * NB * TT * G3 / 256), dim3(256), 0, stream,
                       flag, questions, emb_word, Wx_f, bx_f, Wx_b, bx_b, gx);
    hipLaunchKernelGGL(k_gru, dim3(8), dim3(2 * G3), 0, stream,
                       flag, questions, gx, whf, bh_f, bh_b, qemb);
    hipLaunchKernelGGL(k_scan, dim3(1), dim3(1024), 0, stream, deg, offs, cur);
    hipLaunchKernelGGL(k_scatter, dim3((NEDGES + 255) / 256), dim3(256), 0, stream,
                       flag, edge_src, edge_dst, edge_type, w_comp, cur, ssrc, sco);
    hipLaunchKernelGGL(k_qg, dim3(1), dim3(256), 0, stream, flag, qemb, W_hg, b_hg, qg);
    hipLaunchKernelGGL(k_attn1, dim3(NNODES / 4), dim3(256), 0, stream,
                       flag, node_descs, emb_desc, qg, nf);
    hipLaunchKernelGGL(k_hbg, dim3(NB * NNODES / 64), dim3(256), 0, stream,
                       flag, nf, bases, hb16);
    hipLaunchKernelGGL(k_agg, dim3(NNODES), dim3(256), 0, stream,
                       flag, hb16, offs, ssrc, sco, rgcn_bias, nf);
    hipLaunchKernelGGL(k_attn2, dim3(A2BLK), dim3(256), 0, stream, nf, qg, part);
    hipLaunchKernelGGL(k_attn2m, dim3(1), dim3(256), 0, stream, part, nar, Z);
    hipLaunchKernelGGL(k_fc1, dim3(NB * 16), dim3(256), 0, stream,
                       flag, nar, Z, qemb, W1, b1, hid);
    hipLaunchKernelGGL(k_fc2, dim3(NB * 32), dim3(256), 0, stream,
                       flag, hid, W2, b2, d_out);
}

// Round 9
// 390.543 us; speedup vs baseline: 1.8717x; 1.0694x over previous
//
#include <hip/hip_runtime.h>
#include <hip/hip_bf16.h>
#include <math.h>

typedef __hip_bfloat16 bf16;

#define NNODES 20000
#define NEDGES 320000
#define DLEN   16
#define G      64
#define DW     300
#define DH     256
#define HD     128
#define G3     384
#define NCLS   2000
#define NB     4
#define TT     32
#define A2BLK  1024  // attn2 partial blocks
#define A2MID  64    // stage-1 merge outputs

__device__ __forceinline__ float ld(const float* p, size_t i) { return p[i]; }
__device__ __forceinline__ float ld(const bf16* p, size_t i) { return __bfloat162float(p[i]); }
__device__ __forceinline__ void st(float* p, size_t i, float v) { p[i] = v; }
__device__ __forceinline__ void st(bf16* p, size_t i, float v) { p[i] = __float2bfloat16(v); }
__device__ __forceinline__ float relu(float x) { return (x < 0.f) ? 0.f : x; }

struct __align__(8) bf4 { bf16 x, y, z, w; };

// ---------------- workspace layout (float words) ----------------
#define OFF_FLAG  ((size_t)0)                         // 4
#define OFF_GX    (OFF_FLAG + 4)                      // 98304
#define OFF_WHF   (OFF_GX   + 2*NB*TT*G3)             // 98304
#define OFF_QEMB  (OFF_WHF  + 2*HD*G3)                // 1024
#define OFF_QG    (OFF_QEMB + NB*DH)                  // 256
#define OFF_NF    (OFF_QG   + NB*G)                   // pre:bf16 / post:fp32, 5.12M words
#define OFF_HB    (OFF_NF   + (size_t)NB*NNODES*G)    // bf16 [n][b][g]
#define OFF_PART  (OFF_HB   + (size_t)NB*NNODES*G)    // 1024*4*66 = 270336
#define OFF_PART2 (OFF_PART + (size_t)A2BLK*NB*66)    // 64*4*66 = 16896
#define OFF_DEG   (OFF_PART2+ (size_t)A2MID*NB*66)    // int 20000
#define OFF_OFFS  (OFF_DEG  + NNODES)                 // int 20008
#define OFF_CUR   (OFF_OFFS + NNODES + 8)             // int 20000
#define OFF_SSRC  (OFF_CUR  + NNODES)                 // int 320000
#define OFF_SCO   (OFF_SSRC + NEDGES)                 // float 320000
#define OFF_Z     (OFF_SCO  + NEDGES)                 // 4
#define OFF_NAR   (OFF_Z    + 4)                      // 256
#define OFF_HID   (OFF_NAR  + NB*G)                   // 4096

// ---------------- init: dtype sniff + zero deg ----------------
__global__ void k_init(const unsigned* probe, int* flag, int* deg) {
    int i = blockIdx.x * 256 + threadIdx.x;
    if (i < NNODES) deg[i] = 0;
    if (blockIdx.x == 0 && threadIdx.x < 64) {
        int cnt = 0;
        for (int k = threadIdx.x; k < 4096; k += 64) {
            unsigned lo = probe[k] & 0xFFFFu;
            unsigned e = (lo >> 7) & 0xFFu;
            cnt += (e >= 0x66u && e <= 0x7Eu) ? 1 : 0;
        }
#pragma unroll
        for (int off = 1; off < 64; off <<= 1) cnt += __shfl_xor(cnt, off, 64);
        if (threadIdx.x == 0) *flag = (2 * cnt > 4096) ? 1 : 0;   // 1 = bf16
    }
}

// ---------------- convert Wh to fp32 in ws ----------------
template <typename T>
__device__ void cvt_body(const void* Whf_, const void* Whb_, float* whf) {
    int id = blockIdx.x * 256 + threadIdx.x;
    if (id >= 2 * HD * G3) return;
    int d = id / (HD * G3), r = id % (HD * G3);
    const T* W = (const T*)(d ? Whb_ : Whf_);
    whf[id] = ld(W, (size_t)r);
}
__global__ void k_cvt(const int* flag, const void* Whf, const void* Whb, float* whf) {
    if (*flag) cvt_body<bf16>(Whf, Whb, whf);
    else       cvt_body<float>(Whf, Whb, whf);
}

// ---------------- gx = x @ Wx + bx ----------------
template <typename T>
__device__ void gx_body(const int* questions, const void* emb_word_,
                        const void* Wxf_, const void* bxf_,
                        const void* Wxb_, const void* bxb_, float* gx) {
    int id = blockIdx.x * 256 + threadIdx.x;
    int j = id % G3;
    int step = (id / G3) % TT;
    int b = (id / (G3 * TT)) % NB;
    int d = id / (G3 * TT * NB);
    int t = d ? (TT - 1 - step) : step;
    int tok = questions[b * TT + t];
    const T* Wx = (const T*)(d ? Wxb_ : Wxf_);
    const T* bx = (const T*)(d ? bxb_ : bxf_);
    const T* row = (const T*)emb_word_ + (size_t)tok * DW;
    float acc = ld(bx, (size_t)j);
#pragma unroll 8
    for (int k = 0; k < DW; k++) acc += ld(row, (size_t)k) * ld(Wx, (size_t)k * G3 + j);
    gx[id] = acc;
}
__global__ void k_gx(const int* flag, const int* questions, const void* emb_word,
                     const void* Wxf, const void* bxf,
                     const void* Wxb, const void* bxb, float* gx) {
    if (*flag) gx_body<bf16>(questions, emb_word, Wxf, bxf, Wxb, bxb, gx);
    else       gx_body<float>(questions, emb_word, Wxf, bxf, Wxb, bxb, gx);
}

// ---------------- GRU scan: block per (d,b), Wh register-resident ----------
template <typename T>
__device__ void gru_body(const int* questions, const float* gx, const float* whf,
                         const void* bhf_, const void* bhb_, float* qemb,
                         float* hsm, float* ghs) {
    int tid = threadIdx.x;
    int d = blockIdx.x >> 2, b = blockIdx.x & 3;
    int half = tid / G3, j = tid - half * G3;
    const float* wh = whf + (size_t)d * HD * G3 + (size_t)half * 64 * G3 + j;
    float w[64];
#pragma unroll
    for (int m = 0; m < 64; m++) w[m] = wh[(size_t)m * G3];
    const T* bh = (const T*)(d ? bhb_ : bhf_);
    float bhj = (half == 0) ? ld(bh, (size_t)j) : 0.f;
    if (tid < HD) hsm[tid] = 0.f;
    const float* gxb = gx + ((size_t)(d * NB + b)) * TT * G3;
    __syncthreads();
    const float4* h4 = (const float4*)(hsm + half * 64);
    for (int step = 0; step < TT; step++) {
        float acc = bhj;
#pragma unroll
        for (int m4 = 0; m4 < 16; m4++) {
            float4 hp = h4[m4];
            acc = fmaf(hp.x, w[4 * m4 + 0], acc);
            acc = fmaf(hp.y, w[4 * m4 + 1], acc);
            acc = fmaf(hp.z, w[4 * m4 + 2], acc);
            acc = fmaf(hp.w, w[4 * m4 + 3], acc);
        }
        ghs[half * G3 + j] = acc;
        __syncthreads();
        if (tid < HD) {
            const float* gxp = gxb + step * G3;
            int t = d ? (TT - 1 - step) : step;
            bool msk = questions[b * TT + t] != 0;
            float gr = ghs[tid] + ghs[G3 + tid];
            float gz = ghs[HD + tid] + ghs[G3 + HD + tid];
            float gn = ghs[2 * HD + tid] + ghs[G3 + 2 * HD + tid];
            float r = 1.f / (1.f + expf(-(gxp[tid] + gr)));
            float z = 1.f / (1.f + expf(-(gxp[HD + tid] + gz)));
            float n = tanhf(gxp[2 * HD + tid] + r * gn);
            float hn = (1.f - z) * n + z * hsm[tid];
            if (msk) hsm[tid] = hn;
        }
        __syncthreads();
    }
    if (tid < HD) qemb[b * DH + d * HD + tid] = hsm[tid];
}
__global__ __launch_bounds__(2 * G3) void k_gru(const int* flag, const int* questions,
                                                const float* gx, const float* whf,
                                                const void* bhf, const void* bhb, float* qemb) {
    __shared__ __align__(16) float hsm[HD];
    __shared__ float ghs[2 * G3];
    if (*flag) gru_body<bf16>(questions, gx, whf, bhf, bhb, qemb, hsm, ghs);
    else       gru_body<float>(questions, gx, whf, bhf, bhb, qemb, hsm, ghs);
}

// ---------------- q_g = q_emb @ W_hg + b_hg ----------------
template <typename T>
__device__ void qg_body(const float* qemb, const void* W_hg_, const void* b_hg_, float* qg) {
    int tid = threadIdx.x;
    int b = tid >> 6, g = tid & 63;
    const T* W = (const T*)W_hg_;
    float acc = ld((const T*)b_hg_, (size_t)g);
#pragma unroll 4
    for (int i = 0; i < DH; i++) acc += qemb[b * DH + i] * ld(W, (size_t)i * G + g);
    qg[b * G + g] = acc;
}
__global__ void k_qg(const int* flag, const float* qemb, const void* W_hg,
                     const void* b_hg, float* qg) {
    if (*flag) qg_body<bf16>(qemb, W_hg, b_hg, qg);
    else       qg_body<float>(qemb, W_hg, b_hg, qg);
}

// ---------------- attn1 softmax + node features -> bf16 nf ----------------
// dsm rows stride 68 (16B-aligned), float4 LDS dot; nf written as bf16.
template <typename T>
__device__ void attn1_body(const int* node_descs, const void* emb_desc_,
                           const float* qg, bf16* nf16,
                           float* dsm, float* attn_s, float* qgs) {
    int tid = threadIdx.x;
    if (tid < NB * G) qgs[tid] = qg[tid];
    __syncthreads();
    const T* emb_desc = (const T*)emb_desc_;
    int w = tid >> 6, lane = tid & 63;
    int n = blockIdx.x * 4 + w;
    float dreg[DLEN];
    const int* nd = node_descs + n * DLEN;
    float* dw = dsm + (size_t)w * DLEN * 68;
#pragma unroll
    for (int l = 0; l < DLEN; l++) {
        int idx = nd[l];
        float v = ld(emb_desc, (size_t)idx * G + lane);
        dreg[l] = v;
        dw[l * 68 + lane] = v;
    }
    int lb = lane >> 4, ll = lane & 15;
    float acc = 0.f;
#pragma unroll
    for (int i = 0; i < 16; i++) {
        float4 a = *(const float4*)&dw[ll * 68 + 4 * i];
        float4 q = *(const float4*)&qgs[lb * G + 4 * i];
        acc = fmaf(a.x, q.x, acc);
        acc = fmaf(a.y, q.y, acc);
        acc = fmaf(a.z, q.z, acc);
        acc = fmaf(a.w, q.w, acc);
    }
    float mx = acc;
#pragma unroll
    for (int off = 1; off < 16; off <<= 1) mx = fmaxf(mx, __shfl_xor(mx, off, 64));
    float e = expf(acc - mx);
    float s = e;
#pragma unroll
    for (int off = 1; off < 16; off <<= 1) s += __shfl_xor(s, off, 64);
    attn_s[w * 64 + lane] = e / s;
#pragma unroll
    for (int b = 0; b < NB; b++) {
        float a = 0.f;
#pragma unroll
        for (int l = 0; l < DLEN; l++) a += attn_s[w * 64 + b * 16 + l] * dreg[l];
        nf16[((size_t)b * NNODES + n) * G + lane] = __float2bfloat16(a);
    }
}
__global__ __launch_bounds__(256) void k_attn1(const int* flag, const int* node_descs,
                                               const void* emb_desc, const float* qg, bf16* nf16) {
    __shared__ __align__(16) float dsm[4 * DLEN * 68];
    __shared__ float attn_s[4 * 64];
    __shared__ __align__(16) float qgs[NB * G];
    if (*flag) attn1_body<bf16>(node_descs, emb_desc, qg, nf16, dsm, attn_s, qgs);
    else       attn1_body<float>(node_descs, emb_desc, qg, nf16, dsm, attn_s, qgs);
}

// ---------------- hb = nf16 @ bases[0] : tiled register GEMM, bf16 out -----
template <typename T>
__device__ void hbg_body(const bf16* nf16, const void* bases_, bf16* hb16,
                         float* as, float* bs) {
    int tid = threadIdx.x;
    const T* bases = (const T*)bases_;
    for (int i = tid; i < G * G; i += 256) bs[(i >> 6) * 68 + (i & 63)] = ld(bases, (size_t)i);
    size_t r0 = (size_t)blockIdx.x * 64;
    const bf4* gA = (const bf4*)(nf16 + r0 * G);
#pragma unroll
    for (int i = 0; i < 4; i++) {
        int c = tid + i * 256;               // 0..1023 quad index
        int row = c >> 4, col4 = c & 15;
        bf4 v = gA[c];
        float4 f;
        f.x = __bfloat162float(v.x);
        f.y = __bfloat162float(v.y);
        f.z = __bfloat162float(v.z);
        f.w = __bfloat162float(v.w);
        *(float4*)&as[row * 68 + col4 * 4] = f;
    }
    __syncthreads();
    int tx = tid & 15, ty = tid >> 4;
    float acc[4][4];
#pragma unroll
    for (int i = 0; i < 4; i++)
#pragma unroll
        for (int j = 0; j < 4; j++) acc[i][j] = 0.f;
#pragma unroll 4
    for (int g4 = 0; g4 < 16; g4++) {
        float4 b0 = *(const float4*)&bs[(4 * g4 + 0) * 68 + tx * 4];
        float4 b1 = *(const float4*)&bs[(4 * g4 + 1) * 68 + tx * 4];
        float4 b2 = *(const float4*)&bs[(4 * g4 + 2) * 68 + tx * 4];
        float4 b3 = *(const float4*)&bs[(4 * g4 + 3) * 68 + tx * 4];
#pragma unroll
        for (int i = 0; i < 4; i++) {
            float4 a = *(const float4*)&as[(ty * 4 + i) * 68 + g4 * 4];
            acc[i][0] = fmaf(a.x, b0.x, acc[i][0]);
            acc[i][0] = fmaf(a.y, b1.x, acc[i][0]);
            acc[i][0] = fmaf(a.z, b2.x, acc[i][0]);
            acc[i][0] = fmaf(a.w, b3.x, acc[i][0]);
            acc[i][1] = fmaf(a.x, b0.y, acc[i][1]);
            acc[i][1] = fmaf(a.y, b1.y, acc[i][1]);
            acc[i][1] = fmaf(a.z, b2.y, acc[i][1]);
            acc[i][1] = fmaf(a.w, b3.y, acc[i][1]);
            acc[i][2] = fmaf(a.x, b0.z, acc[i][2]);
            acc[i][2] = fmaf(a.y, b1.z, acc[i][2]);
            acc[i][2] = fmaf(a.z, b2.z, acc[i][2]);
            acc[i][2] = fmaf(a.w, b3.z, acc[i][2]);
            acc[i][3] = fmaf(a.x, b0.w, acc[i][3]);
            acc[i][3] = fmaf(a.y, b1.w, acc[i][3]);
            acc[i][3] = fmaf(a.z, b2.w, acc[i][3]);
            acc[i][3] = fmaf(a.w, b3.w, acc[i][3]);
        }
    }
#pragma unroll
    for (int i = 0; i < 4; i++) {
        size_t r = r0 + ty * 4 + i;          // flat row in [b*NNODES+n]
        int b = (int)(r / NNODES);
        int n = (int)(r - (size_t)b * NNODES);
        bf4 o;
        o.x = __float2bfloat16(acc[i][0]);
        o.y = __float2bfloat16(acc[i][1]);
        o.z = __float2bfloat16(acc[i][2]);
        o.w = __float2bfloat16(acc[i][3]);
        *(bf4*)&hb16[((size_t)n * NB + b) * G + tx * 4] = o;
    }
}
__global__ __launch_bounds__(256) void k_hbg(const int* flag, const bf16* nf16,
                                             const void* bases, bf16* hb16) {
    __shared__ __align__(16) float as[64 * 68];
    __shared__ __align__(16) float bs[64 * 68];
    if (*flag) hbg_body<bf16>(nf16, bases, hb16, as, bs);
    else       hbg_body<float>(nf16, bases, hb16, as, bs);
}

// ---------------- CSR build: histogram, scan, scatter ----------------
__global__ void k_hist(const int* dst, int* deg) {
    int e = blockIdx.x * 256 + threadIdx.x;
    if (e < NEDGES) atomicAdd(&deg[dst[e]], 1);
}

__global__ __launch_bounds__(1024) void k_scan(const int* deg, int* offs, int* cur) {
    __shared__ int tot[1024];
    int t = threadIdx.x;
    int c[20];
    int base = t * 20;
    int run = 0;
#pragma unroll
    for (int i = 0; i < 20; i++) {
        int v = (base + i < NNODES) ? deg[base + i] : 0;
        c[i] = run;
        run += v;
    }
    tot[t] = run;
    __syncthreads();
    for (int off = 1; off < 1024; off <<= 1) {
        int v = (t >= off) ? tot[t - off] : 0;
        __syncthreads();
        tot[t] += v;
        __syncthreads();
    }
    int ebase = tot[t] - run;
#pragma unroll
    for (int i = 0; i < 20; i++) {
        if (base + i < NNODES) {
            offs[base + i] = ebase + c[i];
            cur[base + i] = ebase + c[i];
        }
    }
    if (t == 1023) offs[NNODES] = tot[1023];
}

template <typename T>
__device__ void scatter_body(const int* src, const int* dst, const int* typ,
                             const void* w_comp_, int* cur, int* ssrc, float* sco) {
    int e = blockIdx.x * 256 + threadIdx.x;
    if (e < NEDGES) {
        int dd = dst[e];
        int pos = atomicAdd(&cur[dd], 1);
        ssrc[pos] = src[e];
        sco[pos] = ld((const T*)w_comp_, (size_t)typ[e]);
    }
}
__global__ void k_scatter(const int* flag, const int* src, const int* dst, const int* typ,
                          const void* w_comp, int* cur, int* ssrc, float* sco) {
    if (*flag) scatter_body<bf16>(src, dst, typ, w_comp, cur, ssrc, sco);
    else       scatter_body<float>(src, dst, typ, w_comp, cur, ssrc, sco);
}

// ---------------- RGCN aggregate (gather bf16 over CSR) + bias + relu ------
// 8x unrolled: 8 independent gathers in flight per wave.
template <typename T>
__device__ void agg_body(const bf16* hb16, const int* offs, const int* ssrc,
                         const float* sco, const void* bias_, float* out_nf) {
    int tid = threadIdx.x;
    int b = tid >> 6, g = tid & 63;
    int dn = blockIdx.x;
    int s0 = offs[dn], s1 = offs[dn + 1];
    int boff = b * G + g;
    float acc = 0.f;
    int p = s0;
    for (; p + 7 < s1; p += 8) {
        int i0 = ssrc[p], i1 = ssrc[p + 1], i2 = ssrc[p + 2], i3 = ssrc[p + 3];
        int i4 = ssrc[p + 4], i5 = ssrc[p + 5], i6 = ssrc[p + 6], i7 = ssrc[p + 7];
        float c0 = sco[p], c1 = sco[p + 1], c2 = sco[p + 2], c3 = sco[p + 3];
        float c4 = sco[p + 4], c5 = sco[p + 5], c6 = sco[p + 6], c7 = sco[p + 7];
        float x0 = __bfloat162float(hb16[(size_t)i0 * (NB * G) + boff]);
        float x1 = __bfloat162float(hb16[(size_t)i1 * (NB * G) + boff]);
        float x2 = __bfloat162float(hb16[(size_t)i2 * (NB * G) + boff]);
        float x3 = __bfloat162float(hb16[(size_t)i3 * (NB * G) + boff]);
        float x4 = __bfloat162float(hb16[(size_t)i4 * (NB * G) + boff]);
        float x5 = __bfloat162float(hb16[(size_t)i5 * (NB * G) + boff]);
        float x6 = __bfloat162float(hb16[(size_t)i6 * (NB * G) + boff]);
        float x7 = __bfloat162float(hb16[(size_t)i7 * (NB * G) + boff]);
        acc += c0 * x0;
        acc += c1 * x1;
        acc += c2 * x2;
        acc += c3 * x3;
        acc += c4 * x4;
        acc += c5 * x5;
        acc += c6 * x6;
        acc += c7 * x7;
    }
    for (; p < s1; p++)
        acc += sco[p] * __bfloat162float(hb16[(size_t)ssrc[p] * (NB * G) + boff]);
    out_nf[((size_t)b * NNODES + dn) * G + g] = relu(acc + ld((const T*)bias_, (size_t)g));
}
__global__ __launch_bounds__(256) void k_agg(const int* flag, const bf16* hb16, const int* offs,
                                             const int* ssrc, const float* sco,
                                             const void* bias, float* out_nf) {
    if (*flag) agg_body<bf16>(hb16, offs, ssrc, sco, bias, out_nf);
    else       agg_body<float>(hb16, offs, ssrc, sco, bias, out_nf);
}

// ---------------- attn2: single-pass online softmax, NO atomics ------------
__device__ __forceinline__ void a2_update(float& M, float& L, float& A, float p, float v) {
    if (p > M) {
        float s = expf(M - p);
        A *= s; L *= s; M = p;
    }
    float e = expf(p - M);
    L += e;
    A = fmaf(e, v, A);
}

__global__ __launch_bounds__(256) void k_attn2(const float* rg, const float* qg, float* part) {
    int tid = threadIdx.x;
    int b = tid >> 6, lane = tid & 63;
    float q = qg[b * G + lane];
    int chunk = (NNODES + A2BLK - 1) / A2BLK;
    int n0 = blockIdx.x * chunk;
    int n1 = min(n0 + chunk, NNODES);
    const float* base = rg + (size_t)b * NNODES * G + lane;
    float M = -3.4e38f, L = 0.f, A = 0.f;
    int n = n0;
    for (; n + 3 < n1; n += 4) {
        float v0 = base[(size_t)(n + 0) * G];
        float v1 = base[(size_t)(n + 1) * G];
        float v2 = base[(size_t)(n + 2) * G];
        float v3 = base[(size_t)(n + 3) * G];
        float p0 = v0 * q, p1 = v1 * q, p2 = v2 * q, p3 = v3 * q;
#pragma unroll
        for (int off = 32; off >= 1; off >>= 1) {
            p0 += __shfl_xor(p0, off, 64);
            p1 += __shfl_xor(p1, off, 64);
            p2 += __shfl_xor(p2, off, 64);
            p3 += __shfl_xor(p3, off, 64);
        }
        a2_update(M, L, A, p0, v0);
        a2_update(M, L, A, p1, v1);
        a2_update(M, L, A, p2, v2);
        a2_update(M, L, A, p3, v3);
    }
    for (; n < n1; n++) {
        float v = base[(size_t)n * G];
        float p = v * q;
#pragma unroll
        for (int off = 32; off >= 1; off >>= 1) p += __shfl_xor(p, off, 64);
        a2_update(M, L, A, p, v);
    }
    float* pp = part + ((size_t)blockIdx.x * NB + b) * 66;
    if (lane == 0) { pp[0] = M; pp[1] = L; }
    pp[2 + lane] = A;
}

// stage-1 merge: A2BLK -> A2MID partials (grid = A2MID blocks, 256 thr)
__global__ void k_attn2m(const float* part, float* part2) {
    int tid = threadIdx.x;
    int b = tid >> 6, lane = tid & 63;
    int grp = blockIdx.x;                  // merges partials grp*16 .. grp*16+15
    float M = -3.4e38f, L = 0.f, A = 0.f;
    for (int i = 0; i < A2BLK / A2MID; i++) {
        const float* pp = part + ((size_t)(grp * (A2BLK / A2MID) + i) * NB + b) * 66;
        float m = pp[0], l = pp[1], a = pp[2 + lane];
        float mn = fmaxf(M, m);
        float e1 = expf(M - mn), e2 = expf(m - mn);
        A = A * e1 + a * e2;
        L = L * e1 + l * e2;
        M = mn;
    }
    float* pq = part2 + ((size_t)grp * NB + b) * 66;
    if (lane == 0) { pq[0] = M; pq[1] = L; }
    pq[2 + lane] = A;
}

// stage-2 merge: A2MID -> nar/Z (1 block, 256 thr)
__global__ void k_attn2f(const float* part2, float* nar, float* Z) {
    int tid = threadIdx.x;
    int b = tid >> 6, lane = tid & 63;
    float M = -3.4e38f, L = 0.f, A = 0.f;
    for (int p = 0; p < A2MID; p++) {
        const float* pp = part2 + ((size_t)p * NB + b) * 66;
        float m = pp[0], l = pp[1], a = pp[2 + lane];
        float mn = fmaxf(M, m);
        float e1 = expf(M - mn), e2 = expf(m - mn);
        A = A * e1 + a * e2;
        L = L * e1 + l * e2;
        M = mn;
    }
    nar[b * G + lane] = A;
    if (lane == 0) Z[b] = L;
}

// ---------------- classifier: fc1, parallel k-reduction ----------------
template <typename T>
__device__ void fc1_body(const float* nar, const float* Z, const float* qemb,
                         const void* W1_, const void* b1_, float* hid,
                         float* feat, float* psum) {
    int tid = threadIdx.x;
    int b = blockIdx.x >> 4, tile = blockIdx.x & 15;
    for (int i = tid; i < 320; i += 256) {
        feat[i] = (i < G) ? nar[b * G + i] / Z[b] : qemb[b * DH + i - G];
    }
    __syncthreads();
    int lane = tid & 63, phase = tid >> 6;
    int u = tile * 64 + lane;
    const T* W1 = (const T*)W1_;
    float acc = 0.f;
#pragma unroll 8
    for (int kk = 0; kk < 80; kk++) {
        int k = phase * 80 + kk;
        acc += feat[k] * ld(W1, (size_t)k * 1024 + u);
    }
    psum[tid] = acc;
    __syncthreads();
    if (phase == 0) {
        float tot = psum[lane] + psum[64 + lane] + psum[128 + lane] + psum[192 + lane]
                  + ld((const T*)b1_, (size_t)u);
        hid[b * 1024 + u] = relu(tot);
    }
}
__global__ __launch_bounds__(256) void k_fc1(const int* flag, const float* nar, const float* Z,
                                             const float* qemb, const void* W1, const void* b1,
                                             float* hid) {
    __shared__ float feat[320];
    __shared__ float psum[256];
    if (*flag) fc1_body<bf16>(nar, Z, qemb, W1, b1, hid, feat, psum);
    else       fc1_body<float>(nar, Z, qemb, W1, b1, hid, feat, psum);
}

// ---------------- classifier: fc2, parallel k-reduction ----------------
template <typename T>
__device__ void fc2_body(const float* hid, const void* W2_, const void* b2_, void* out_,
                         float* hs, float* psum) {
    int tid = threadIdx.x;
    int b = blockIdx.x >> 5, tile = blockIdx.x & 31;
#pragma unroll
    for (int i = 0; i < 4; i++) hs[tid + 256 * i] = hid[b * 1024 + tid + 256 * i];
    __syncthreads();
    int lane = tid & 63, phase = tid >> 6;
    int c = tile * 64 + lane;
    bool ok = (c < NCLS);
    const T* W2 = (const T*)W2_;
    float acc = 0.f;
    if (ok) {
#pragma unroll 8
        for (int uu = 0; uu < 256; uu++) {
            int u = phase * 256 + uu;
            acc += hs[u] * ld(W2, (size_t)u * NCLS + c);
        }
    }
    psum[tid] = acc;
    __syncthreads();
    if (phase == 0 && ok) {
        float tot = psum[lane] + psum[64 + lane] + psum[128 + lane] + psum[192 + lane]
                  + ld((const T*)b2_, (size_t)c);
        st((T*)out_, (size_t)b * NCLS + c, tot);
    }
}
__global__ __launch_bounds__(256) void k_fc2(const int* flag, const float* hid,
                                             const void* W2, const void* b2v, void* out) {
    __shared__ float hs[1024];
    __shared__ float psum[256];
    if (*flag) fc2_body<bf16>(hid, W2, b2v, out, hs, psum);
    else       fc2_body<float>(hid, W2, b2v, out, hs, psum);
}

extern "C" void kernel_launch(void* const* d_in, const int* in_sizes, int n_in,
                              void* d_out, int out_size, void* d_ws, size_t ws_size,
                              hipStream_t stream) {
    const int* questions  = (const int*)d_in[0];
    const int* node_descs = (const int*)d_in[1];
    const int* edge_src   = (const int*)d_in[2];
    const int* edge_dst   = (const int*)d_in[3];
    const int* edge_type  = (const int*)d_in[4];
    const void* emb_word  = d_in[5];
    const void* emb_desc  = d_in[6];
    const void* Wx_f = d_in[7];
    const void* Wh_f = d_in[8];
    const void* bx_f = d_in[9];
    const void* bh_f = d_in[10];
    const void* Wx_b = d_in[11];
    const void* Wh_b = d_in[12];
    const void* bx_b = d_in[13];
    const void* bh_b = d_in[14];
    const void* W_hg = d_in[15];
    const void* b_hg = d_in[16];
    const void* bases = d_in[17];
    const void* w_comp = d_in[18];
    const void* rgcn_bias = d_in[19];
    const void* W1 = d_in[20];
    const void* b1 = d_in[21];
    const void* W2 = d_in[22];
    const void* b2 = d_in[23];

    float* ws = (float*)d_ws;
    int*      flag = (int*)(ws + OFF_FLAG);
    float*    gx    = ws + OFF_GX;
    float*    whf   = ws + OFF_WHF;
    float*    qemb  = ws + OFF_QEMB;
    float*    qg    = ws + OFF_QG;
    float*    nf    = ws + OFF_NF;         // fp32 view (post-RGCN)
    bf16*     nf16  = (bf16*)(ws + OFF_NF);// bf16 view (pre-RGCN)
    bf16*     hb16  = (bf16*)(ws + OFF_HB);
    float*    part  = ws + OFF_PART;
    float*    part2 = ws + OFF_PART2;
    int*      deg   = (int*)(ws + OFF_DEG);
    int*      offs  = (int*)(ws + OFF_OFFS);
    int*      cur   = (int*)(ws + OFF_CUR);
    int*      ssrc  = (int*)(ws + OFF_SSRC);
    float*    sco   = ws + OFF_SCO;
    float*    Z     = ws + OFF_Z;
    float*    nar   = ws + OFF_NAR;
    float*    hid   = ws + OFF_HID;

    hipLaunchKernelGGL(k_init, dim3(80), dim3(256), 0, stream,
                       (const unsigned*)emb_word, flag, deg);
    hipLaunchKernelGGL(k_hist, dim3((NEDGES + 255) / 256), dim3(256), 0, stream, edge_dst, deg);
    hipLaunchKernelGGL(k_cvt, dim3((2 * HD * G3 + 255) / 256), dim3(256), 0, stream,
                       flag, Wh_f, Wh_b, whf);
    hipLaunchKernelGGL(k_gx, dim3(2 * NB * TT * G3 / 256), dim3(256), 0, stream,
                       flag, questions, emb_word, Wx_f, bx_f, Wx_b, bx_b, gx);
    hipLaunchKernelGGL(k_gru, dim3(8), dim3(2 * G3), 0, stream,
                       flag, questions, gx, whf, bh_f, bh_b, qemb);
    hipLaunchKernelGGL(k_scan, dim3(1), dim3(1024), 0, stream, deg, offs, cur);
    hipLaunchKernelGGL(k_scatter, dim3((NEDGES + 255) / 256), dim3(256), 0, stream,
                       flag, edge_src, edge_dst, edge_type, w_comp, cur, ssrc, sco);
    hipLaunchKernelGGL(k_qg, dim3(1), dim3(256), 0, stream, flag, qemb, W_hg, b_hg, qg);
    hipLaunchKernelGGL(k_attn1, dim3(NNODES / 4), dim3(256), 0, stream,
                       flag, node_descs, emb_desc, qg, nf16);
    hipLaunchKernelGGL(k_hbg, dim3(NB * NNODES / 64), dim3(256), 0, stream,
                       flag, nf16, bases, hb16);
    hipLaunchKernelGGL(k_agg, dim3(NNODES), dim3(256), 0, stream,
                       flag, hb16, offs, ssrc, sco, rgcn_bias, nf);
    hipLaunchKernelGGL(k_attn2, dim3(A2BLK), dim3(256), 0, stream, nf, qg, part);
    hipLaunchKernelGGL(k_attn2m, dim3(A2MID), dim3(256), 0, stream, part, part2);
    hipLaunchKernelGGL(k_attn2f, dim3(1), dim3(256), 0, stream, part2, nar, Z);
    hipLaunchKernelGGL(k_fc1, dim3(NB * 16), dim3(256), 0, stream,
                       flag, nar, Z, qemb, W1, b1, hid);
    hipLaunchKernelGGL(k_fc2, dim3(NB * 32), dim3(256), 0, stream,
                       flag, hid, W2, b2, d_out);
}

// Round 10
// 349.325 us; speedup vs baseline: 2.0926x; 1.1180x over previous
//
#include <hip/hip_runtime.h>
#include <hip/hip_bf16.h>
#include <math.h>

typedef __hip_bfloat16 bf16;

#define NNODES 20000
#define NEDGES 320000
#define DLEN   16
#define G      64
#define DW     300
#define DH     256
#define HD     128
#define G3     384
#define NCLS   2000
#define NB     4
#define TT     32
#define A2BLK  1024  // attn2 partial blocks
#define A2MID  64    // stage-1 merge outputs

#define NBLK_CVT  384
#define NBLK_GX   384
#define NBLK_HIST ((NEDGES + 255) / 256)

__device__ __forceinline__ float ld(const float* p, size_t i) { return p[i]; }
__device__ __forceinline__ float ld(const bf16* p, size_t i) { return __bfloat162float(p[i]); }
__device__ __forceinline__ void st(float* p, size_t i, float v) { p[i] = v; }
__device__ __forceinline__ void st(bf16* p, size_t i, float v) { p[i] = __float2bfloat16(v); }
__device__ __forceinline__ float relu(float x) { return (x < 0.f) ? 0.f : x; }

struct __align__(8) bf4 { bf16 x, y, z, w; };

// ---------------- workspace layout (float words) ----------------
#define OFF_FLAG  ((size_t)0)                         // 4
#define OFF_GX    (OFF_FLAG + 4)                      // 98304
#define OFF_WHF   (OFF_GX   + 2*NB*TT*G3)             // 98304
#define OFF_QEMB  (OFF_WHF  + 2*HD*G3)                // 1024
#define OFF_QG    (OFF_QEMB + NB*DH)                  // 256
#define OFF_NF    (OFF_QG   + NB*G)                   // pre:bf16 / post:fp32
#define OFF_HB    (OFF_NF   + (size_t)NB*NNODES*G)    // bf16 [n][b][g]
#define OFF_PART  (OFF_HB   + (size_t)NB*NNODES*G)    // 1024*4*66
#define OFF_PART2 (OFF_PART + (size_t)A2BLK*NB*66)    // 64*4*66
#define OFF_DEG   (OFF_PART2+ (size_t)A2MID*NB*66)    // int 20000
#define OFF_OFFS  (OFF_DEG  + NNODES)                 // int 20008
#define OFF_CUR   (OFF_OFFS + NNODES + 8)             // int 20000
#define OFF_SSRC  (OFF_CUR  + NNODES)                 // int 320000
#define OFF_SCO   (OFF_SSRC + NEDGES)                 // float 320000
#define OFF_HID   (OFF_SCO  + NEDGES)                 // 4096

// ---------------- init: dtype sniff + zero deg ----------------
__global__ void k_init(const unsigned* probe, int* flag, int* deg) {
    int i = blockIdx.x * 256 + threadIdx.x;
    if (i < NNODES) deg[i] = 0;
    if (blockIdx.x == 0 && threadIdx.x < 64) {
        int cnt = 0;
        for (int k = threadIdx.x; k < 4096; k += 64) {
            unsigned lo = probe[k] & 0xFFFFu;
            unsigned e = (lo >> 7) & 0xFFu;
            cnt += (e >= 0x66u && e <= 0x7Eu) ? 1 : 0;
        }
#pragma unroll
        for (int off = 1; off < 64; off <<= 1) cnt += __shfl_xor(cnt, off, 64);
        if (threadIdx.x == 0) *flag = (2 * cnt > 4096) ? 1 : 0;   // 1 = bf16
    }
}

// ---------------- fused prep: cvt | gx | hist (block-partitioned) ----------
template <typename T>
__device__ void cvt_body(int id, const void* Whf_, const void* Whb_, float* whf) {
    if (id >= 2 * HD * G3) return;
    int d = id / (HD * G3), r = id % (HD * G3);
    const T* W = (const T*)(d ? Whb_ : Whf_);
    whf[id] = ld(W, (size_t)r);
}

template <typename T>
__device__ void gx_body(int id, const int* questions, const void* emb_word_,
                        const void* Wxf_, const void* bxf_,
                        const void* Wxb_, const void* bxb_, float* gx) {
    int j = id % G3;
    int step = (id / G3) % TT;
    int b = (id / (G3 * TT)) % NB;
    int d = id / (G3 * TT * NB);
    int t = d ? (TT - 1 - step) : step;
    int tok = questions[b * TT + t];
    const T* Wx = (const T*)(d ? Wxb_ : Wxf_);
    const T* bx = (const T*)(d ? bxb_ : bxf_);
    const T* row = (const T*)emb_word_ + (size_t)tok * DW;
    float acc = ld(bx, (size_t)j);
#pragma unroll 8
    for (int k = 0; k < DW; k++) acc += ld(row, (size_t)k) * ld(Wx, (size_t)k * G3 + j);
    gx[id] = acc;
}

__global__ void k_prep(const int* flag, const void* Whf, const void* Whb, float* whf,
                       const int* questions, const void* emb_word,
                       const void* Wxf, const void* bxf,
                       const void* Wxb, const void* bxb, float* gx,
                       const int* edge_dst, int* deg) {
    int bx = blockIdx.x;
    int tid = threadIdx.x;
    if (bx < NBLK_CVT) {
        int id = bx * 256 + tid;
        if (*flag) cvt_body<bf16>(id, Whf, Whb, whf);
        else       cvt_body<float>(id, Whf, Whb, whf);
    } else if (bx < NBLK_CVT + NBLK_GX) {
        int id = (bx - NBLK_CVT) * 256 + tid;
        if (*flag) gx_body<bf16>(id, questions, emb_word, Wxf, bxf, Wxb, bxb, gx);
        else       gx_body<float>(id, questions, emb_word, Wxf, bxf, Wxb, bxb, gx);
    } else {
        int e = (bx - NBLK_CVT - NBLK_GX) * 256 + tid;
        if (e < NEDGES) atomicAdd(&deg[edge_dst[e]], 1);
    }
}

// ---------------- GRU scan: block per (d,b), Wh register-resident ----------
template <typename T>
__device__ void gru_body(const int* questions, const float* gx, const float* whf,
                         const void* bhf_, const void* bhb_, float* qemb,
                         float* hsm, float* ghs) {
    int tid = threadIdx.x;
    int d = blockIdx.x >> 2, b = blockIdx.x & 3;
    int half = tid / G3, j = tid - half * G3;
    const float* wh = whf + (size_t)d * HD * G3 + (size_t)half * 64 * G3 + j;
    float w[64];
#pragma unroll
    for (int m = 0; m < 64; m++) w[m] = wh[(size_t)m * G3];
    const T* bh = (const T*)(d ? bhb_ : bhf_);
    float bhj = (half == 0) ? ld(bh, (size_t)j) : 0.f;
    if (tid < HD) hsm[tid] = 0.f;
    const float* gxb = gx + ((size_t)(d * NB + b)) * TT * G3;
    __syncthreads();
    const float4* h4 = (const float4*)(hsm + half * 64);
    for (int step = 0; step < TT; step++) {
        float acc = bhj;
#pragma unroll
        for (int m4 = 0; m4 < 16; m4++) {
            float4 hp = h4[m4];
            acc = fmaf(hp.x, w[4 * m4 + 0], acc);
            acc = fmaf(hp.y, w[4 * m4 + 1], acc);
            acc = fmaf(hp.z, w[4 * m4 + 2], acc);
            acc = fmaf(hp.w, w[4 * m4 + 3], acc);
        }
        ghs[half * G3 + j] = acc;
        __syncthreads();
        if (tid < HD) {
            const float* gxp = gxb + step * G3;
            int t = d ? (TT - 1 - step) : step;
            bool msk = questions[b * TT + t] != 0;
            float gr = ghs[tid] + ghs[G3 + tid];
            float gz = ghs[HD + tid] + ghs[G3 + HD + tid];
            float gn = ghs[2 * HD + tid] + ghs[G3 + 2 * HD + tid];
            float r = 1.f / (1.f + expf(-(gxp[tid] + gr)));
            float z = 1.f / (1.f + expf(-(gxp[HD + tid] + gz)));
            float n = tanhf(gxp[2 * HD + tid] + r * gn);
            float hn = (1.f - z) * n + z * hsm[tid];
            if (msk) hsm[tid] = hn;
        }
        __syncthreads();
    }
    if (tid < HD) qemb[b * DH + d * HD + tid] = hsm[tid];
}
__global__ __launch_bounds__(2 * G3) void k_gru(const int* flag, const int* questions,
                                                const float* gx, const float* whf,
                                                const void* bhf, const void* bhb, float* qemb) {
    __shared__ __align__(16) float hsm[HD];
    __shared__ float ghs[2 * G3];
    if (*flag) gru_body<bf16>(questions, gx, whf, bhf, bhb, qemb, hsm, ghs);
    else       gru_body<float>(questions, gx, whf, bhf, bhb, qemb, hsm, ghs);
}

// ---------------- fused: CSR scan (block 0) + qg (block 1) ----------------
template <typename T>
__device__ void qg_body(const float* qemb, const void* W_hg_, const void* b_hg_, float* qg) {
    int tid = threadIdx.x;
    if (tid >= 256) return;
    int b = tid >> 6, g = tid & 63;
    const T* W = (const T*)W_hg_;
    float acc = ld((const T*)b_hg_, (size_t)g);
#pragma unroll 4
    for (int i = 0; i < DH; i++) acc += qemb[b * DH + i] * ld(W, (size_t)i * G + g);
    qg[b * G + g] = acc;
}

__global__ __launch_bounds__(1024) void k_scan_qg(const int* flag, const int* deg,
                                                  int* offs, int* cur,
                                                  const float* qemb, const void* W_hg,
                                                  const void* b_hg, float* qg) {
    if (blockIdx.x == 1) {
        if (*flag) qg_body<bf16>(qemb, W_hg, b_hg, qg);
        else       qg_body<float>(qemb, W_hg, b_hg, qg);
        return;
    }
    // block 0: exclusive scan of deg -> offs/cur, via wave shfl-scan
    __shared__ int wtot[16];
    int t = threadIdx.x;
    int lane = t & 63, wave = t >> 6;
    int c[20];
    int base = t * 20;
    int run = 0;
#pragma unroll
    for (int i = 0; i < 20; i++) {
        int v = (base + i < NNODES) ? deg[base + i] : 0;
        c[i] = run;
        run += v;
    }
    int myrun = run;
    int inc = myrun;
#pragma unroll
    for (int off = 1; off < 64; off <<= 1) {
        int u = __shfl_up(inc, off, 64);
        if (lane >= off) inc += u;
    }
    if (lane == 63) wtot[wave] = inc;
    __syncthreads();
    if (t == 0) {
        int s = 0;
#pragma unroll
        for (int i = 0; i < 16; i++) { int v = wtot[i]; wtot[i] = s; s += v; }
        offs[NNODES] = s;
    }
    __syncthreads();
    int ebase = wtot[wave] + inc - myrun;
#pragma unroll
    for (int i = 0; i < 20; i++) {
        if (base + i < NNODES) {
            offs[base + i] = ebase + c[i];
            cur[base + i] = ebase + c[i];
        }
    }
}

template <typename T>
__device__ void scatter_body(const int* src, const int* dst, const int* typ,
                             const void* w_comp_, int* cur, int* ssrc, float* sco) {
    int e = blockIdx.x * 256 + threadIdx.x;
    if (e < NEDGES) {
        int dd = dst[e];
        int pos = atomicAdd(&cur[dd], 1);
        ssrc[pos] = src[e];
        sco[pos] = ld((const T*)w_comp_, (size_t)typ[e]);
    }
}
__global__ void k_scatter(const int* flag, const int* src, const int* dst, const int* typ,
                          const void* w_comp, int* cur, int* ssrc, float* sco) {
    if (*flag) scatter_body<bf16>(src, dst, typ, w_comp, cur, ssrc, sco);
    else       scatter_body<float>(src, dst, typ, w_comp, cur, ssrc, sco);
}

// ---------------- attn1 softmax + node features -> bf16 nf ----------------
template <typename T>
__device__ void attn1_body(const int* node_descs, const void* emb_desc_,
                           const float* qg, bf16* nf16,
                           float* dsm, float* attn_s, float* qgs) {
    int tid = threadIdx.x;
    if (tid < NB * G) qgs[tid] = qg[tid];
    __syncthreads();
    const T* emb_desc = (const T*)emb_desc_;
    int w = tid >> 6, lane = tid & 63;
    int n = blockIdx.x * 4 + w;
    float dreg[DLEN];
    const int* nd = node_descs + n * DLEN;
    float* dw = dsm + (size_t)w * DLEN * 68;
#pragma unroll
    for (int l = 0; l < DLEN; l++) {
        int idx = nd[l];
        float v = ld(emb_desc, (size_t)idx * G + lane);
        dreg[l] = v;
        dw[l * 68 + lane] = v;
    }
    int lb = lane >> 4, ll = lane & 15;
    float acc = 0.f;
#pragma unroll
    for (int i = 0; i < 16; i++) {
        float4 a = *(const float4*)&dw[ll * 68 + 4 * i];
        float4 q = *(const float4*)&qgs[lb * G + 4 * i];
        acc = fmaf(a.x, q.x, acc);
        acc = fmaf(a.y, q.y, acc);
        acc = fmaf(a.z, q.z, acc);
        acc = fmaf(a.w, q.w, acc);
    }
    float mx = acc;
#pragma unroll
    for (int off = 1; off < 16; off <<= 1) mx = fmaxf(mx, __shfl_xor(mx, off, 64));
    float e = expf(acc - mx);
    float s = e;
#pragma unroll
    for (int off = 1; off < 16; off <<= 1) s += __shfl_xor(s, off, 64);
    attn_s[w * 64 + lane] = e / s;
#pragma unroll
    for (int b = 0; b < NB; b++) {
        float a = 0.f;
#pragma unroll
        for (int l = 0; l < DLEN; l++) a += attn_s[w * 64 + b * 16 + l] * dreg[l];
        nf16[((size_t)b * NNODES + n) * G + lane] = __float2bfloat16(a);
    }
}
__global__ __launch_bounds__(256) void k_attn1(const int* flag, const int* node_descs,
                                               const void* emb_desc, const float* qg, bf16* nf16) {
    __shared__ __align__(16) float dsm[4 * DLEN * 68];
    __shared__ float attn_s[4 * 64];
    __shared__ __align__(16) float qgs[NB * G];
    if (*flag) attn1_body<bf16>(node_descs, emb_desc, qg, nf16, dsm, attn_s, qgs);
    else       attn1_body<float>(node_descs, emb_desc, qg, nf16, dsm, attn_s, qgs);
}

// ---------------- hb = nf16 @ bases[0] : tiled register GEMM, bf16 out -----
template <typename T>
__device__ void hbg_body(const bf16* nf16, const void* bases_, bf16* hb16,
                         float* as, float* bs) {
    int tid = threadIdx.x;
    const T* bases = (const T*)bases_;
    for (int i = tid; i < G * G; i += 256) bs[(i >> 6) * 68 + (i & 63)] = ld(bases, (size_t)i);
    size_t r0 = (size_t)blockIdx.x * 64;
    const bf4* gA = (const bf4*)(nf16 + r0 * G);
#pragma unroll
    for (int i = 0; i < 4; i++) {
        int c = tid + i * 256;
        int row = c >> 4, col4 = c & 15;
        bf4 v = gA[c];
        float4 f;
        f.x = __bfloat162float(v.x);
        f.y = __bfloat162float(v.y);
        f.z = __bfloat162float(v.z);
        f.w = __bfloat162float(v.w);
        *(float4*)&as[row * 68 + col4 * 4] = f;
    }
    __syncthreads();
    int tx = tid & 15, ty = tid >> 4;
    float acc[4][4];
#pragma unroll
    for (int i = 0; i < 4; i++)
#pragma unroll
        for (int j = 0; j < 4; j++) acc[i][j] = 0.f;
#pragma unroll 4
    for (int g4 = 0; g4 < 16; g4++) {
        float4 b0 = *(const float4*)&bs[(4 * g4 + 0) * 68 + tx * 4];
        float4 b1 = *(const float4*)&bs[(4 * g4 + 1) * 68 + tx * 4];
        float4 b2 = *(const float4*)&bs[(4 * g4 + 2) * 68 + tx * 4];
        float4 b3 = *(const float4*)&bs[(4 * g4 + 3) * 68 + tx * 4];
#pragma unroll
        for (int i = 0; i < 4; i++) {
            float4 a = *(const float4*)&as[(ty * 4 + i) * 68 + g4 * 4];
            acc[i][0] = fmaf(a.x, b0.x, acc[i][0]);
            acc[i][0] = fmaf(a.y, b1.x, acc[i][0]);
            acc[i][0] = fmaf(a.z, b2.x, acc[i][0]);
            acc[i][0] = fmaf(a.w, b3.x, acc[i][0]);
            acc[i][1] = fmaf(a.x, b0.y, acc[i][1]);
            acc[i][1] = fmaf(a.y, b1.y, acc[i][1]);
            acc[i][1] = fmaf(a.z, b2.y, acc[i][1]);
            acc[i][1] = fmaf(a.w, b3.y, acc[i][1]);
            acc[i][2] = fmaf(a.x, b0.z, acc[i][2]);
            acc[i][2] = fmaf(a.y, b1.z, acc[i][2]);
            acc[i][2] = fmaf(a.z, b2.z, acc[i][2]);
            acc[i][2] = fmaf(a.w, b3.z, acc[i][2]);
            acc[i][3] = fmaf(a.x, b0.w, acc[i][3]);
            acc[i][3] = fmaf(a.y, b1.w, acc[i][3]);
            acc[i][3] = fmaf(a.z, b2.w, acc[i][3]);
            acc[i][3] = fmaf(a.w, b3.w, acc[i][3]);
        }
    }
#pragma unroll
    for (int i = 0; i < 4; i++) {
        size_t r = r0 + ty * 4 + i;
        int b = (int)(r / NNODES);
        int n = (int)(r - (size_t)b * NNODES);
        bf4 o;
        o.x = __float2bfloat16(acc[i][0]);
        o.y = __float2bfloat16(acc[i][1]);
        o.z = __float2bfloat16(acc[i][2]);
        o.w = __float2bfloat16(acc[i][3]);
        *(bf4*)&hb16[((size_t)n * NB + b) * G + tx * 4] = o;
    }
}
__global__ __launch_bounds__(256) void k_hbg(const int* flag, const bf16* nf16,
                                             const void* bases, bf16* hb16) {
    __shared__ __align__(16) float as[64 * 68];
    __shared__ __align__(16) float bs[64 * 68];
    if (*flag) hbg_body<bf16>(nf16, bases, hb16, as, bs);
    else       hbg_body<float>(nf16, bases, hb16, as, bs);
}

// ---------------- RGCN aggregate: 16/8/4/1 unroll cascade ------------------
template <typename T>
__device__ void agg_body(const bf16* hb16, const int* offs, const int* ssrc,
                         const float* sco, const void* bias_, float* out_nf) {
    int tid = threadIdx.x;
    int b = tid >> 6, g = tid & 63;
    int dn = blockIdx.x;
    int s0 = offs[dn], s1 = offs[dn + 1];
    int boff = b * G + g;
    float acc = 0.f;
    int p = s0;
    for (; p + 15 < s1; p += 16) {
        int ix[16]; float co[16]; float x[16];
#pragma unroll
        for (int k = 0; k < 16; k++) { ix[k] = ssrc[p + k]; co[k] = sco[p + k]; }
#pragma unroll
        for (int k = 0; k < 16; k++) x[k] = __bfloat162float(hb16[(size_t)ix[k] * (NB * G) + boff]);
#pragma unroll
        for (int k = 0; k < 16; k++) acc += co[k] * x[k];
    }
    for (; p + 7 < s1; p += 8) {
        int ix[8]; float co[8]; float x[8];
#pragma unroll
        for (int k = 0; k < 8; k++) { ix[k] = ssrc[p + k]; co[k] = sco[p + k]; }
#pragma unroll
        for (int k = 0; k < 8; k++) x[k] = __bfloat162float(hb16[(size_t)ix[k] * (NB * G) + boff]);
#pragma unroll
        for (int k = 0; k < 8; k++) acc += co[k] * x[k];
    }
    for (; p + 3 < s1; p += 4) {
        int ix[4]; float co[4]; float x[4];
#pragma unroll
        for (int k = 0; k < 4; k++) { ix[k] = ssrc[p + k]; co[k] = sco[p + k]; }
#pragma unroll
        for (int k = 0; k < 4; k++) x[k] = __bfloat162float(hb16[(size_t)ix[k] * (NB * G) + boff]);
#pragma unroll
        for (int k = 0; k < 4; k++) acc += co[k] * x[k];
    }
    for (; p < s1; p++)
        acc += sco[p] * __bfloat162float(hb16[(size_t)ssrc[p] * (NB * G) + boff]);
    out_nf[((size_t)b * NNODES + dn) * G + g] = relu(acc + ld((const T*)bias_, (size_t)g));
}
__global__ __launch_bounds__(256) void k_agg(const int* flag, const bf16* hb16, const int* offs,
                                             const int* ssrc, const float* sco,
                                             const void* bias, float* out_nf) {
    if (*flag) agg_body<bf16>(hb16, offs, ssrc, sco, bias, out_nf);
    else       agg_body<float>(hb16, offs, ssrc, sco, bias, out_nf);
}

// ---------------- attn2: single-pass online softmax, NO atomics ------------
__device__ __forceinline__ void a2_update(float& M, float& L, float& A, float p, float v) {
    if (p > M) {
        float s = expf(M - p);
        A *= s; L *= s; M = p;
    }
    float e = expf(p - M);
    L += e;
    A = fmaf(e, v, A);
}

__global__ __launch_bounds__(256) void k_attn2(const float* rg, const float* qg, float* part) {
    int tid = threadIdx.x;
    int b = tid >> 6, lane = tid & 63;
    float q = qg[b * G + lane];
    int chunk = (NNODES + A2BLK - 1) / A2BLK;
    int n0 = blockIdx.x * chunk;
    int n1 = min(n0 + chunk, NNODES);
    const float* base = rg + (size_t)b * NNODES * G + lane;
    float M = -3.4e38f, L = 0.f, A = 0.f;
    int n = n0;
    for (; n + 3 < n1; n += 4) {
        float v0 = base[(size_t)(n + 0) * G];
        float v1 = base[(size_t)(n + 1) * G];
        float v2 = base[(size_t)(n + 2) * G];
        float v3 = base[(size_t)(n + 3) * G];
        float p0 = v0 * q, p1 = v1 * q, p2 = v2 * q, p3 = v3 * q;
#pragma unroll
        for (int off = 32; off >= 1; off >>= 1) {
            p0 += __shfl_xor(p0, off, 64);
            p1 += __shfl_xor(p1, off, 64);
            p2 += __shfl_xor(p2, off, 64);
            p3 += __shfl_xor(p3, off, 64);
        }
        a2_update(M, L, A, p0, v0);
        a2_update(M, L, A, p1, v1);
        a2_update(M, L, A, p2, v2);
        a2_update(M, L, A, p3, v3);
    }
    for (; n < n1; n++) {
        float v = base[(size_t)n * G];
        float p = v * q;
#pragma unroll
        for (int off = 32; off >= 1; off >>= 1) p += __shfl_xor(p, off, 64);
        a2_update(M, L, A, p, v);
    }
    float* pp = part + ((size_t)blockIdx.x * NB + b) * 66;
    if (lane == 0) { pp[0] = M; pp[1] = L; }
    pp[2 + lane] = A;
}

// stage-1 merge: A2BLK -> A2MID partials
__global__ void k_attn2m(const float* part, float* part2) {
    int tid = threadIdx.x;
    int b = tid >> 6, lane = tid & 63;
    int grp = blockIdx.x;
    float M = -3.4e38f, L = 0.f, A = 0.f;
    for (int i = 0; i < A2BLK / A2MID; i++) {
        const float* pp = part + ((size_t)(grp * (A2BLK / A2MID) + i) * NB + b) * 66;
        float m = pp[0], l = pp[1], a = pp[2 + lane];
        float mn = fmaxf(M, m);
        float e1 = expf(M - mn), e2 = expf(m - mn);
        A = A * e1 + a * e2;
        L = L * e1 + l * e2;
        M = mn;
    }
    float* pq = part2 + ((size_t)grp * NB + b) * 66;
    if (lane == 0) { pq[0] = M; pq[1] = L; }
    pq[2 + lane] = A;
}

// ---------------- fc1 with inline final attn2 merge ----------------
template <typename T>
__device__ void fc1_body(const float* part2, const float* qemb,
                         const void* W1_, const void* b1_, float* hid,
                         float* feat, float* psum) {
    int tid = threadIdx.x;
    int b = blockIdx.x >> 4, tile = blockIdx.x & 15;
    if (tid < 64) {
        // final merge of A2MID partials for feature lane=tid (all threads share M/L chain)
        float M = -3.4e38f, L = 0.f, A = 0.f;
        for (int p = 0; p < A2MID; p++) {
            const float* pp = part2 + ((size_t)p * NB + b) * 66;
            float m = pp[0], l = pp[1], a = pp[2 + tid];
            float mn = fmaxf(M, m);
            float e1 = expf(M - mn), e2 = expf(m - mn);
            A = A * e1 + a * e2;
            L = L * e1 + l * e2;
            M = mn;
        }
        feat[tid] = A / L;
        feat[tid + 256] = qemb[b * DH + tid + 192];
    } else {
        feat[tid] = qemb[b * DH + tid - G];
    }
    __syncthreads();
    int lane = tid & 63, phase = tid >> 6;
    int u = tile * 64 + lane;
    const T* W1 = (const T*)W1_;
    float acc = 0.f;
#pragma unroll 8
    for (int kk = 0; kk < 80; kk++) {
        int k = phase * 80 + kk;
        acc += feat[k] * ld(W1, (size_t)k * 1024 + u);
    }
    psum[tid] = acc;
    __syncthreads();
    if (phase == 0) {
        float tot = psum[lane] + psum[64 + lane] + psum[128 + lane] + psum[192 + lane]
                  + ld((const T*)b1_, (size_t)u);
        hid[b * 1024 + u] = relu(tot);
    }
}
__global__ __launch_bounds__(256) void k_fc1(const int* flag, const float* part2,
                                             const float* qemb, const void* W1, const void* b1,
                                             float* hid) {
    __shared__ float feat[320];
    __shared__ float psum[256];
    if (*flag) fc1_body<bf16>(part2, qemb, W1, b1, hid, feat, psum);
    else       fc1_body<float>(part2, qemb, W1, b1, hid, feat, psum);
}

// ---------------- classifier: fc2, parallel k-reduction ----------------
template <typename T>
__device__ void fc2_body(const float* hid, const void* W2_, const void* b2_, void* out_,
                         float* hs, float* psum) {
    int tid = threadIdx.x;
    int b = blockIdx.x >> 5, tile = blockIdx.x & 31;
#pragma unroll
    for (int i = 0; i < 4; i++) hs[tid + 256 * i] = hid[b * 1024 + tid + 256 * i];
    __syncthreads();
    int lane = tid & 63, phase = tid >> 6;
    int c = tile * 64 + lane;
    bool ok = (c < NCLS);
    const T* W2 = (const T*)W2_;
    float acc = 0.f;
    if (ok) {
#pragma unroll 8
        for (int uu = 0; uu < 256; uu++) {
            int u = phase * 256 + uu;
            acc += hs[u] * ld(W2, (size_t)u * NCLS + c);
        }
    }
    psum[tid] = acc;
    __syncthreads();
    if (phase == 0 && ok) {
        float tot = psum[lane] + psum[64 + lane] + psum[128 + lane] + psum[192 + lane]
                  + ld((const T*)b2_, (size_t)c);
        st((T*)out_, (size_t)b * NCLS + c, tot);
    }
}
__global__ __launch_bounds__(256) void k_fc2(const int* flag, const float* hid,
                                             const void* W2, const void* b2v, void* out) {
    __shared__ float hs[1024];
    __shared__ float psum[256];
    if (*flag) fc2_body<bf16>(hid, W2, b2v, out, hs, psum);
    else       fc2_body<float>(hid, W2, b2v, out, hs, psum);
}

extern "C" void kernel_launch(void* const* d_in, const int* in_sizes, int n_in,
                              void* d_out, int out_size, void* d_ws, size_t ws_size,
                              hipStream_t stream) {
    const int* questions  = (const int*)d_in[0];
    const int* node_descs = (const int*)d_in[1];
    const int* edge_src   = (const int*)d_in[2];
    const int* edge_dst   = (const int*)d_in[3];
    const int* edge_type  = (const int*)d_in[4];
    const void* emb_word  = d_in[5];
    const void* emb_desc  = d_in[6];
    const void* Wx_f = d_in[7];
    const void* Wh_f = d_in[8];
    const void* bx_f = d_in[9];
    const void* bh_f = d_in[10];
    const void* Wx_b = d_in[11];
    const void* Wh_b = d_in[12];
    const void* bx_b = d_in[13];
    const void* bh_b = d_in[14];
    const void* W_hg = d_in[15];
    const void* b_hg = d_in[16];
    const void* bases = d_in[17];
    const void* w_comp = d_in[18];
    const void* rgcn_bias = d_in[19];
    const void* W1 = d_in[20];
    const void* b1 = d_in[21];
    const void* W2 = d_in[22];
    const void* b2 = d_in[23];

    float* ws = (float*)d_ws;
    int*      flag  = (int*)(ws + OFF_FLAG);
    float*    gx    = ws + OFF_GX;
    float*    whf   = ws + OFF_WHF;
    float*    qemb  = ws + OFF_QEMB;
    float*    qg    = ws + OFF_QG;
    float*    nf    = ws + OFF_NF;
    bf16*     nf16  = (bf16*)(ws + OFF_NF);
    bf16*     hb16  = (bf16*)(ws + OFF_HB);
    float*    part  = ws + OFF_PART;
    float*    part2 = ws + OFF_PART2;
    int*      deg   = (int*)(ws + OFF_DEG);
    int*      offs  = (int*)(ws + OFF_OFFS);
    int*      cur   = (int*)(ws + OFF_CUR);
    int*      ssrc  = (int*)(ws + OFF_SSRC);
    float*    sco   = ws + OFF_SCO;
    float*    hid   = ws + OFF_HID;

    hipLaunchKernelGGL(k_init, dim3(80), dim3(256), 0, stream,
                       (const unsigned*)emb_word, flag, deg);
    hipLaunchKernelGGL(k_prep, dim3(NBLK_CVT + NBLK_GX + NBLK_HIST), dim3(256), 0, stream,
                       flag, Wh_f, Wh_b, whf,
                       questions, emb_word, Wx_f, bx_f, Wx_b, bx_b, gx,
                       edge_dst, deg);
    hipLaunchKernelGGL(k_gru, dim3(8), dim3(2 * G3), 0, stream,
                       flag, questions, gx, whf, bh_f, bh_b, qemb);
    hipLaunchKernelGGL(k_scan_qg, dim3(2), dim3(1024), 0, stream,
                       flag, deg, offs, cur, qemb, W_hg, b_hg, qg);
    hipLaunchKernelGGL(k_scatter, dim3((NEDGES + 255) / 256), dim3(256), 0, stream,
                       flag, edge_src, edge_dst, edge_type, w_comp, cur, ssrc, sco);
    hipLaunchKernelGGL(k_attn1, dim3(NNODES / 4), dim3(256), 0, stream,
                       flag, node_descs, emb_desc, qg, nf16);
    hipLaunchKernelGGL(k_hbg, dim3(NB * NNODES / 64), dim3(256), 0, stream,
                       flag, nf16, bases, hb16);
    hipLaunchKernelGGL(k_agg, dim3(NNODES), dim3(256), 0, stream,
                       flag, hb16, offs, ssrc, sco, rgcn_bias, nf);
    hipLaunchKernelGGL(k_attn2, dim3(A2BLK), dim3(256), 0, stream, nf, qg, part);
    hipLaunchKernelGGL(k_attn2m, dim3(A2MID), dim3(256), 0, stream, part, part2);
    hipLaunchKernelGGL(k_fc1, dim3(NB * 16), dim3(256), 0, stream,
                       flag, part2, qemb, W1, b1, hid);
    hipLaunchKernelGGL(k_fc2, dim3(NB * 32), dim3(256), 0, stream,
                       flag, hid, W2, b2, d_out);
}

// Round 11
// 334.787 us; speedup vs baseline: 2.1834x; 1.0434x over previous
//
#include <hip/hip_runtime.h>
#include <hip/hip_bf16.h>
#include <math.h>

typedef __hip_bfloat16 bf16;

#define NNODES 20000
#define NEDGES 320000
#define DLEN   16
#define G      64
#define DW     300
#define DH     256
#define HD     128
#define G3     384
#define NCLS   2000
#define NB     4
#define TT     32
#define A2BLK  1024  // attn2 partial blocks
#define A2MID  64    // stage-1 merge outputs

#define NBLK_CVT  384
#define NBLK_GX2  1536   // 256 rows (d,b,step) x 6 j-tiles of 64
#define NBLK_HIST ((NEDGES + 255) / 256)

__device__ __forceinline__ float ld(const float* p, size_t i) { return p[i]; }
__device__ __forceinline__ float ld(const bf16* p, size_t i) { return __bfloat162float(p[i]); }
__device__ __forceinline__ void st(float* p, size_t i, float v) { p[i] = v; }
__device__ __forceinline__ void st(bf16* p, size_t i, float v) { p[i] = __float2bfloat16(v); }
__device__ __forceinline__ float relu(float x) { return (x < 0.f) ? 0.f : x; }

struct __align__(8) bf4 { bf16 x, y, z, w; };

// ---------------- workspace layout (float words) ----------------
#define OFF_FLAG  ((size_t)0)                         // 4
#define OFF_GX    (OFF_FLAG + 4)                      // 98304
#define OFF_WHF   (OFF_GX   + 2*NB*TT*G3)             // 98304
#define OFF_QEMB  (OFF_WHF  + 2*HD*G3)                // 1024
#define OFF_QG    (OFF_QEMB + NB*DH)                  // 256
#define OFF_NF    (OFF_QG   + NB*G)                   // pre:bf16 / post:fp32
#define OFF_HB    (OFF_NF   + (size_t)NB*NNODES*G)    // bf16 [n][b][g]
#define OFF_PART  (OFF_HB   + (size_t)NB*NNODES*G)    // 1024*4*66
#define OFF_PART2 (OFF_PART + (size_t)A2BLK*NB*66)    // 64*4*66
#define OFF_DEG   (OFF_PART2+ (size_t)A2MID*NB*66)    // int 20000
#define OFF_OFFS  (OFF_DEG  + NNODES)                 // int 20008
#define OFF_CUR   (OFF_OFFS + NNODES + 8)             // int 20000
#define OFF_SSRC  (OFF_CUR  + NNODES)                 // int 320000
#define OFF_SCO   (OFF_SSRC + NEDGES)                 // float 320000
#define OFF_HID   (OFF_SCO  + NEDGES)                 // 4096

// ---------------- init: dtype sniff + zero deg ----------------
__global__ void k_init(const unsigned* probe, int* flag, int* deg) {
    int i = blockIdx.x * 256 + threadIdx.x;
    if (i < NNODES) deg[i] = 0;
    if (blockIdx.x == 0 && threadIdx.x < 64) {
        int cnt = 0;
        for (int k = threadIdx.x; k < 4096; k += 64) {
            unsigned lo = probe[k] & 0xFFFFu;
            unsigned e = (lo >> 7) & 0xFFu;
            cnt += (e >= 0x66u && e <= 0x7Eu) ? 1 : 0;
        }
#pragma unroll
        for (int off = 1; off < 64; off <<= 1) cnt += __shfl_xor(cnt, off, 64);
        if (threadIdx.x == 0) *flag = (2 * cnt > 4096) ? 1 : 0;   // 1 = bf16
    }
}

// ---------------- fused prep: cvt | gx (K-split) | hist --------------------
template <typename T>
__device__ void cvt_body(int id, const void* Whf_, const void* Whb_, float* whf) {
    if (id >= 2 * HD * G3) return;
    int d = id / (HD * G3), r = id % (HD * G3);
    const T* W = (const T*)(d ? Whb_ : Whf_);
    whf[id] = ld(W, (size_t)r);
}

// gx K-split: block = 64 j-lanes x 4 k-phases of 75; emb row staged in LDS.
// bx2 in [0,1536): rid = bx2/6 (= (d*NB+b)*TT + step), jt = bx2%6.
template <typename T>
__device__ void gx2_body(int bx2, const int* questions, const void* emb_word_,
                         const void* Wxf_, const void* bxf_,
                         const void* Wxb_, const void* bxb_, float* gx,
                         float* xs, float* psum) {
    int tid = threadIdx.x;
    int jt = bx2 % 6;
    int rid = bx2 / 6;                  // 0..255
    int step = rid & 31;
    int b = (rid >> 5) & 3;
    int d = rid >> 7;
    int t = d ? (TT - 1 - step) : step;
    int tok = questions[b * TT + t];
    const T* row = (const T*)emb_word_ + (size_t)tok * DW;
    for (int k = tid; k < DW; k += 256) xs[k] = ld(row, (size_t)k);
    __syncthreads();
    int lane = tid & 63, phase = tid >> 6;
    int j = jt * 64 + lane;
    const T* Wx = (const T*)(d ? Wxb_ : Wxf_);
    float acc = 0.f;
    int k0 = phase * 75;
#pragma unroll 15
    for (int kk = 0; kk < 75; kk++) {
        int k = k0 + kk;
        acc += xs[k] * ld(Wx, (size_t)k * G3 + j);
    }
    psum[tid] = acc;
    __syncthreads();
    if (phase == 0) {
        const T* bx = (const T*)(d ? bxb_ : bxf_);
        float tot = ld(bx, (size_t)j)
                  + psum[lane] + psum[64 + lane] + psum[128 + lane] + psum[192 + lane];
        gx[(size_t)rid * G3 + j] = tot;
    }
}

__global__ void k_prep(const int* flag, const void* Whf, const void* Whb, float* whf,
                       const int* questions, const void* emb_word,
                       const void* Wxf, const void* bxf,
                       const void* Wxb, const void* bxb, float* gx,
                       const int* edge_dst, int* deg) {
    __shared__ float xs[DW];
    __shared__ float psum[256];
    int bx = blockIdx.x;
    int tid = threadIdx.x;
    if (bx < NBLK_CVT) {
        int id = bx * 256 + tid;
        if (*flag) cvt_body<bf16>(id, Whf, Whb, whf);
        else       cvt_body<float>(id, Whf, Whb, whf);
    } else if (bx < NBLK_CVT + NBLK_GX2) {
        int bx2 = bx - NBLK_CVT;
        if (*flag) gx2_body<bf16>(bx2, questions, emb_word, Wxf, bxf, Wxb, bxb, gx, xs, psum);
        else       gx2_body<float>(bx2, questions, emb_word, Wxf, bxf, Wxb, bxb, gx, xs, psum);
    } else {
        int e = (bx - NBLK_CVT - NBLK_GX2) * 256 + tid;
        if (e < NEDGES) atomicAdd(&deg[edge_dst[e]], 1);
    }
}

// ---------------- GRU scan: block per (d,b), Wh register-resident ----------
template <typename T>
__device__ void gru_body(const int* questions, const float* gx, const float* whf,
                         const void* bhf_, const void* bhb_, float* qemb,
                         float* hsm, float* ghs) {
    int tid = threadIdx.x;
    int d = blockIdx.x >> 2, b = blockIdx.x & 3;
    int half = tid / G3, j = tid - half * G3;
    const float* wh = whf + (size_t)d * HD * G3 + (size_t)half * 64 * G3 + j;
    float w[64];
#pragma unroll
    for (int m = 0; m < 64; m++) w[m] = wh[(size_t)m * G3];
    const T* bh = (const T*)(d ? bhb_ : bhf_);
    float bhj = (half == 0) ? ld(bh, (size_t)j) : 0.f;
    if (tid < HD) hsm[tid] = 0.f;
    const float* gxb = gx + ((size_t)(d * NB + b)) * TT * G3;
    __syncthreads();
    const float4* h4 = (const float4*)(hsm + half * 64);
    for (int step = 0; step < TT; step++) {
        float acc = bhj;
#pragma unroll
        for (int m4 = 0; m4 < 16; m4++) {
            float4 hp = h4[m4];
            acc = fmaf(hp.x, w[4 * m4 + 0], acc);
            acc = fmaf(hp.y, w[4 * m4 + 1], acc);
            acc = fmaf(hp.z, w[4 * m4 + 2], acc);
            acc = fmaf(hp.w, w[4 * m4 + 3], acc);
        }
        ghs[half * G3 + j] = acc;
        __syncthreads();
        if (tid < HD) {
            const float* gxp = gxb + step * G3;
            int t = d ? (TT - 1 - step) : step;
            bool msk = questions[b * TT + t] != 0;
            float gr = ghs[tid] + ghs[G3 + tid];
            float gz = ghs[HD + tid] + ghs[G3 + HD + tid];
            float gn = ghs[2 * HD + tid] + ghs[G3 + 2 * HD + tid];
            float r = 1.f / (1.f + expf(-(gxp[tid] + gr)));
            float z = 1.f / (1.f + expf(-(gxp[HD + tid] + gz)));
            float n = tanhf(gxp[2 * HD + tid] + r * gn);
            float hn = (1.f - z) * n + z * hsm[tid];
            if (msk) hsm[tid] = hn;
        }
        __syncthreads();
    }
    if (tid < HD) qemb[b * DH + d * HD + tid] = hsm[tid];
}
__global__ __launch_bounds__(2 * G3) void k_gru(const int* flag, const int* questions,
                                                const float* gx, const float* whf,
                                                const void* bhf, const void* bhb, float* qemb) {
    __shared__ __align__(16) float hsm[HD];
    __shared__ float ghs[2 * G3];
    if (*flag) gru_body<bf16>(questions, gx, whf, bhf, bhb, qemb, hsm, ghs);
    else       gru_body<float>(questions, gx, whf, bhf, bhb, qemb, hsm, ghs);
}

// ---------------- fused: CSR scan (block 0) + qg (block 1) ----------------
template <typename T>
__device__ void qg_body(const float* qemb, const void* W_hg_, const void* b_hg_, float* qg) {
    int tid = threadIdx.x;
    if (tid >= 256) return;
    int b = tid >> 6, g = tid & 63;
    const T* W = (const T*)W_hg_;
    float acc = ld((const T*)b_hg_, (size_t)g);
#pragma unroll 4
    for (int i = 0; i < DH; i++) acc += qemb[b * DH + i] * ld(W, (size_t)i * G + g);
    qg[b * G + g] = acc;
}

__global__ __launch_bounds__(1024) void k_scan_qg(const int* flag, const int* deg,
                                                  int* offs, int* cur,
                                                  const float* qemb, const void* W_hg,
                                                  const void* b_hg, float* qg) {
    if (blockIdx.x == 1) {
        if (*flag) qg_body<bf16>(qemb, W_hg, b_hg, qg);
        else       qg_body<float>(qemb, W_hg, b_hg, qg);
        return;
    }
    __shared__ int wtot[16];
    int t = threadIdx.x;
    int lane = t & 63, wave = t >> 6;
    int c[20];
    int base = t * 20;
    int run = 0;
#pragma unroll
    for (int i = 0; i < 20; i++) {
        int v = (base + i < NNODES) ? deg[base + i] : 0;
        c[i] = run;
        run += v;
    }
    int myrun = run;
    int inc = myrun;
#pragma unroll
    for (int off = 1; off < 64; off <<= 1) {
        int u = __shfl_up(inc, off, 64);
        if (lane >= off) inc += u;
    }
    if (lane == 63) wtot[wave] = inc;
    __syncthreads();
    if (t == 0) {
        int s = 0;
#pragma unroll
        for (int i = 0; i < 16; i++) { int v = wtot[i]; wtot[i] = s; s += v; }
        offs[NNODES] = s;
    }
    __syncthreads();
    int ebase = wtot[wave] + inc - myrun;
#pragma unroll
    for (int i = 0; i < 20; i++) {
        if (base + i < NNODES) {
            offs[base + i] = ebase + c[i];
            cur[base + i] = ebase + c[i];
        }
    }
}

template <typename T>
__device__ void scatter_body(const int* src, const int* dst, const int* typ,
                             const void* w_comp_, int* cur, int* ssrc, float* sco) {
    int e = blockIdx.x * 256 + threadIdx.x;
    if (e < NEDGES) {
        int dd = dst[e];
        int pos = atomicAdd(&cur[dd], 1);
        ssrc[pos] = src[e];
        sco[pos] = ld((const T*)w_comp_, (size_t)typ[e]);
    }
}
__global__ void k_scatter(const int* flag, const int* src, const int* dst, const int* typ,
                          const void* w_comp, int* cur, int* ssrc, float* sco) {
    if (*flag) scatter_body<bf16>(src, dst, typ, w_comp, cur, ssrc, sco);
    else       scatter_body<float>(src, dst, typ, w_comp, cur, ssrc, sco);
}

// ---------------- attn1 softmax + node features -> bf16 nf ----------------
template <typename T>
__device__ void attn1_body(const int* node_descs, const void* emb_desc_,
                           const float* qg, bf16* nf16,
                           float* dsm, float* attn_s, float* qgs) {
    int tid = threadIdx.x;
    if (tid < NB * G) qgs[tid] = qg[tid];
    __syncthreads();
    const T* emb_desc = (const T*)emb_desc_;
    int w = tid >> 6, lane = tid & 63;
    int n = blockIdx.x * 4 + w;
    float dreg[DLEN];
    const int* nd = node_descs + n * DLEN;
    float* dw = dsm + (size_t)w * DLEN * 68;
#pragma unroll
    for (int l = 0; l < DLEN; l++) {
        int idx = nd[l];
        float v = ld(emb_desc, (size_t)idx * G + lane);
        dreg[l] = v;
        dw[l * 68 + lane] = v;
    }
    int lb = lane >> 4, ll = lane & 15;
    float acc = 0.f;
#pragma unroll
    for (int i = 0; i < 16; i++) {
        float4 a = *(const float4*)&dw[ll * 68 + 4 * i];
        float4 q = *(const float4*)&qgs[lb * G + 4 * i];
        acc = fmaf(a.x, q.x, acc);
        acc = fmaf(a.y, q.y, acc);
        acc = fmaf(a.z, q.z, acc);
        acc = fmaf(a.w, q.w, acc);
    }
    float mx = acc;
#pragma unroll
    for (int off = 1; off < 16; off <<= 1) mx = fmaxf(mx, __shfl_xor(mx, off, 64));
    float e = expf(acc - mx);
    float s = e;
#pragma unroll
    for (int off = 1; off < 16; off <<= 1) s += __shfl_xor(s, off, 64);
    attn_s[w * 64 + lane] = e / s;
#pragma unroll
    for (int b = 0; b < NB; b++) {
        float a = 0.f;
#pragma unroll
        for (int l = 0; l < DLEN; l++) a += attn_s[w * 64 + b * 16 + l] * dreg[l];
        nf16[((size_t)b * NNODES + n) * G + lane] = __float2bfloat16(a);
    }
}
__global__ __launch_bounds__(256) void k_attn1(const int* flag, const int* node_descs,
                                               const void* emb_desc, const float* qg, bf16* nf16) {
    __shared__ __align__(16) float dsm[4 * DLEN * 68];
    __shared__ float attn_s[4 * 64];
    __shared__ __align__(16) float qgs[NB * G];
    if (*flag) attn1_body<bf16>(node_descs, emb_desc, qg, nf16, dsm, attn_s, qgs);
    else       attn1_body<float>(node_descs, emb_desc, qg, nf16, dsm, attn_s, qgs);
}

// ---------------- hb = nf16 @ bases[0] : tiled register GEMM, bf16 out -----
template <typename T>
__device__ void hbg_body(const bf16* nf16, const void* bases_, bf16* hb16,
                         float* as, float* bs) {
    int tid = threadIdx.x;
    const T* bases = (const T*)bases_;
    for (int i = tid; i < G * G; i += 256) bs[(i >> 6) * 68 + (i & 63)] = ld(bases, (size_t)i);
    size_t r0 = (size_t)blockIdx.x * 64;
    const bf4* gA = (const bf4*)(nf16 + r0 * G);
#pragma unroll
    for (int i = 0; i < 4; i++) {
        int c = tid + i * 256;
        int row = c >> 4, col4 = c & 15;
        bf4 v = gA[c];
        float4 f;
        f.x = __bfloat162float(v.x);
        f.y = __bfloat162float(v.y);
        f.z = __bfloat162float(v.z);
        f.w = __bfloat162float(v.w);
        *(float4*)&as[row * 68 + col4 * 4] = f;
    }
    __syncthreads();
    int tx = tid & 15, ty = tid >> 4;
    float acc[4][4];
#pragma unroll
    for (int i = 0; i < 4; i++)
#pragma unroll
        for (int j = 0; j < 4; j++) acc[i][j] = 0.f;
#pragma unroll 4
    for (int g4 = 0; g4 < 16; g4++) {
        float4 b0 = *(const float4*)&bs[(4 * g4 + 0) * 68 + tx * 4];
        float4 b1 = *(const float4*)&bs[(4 * g4 + 1) * 68 + tx * 4];
        float4 b2 = *(const float4*)&bs[(4 * g4 + 2) * 68 + tx * 4];
        float4 b3 = *(const float4*)&bs[(4 * g4 + 3) * 68 + tx * 4];
#pragma unroll
        for (int i = 0; i < 4; i++) {
            float4 a = *(const float4*)&as[(ty * 4 + i) * 68 + g4 * 4];
            acc[i][0] = fmaf(a.x, b0.x, acc[i][0]);
            acc[i][0] = fmaf(a.y, b1.x, acc[i][0]);
            acc[i][0] = fmaf(a.z, b2.x, acc[i][0]);
            acc[i][0] = fmaf(a.w, b3.x, acc[i][0]);
            acc[i][1] = fmaf(a.x, b0.y, acc[i][1]);
            acc[i][1] = fmaf(a.y, b1.y, acc[i][1]);
            acc[i][1] = fmaf(a.z, b2.y, acc[i][1]);
            acc[i][1] = fmaf(a.w, b3.y, acc[i][1]);
            acc[i][2] = fmaf(a.x, b0.z, acc[i][2]);
            acc[i][2] = fmaf(a.y, b1.z, acc[i][2]);
            acc[i][2] = fmaf(a.z, b2.z, acc[i][2]);
            acc[i][2] = fmaf(a.w, b3.z, acc[i][2]);
            acc[i][3] = fmaf(a.x, b0.w, acc[i][3]);
            acc[i][3] = fmaf(a.y, b1.w, acc[i][3]);
            acc[i][3] = fmaf(a.z, b2.w, acc[i][3]);
            acc[i][3] = fmaf(a.w, b3.w, acc[i][3]);
        }
    }
#pragma unroll
    for (int i = 0; i < 4; i++) {
        size_t r = r0 + ty * 4 + i;
        int b = (int)(r / NNODES);
        int n = (int)(r - (size_t)b * NNODES);
        bf4 o;
        o.x = __float2bfloat16(acc[i][0]);
        o.y = __float2bfloat16(acc[i][1]);
        o.z = __float2bfloat16(acc[i][2]);
        o.w = __float2bfloat16(acc[i][3]);
        *(bf4*)&hb16[((size_t)n * NB + b) * G + tx * 4] = o;
    }
}
__global__ __launch_bounds__(256) void k_hbg(const int* flag, const bf16* nf16,
                                             const void* bases, bf16* hb16) {
    __shared__ __align__(16) float as[64 * 68];
    __shared__ __align__(16) float bs[64 * 68];
    if (*flag) hbg_body<bf16>(nf16, bases, hb16, as, bs);
    else       hbg_body<float>(nf16, bases, hb16, as, bs);
}

// ---------------- RGCN aggregate: 16/8/4/1 unroll cascade ------------------
template <typename T>
__device__ void agg_body(const bf16* hb16, const int* offs, const int* ssrc,
                         const float* sco, const void* bias_, float* out_nf) {
    int tid = threadIdx.x;
    int b = tid >> 6, g = tid & 63;
    int dn = blockIdx.x;
    int s0 = offs[dn], s1 = offs[dn + 1];
    int boff = b * G + g;
    float acc = 0.f;
    int p = s0;
    for (; p + 15 < s1; p += 16) {
        int ix[16]; float co[16]; float x[16];
#pragma unroll
        for (int k = 0; k < 16; k++) { ix[k] = ssrc[p + k]; co[k] = sco[p + k]; }
#pragma unroll
        for (int k = 0; k < 16; k++) x[k] = __bfloat162float(hb16[(size_t)ix[k] * (NB * G) + boff]);
#pragma unroll
        for (int k = 0; k < 16; k++) acc += co[k] * x[k];
    }
    for (; p + 7 < s1; p += 8) {
        int ix[8]; float co[8]; float x[8];
#pragma unroll
        for (int k = 0; k < 8; k++) { ix[k] = ssrc[p + k]; co[k] = sco[p + k]; }
#pragma unroll
        for (int k = 0; k < 8; k++) x[k] = __bfloat162float(hb16[(size_t)ix[k] * (NB * G) + boff]);
#pragma unroll
        for (int k = 0; k < 8; k++) acc += co[k] * x[k];
    }
    for (; p + 3 < s1; p += 4) {
        int ix[4]; float co[4]; float x[4];
#pragma unroll
        for (int k = 0; k < 4; k++) { ix[k] = ssrc[p + k]; co[k] = sco[p + k]; }
#pragma unroll
        for (int k = 0; k < 4; k++) x[k] = __bfloat162float(hb16[(size_t)ix[k] * (NB * G) + boff]);
#pragma unroll
        for (int k = 0; k < 4; k++) acc += co[k] * x[k];
    }
    for (; p < s1; p++)
        acc += sco[p] * __bfloat162float(hb16[(size_t)ssrc[p] * (NB * G) + boff]);
    out_nf[((size_t)b * NNODES + dn) * G + g] = relu(acc + ld((const T*)bias_, (size_t)g));
}
__global__ __launch_bounds__(256) void k_agg(const int* flag, const bf16* hb16, const int* offs,
                                             const int* ssrc, const float* sco,
                                             const void* bias, float* out_nf) {
    if (*flag) agg_body<bf16>(hb16, offs, ssrc, sco, bias, out_nf);
    else       agg_body<float>(hb16, offs, ssrc, sco, bias, out_nf);
}

// ---------------- attn2: single-pass online softmax, NO atomics ------------
__device__ __forceinline__ void a2_update(float& M, float& L, float& A, float p, float v) {
    if (p > M) {
        float s = expf(M - p);
        A *= s; L *= s; M = p;
    }
    float e = expf(p - M);
    L += e;
    A = fmaf(e, v, A);
}

__global__ __launch_bounds__(256) void k_attn2(const float* rg, const float* qg, float* part) {
    int tid = threadIdx.x;
    int b = tid >> 6, lane = tid & 63;
    float q = qg[b * G + lane];
    int chunk = (NNODES + A2BLK - 1) / A2BLK;
    int n0 = blockIdx.x * chunk;
    int n1 = min(n0 + chunk, NNODES);
    const float* base = rg + (size_t)b * NNODES * G + lane;
    float M = -3.4e38f, L = 0.f, A = 0.f;
    int n = n0;
    for (; n + 3 < n1; n += 4) {
        float v0 = base[(size_t)(n + 0) * G];
        float v1 = base[(size_t)(n + 1) * G];
        float v2 = base[(size_t)(n + 2) * G];
        float v3 = base[(size_t)(n + 3) * G];
        float p0 = v0 * q, p1 = v1 * q, p2 = v2 * q, p3 = v3 * q;
#pragma unroll
        for (int off = 32; off >= 1; off >>= 1) {
            p0 += __shfl_xor(p0, off, 64);
            p1 += __shfl_xor(p1, off, 64);
            p2 += __shfl_xor(p2, off, 64);
            p3 += __shfl_xor(p3, off, 64);
        }
        a2_update(M, L, A, p0, v0);
        a2_update(M, L, A, p1, v1);
        a2_update(M, L, A, p2, v2);
        a2_update(M, L, A, p3, v3);
    }
    for (; n < n1; n++) {
        float v = base[(size_t)n * G];
        float p = v * q;
#pragma unroll
        for (int off = 32; off >= 1; off >>= 1) p += __shfl_xor(p, off, 64);
        a2_update(M, L, A, p, v);
    }
    float* pp = part + ((size_t)blockIdx.x * NB + b) * 66;
    if (lane == 0) { pp[0] = M; pp[1] = L; }
    pp[2 + lane] = A;
}

// stage-1 merge: A2BLK -> A2MID partials
__global__ void k_attn2m(const float* part, float* part2) {
    int tid = threadIdx.x;
    int b = tid >> 6, lane = tid & 63;
    int grp = blockIdx.x;
    float M = -3.4e38f, L = 0.f, A = 0.f;
    for (int i = 0; i < A2BLK / A2MID; i++) {
        const float* pp = part + ((size_t)(grp * (A2BLK / A2MID) + i) * NB + b) * 66;
        float m = pp[0], l = pp[1], a = pp[2 + lane];
        float mn = fmaxf(M, m);
        float e1 = expf(M - mn), e2 = expf(m - mn);
        A = A * e1 + a * e2;
        L = L * e1 + l * e2;
        M = mn;
    }
    float* pq = part2 + ((size_t)grp * NB + b) * 66;
    if (lane == 0) { pq[0] = M; pq[1] = L; }
    pq[2 + lane] = A;
}

// ---------------- fc1 with inline final attn2 merge ----------------
template <typename T>
__device__ void fc1_body(const float* part2, const float* qemb,
                         const void* W1_, const void* b1_, float* hid,
                         float* feat, float* psum) {
    int tid = threadIdx.x;
    int b = blockIdx.x >> 4, tile = blockIdx.x & 15;
    if (tid < 64) {
        float M = -3.4e38f, L = 0.f, A = 0.f;
        for (int p = 0; p < A2MID; p++) {
            const float* pp = part2 + ((size_t)p * NB + b) * 66;
            float m = pp[0], l = pp[1], a = pp[2 + tid];
            float mn = fmaxf(M, m);
            float e1 = expf(M - mn), e2 = expf(m - mn);
            A = A * e1 + a * e2;
            L = L * e1 + l * e2;
            M = mn;
        }
        feat[tid] = A / L;
        feat[tid + 256] = qemb[b * DH + tid + 192];
    } else {
        feat[tid] = qemb[b * DH + tid - G];
    }
    __syncthreads();
    int lane = tid & 63, phase = tid >> 6;
    int u = tile * 64 + lane;
    const T* W1 = (const T*)W1_;
    float acc = 0.f;
#pragma unroll 8
    for (int kk = 0; kk < 80; kk++) {
        int k = phase * 80 + kk;
        acc += feat[k] * ld(W1, (size_t)k * 1024 + u);
    }
    psum[tid] = acc;
    __syncthreads();
    if (phase == 0) {
        float tot = psum[lane] + psum[64 + lane] + psum[128 + lane] + psum[192 + lane]
                  + ld((const T*)b1_, (size_t)u);
        hid[b * 1024 + u] = relu(tot);
    }
}
__global__ __launch_bounds__(256) void k_fc1(const int* flag, const float* part2,
                                             const float* qemb, const void* W1, const void* b1,
                                             float* hid) {
    __shared__ float feat[320];
    __shared__ float psum[256];
    if (*flag) fc1_body<bf16>(part2, qemb, W1, b1, hid, feat, psum);
    else       fc1_body<float>(part2, qemb, W1, b1, hid, feat, psum);
}

// ---------------- classifier: fc2, parallel k-reduction ----------------
template <typename T>
__device__ void fc2_body(const float* hid, const void* W2_, const void* b2_, void* out_,
                         float* hs, float* psum) {
    int tid = threadIdx.x;
    int b = blockIdx.x >> 5, tile = blockIdx.x & 31;
#pragma unroll
    for (int i = 0; i < 4; i++) hs[tid + 256 * i] = hid[b * 1024 + tid + 256 * i];
    __syncthreads();
    int lane = tid & 63, phase = tid >> 6;
    int c = tile * 64 + lane;
    bool ok = (c < NCLS);
    const T* W2 = (const T*)W2_;
    float acc = 0.f;
    if (ok) {
#pragma unroll 8
        for (int uu = 0; uu < 256; uu++) {
            int u = phase * 256 + uu;
            acc += hs[u] * ld(W2, (size_t)u * NCLS + c);
        }
    }
    psum[tid] = acc;
    __syncthreads();
    if (phase == 0 && ok) {
        float tot = psum[lane] + psum[64 + lane] + psum[128 + lane] + psum[192 + lane]
                  + ld((const T*)b2_, (size_t)c);
        st((T*)out_, (size_t)b * NCLS + c, tot);
    }
}
__global__ __launch_bounds__(256) void k_fc2(const int* flag, const float* hid,
                                             const void* W2, const void* b2v, void* out) {
    __shared__ float hs[1024];
    __shared__ float psum[256];
    if (*flag) fc2_body<bf16>(hid, W2, b2v, out, hs, psum);
    else       fc2_body<float>(hid, W2, b2v, out, hs, psum);
}

extern "C" void kernel_launch(void* const* d_in, const int* in_sizes, int n_in,
                              void* d_out, int out_size, void* d_ws, size_t ws_size,
                              hipStream_t stream) {
    const int* questions  = (const int*)d_in[0];
    const int* node_descs = (const int*)d_in[1];
    const int* edge_src   = (const int*)d_in[2];
    const int* edge_dst   = (const int*)d_in[3];
    const int* edge_type  = (const int*)d_in[4];
    const void* emb_word  = d_in[5];
    const void* emb_desc  = d_in[6];
    const void* Wx_f = d_in[7];
    const void* Wh_f = d_in[8];
    const void* bx_f = d_in[9];
    const void* bh_f = d_in[10];
    const void* Wx_b = d_in[11];
    const void* Wh_b = d_in[12];
    const void* bx_b = d_in[13];
    const void* bh_b = d_in[14];
    const void* W_hg = d_in[15];
    const void* b_hg = d_in[16];
    const void* bases = d_in[17];
    const void* w_comp = d_in[18];
    const void* rgcn_bias = d_in[19];
    const void* W1 = d_in[20];
    const void* b1 = d_in[21];
    const void* W2 = d_in[22];
    const void* b2 = d_in[23];

    float* ws = (float*)d_ws;
    int*      flag  = (int*)(ws + OFF_FLAG);
    float*    gx    = ws + OFF_GX;
    float*    whf   = ws + OFF_WHF;
    float*    qemb  = ws + OFF_QEMB;
    float*    qg    = ws + OFF_QG;
    float*    nf    = ws + OFF_NF;
    bf16*     nf16  = (bf16*)(ws + OFF_NF);
    bf16*     hb16  = (bf16*)(ws + OFF_HB);
    float*    part  = ws + OFF_PART;
    float*    part2 = ws + OFF_PART2;
    int*      deg   = (int*)(ws + OFF_DEG);
    int*      offs  = (int*)(ws + OFF_OFFS);
    int*      cur   = (int*)(ws + OFF_CUR);
    int*      ssrc  = (int*)(ws + OFF_SSRC);
    float*    sco   = ws + OFF_SCO;
    float*    hid   = ws + OFF_HID;

    hipLaunchKernelGGL(k_init, dim3(80), dim3(256), 0, stream,
                       (const unsigned*)emb_word, flag, deg);
    hipLaunchKernelGGL(k_prep, dim3(NBLK_CVT + NBLK_GX2 + NBLK_HIST), dim3(256), 0, stream,
                       flag, Wh_f, Wh_b, whf,
                       questions, emb_word, Wx_f, bx_f, Wx_b, bx_b, gx,
                       edge_dst, deg);
    hipLaunchKernelGGL(k_gru, dim3(8), dim3(2 * G3), 0, stream,
                       flag, questions, gx, whf, bh_f, bh_b, qemb);
    hipLaunchKernelGGL(k_scan_qg, dim3(2), dim3(1024), 0, stream,
                       flag, deg, offs, cur, qemb, W_hg, b_hg, qg);
    hipLaunchKernelGGL(k_scatter, dim3((NEDGES + 255) / 256), dim3(256), 0, stream,
                       flag, edge_src, edge_dst, edge_type, w_comp, cur, ssrc, sco);
    hipLaunchKernelGGL(k_attn1, dim3(NNODES / 4), dim3(256), 0, stream,
                       flag, node_descs, emb_desc, qg, nf16);
    hipLaunchKernelGGL(k_hbg, dim3(NB * NNODES / 64), dim3(256), 0, stream,
                       flag, nf16, bases, hb16);
    hipLaunchKernelGGL(k_agg, dim3(NNODES), dim3(256), 0, stream,
                       flag, hb16, offs, ssrc, sco, rgcn_bias, nf);
    hipLaunchKernelGGL(k_attn2, dim3(A2BLK), dim3(256), 0, stream, nf, qg, part);
    hipLaunchKernelGGL(k_attn2m, dim3(A2MID), dim3(256), 0, stream, part, part2);
    hipLaunchKernelGGL(k_fc1, dim3(NB * 16), dim3(256), 0, stream,
                       flag, part2, qemb, W1, b1, hid);
    hipLaunchKernelGGL(k_fc2, dim3(NB * 32), dim3(256), 0, stream,
                       flag, hid, W2, b2, d_out);
}

// Round 12
// 322.181 us; speedup vs baseline: 2.2689x; 1.0391x over previous
//
#include <hip/hip_runtime.h>
#include <hip/hip_bf16.h>
#include <math.h>

typedef __hip_bfloat16 bf16;

#define NNODES 20000
#define NEDGES 320000
#define DLEN   16
#define G      64
#define DW     300
#define DH     256
#define HD     128
#define G3     384
#define NCLS   2000
#define NB     4
#define TT     32
#define A2BLK  1024  // attn2 partial blocks
#define A2MID  64    // stage-1 merge outputs

#define NBLK_CVT  384
#define NBLK_GX2  1536   // 256 rows (d,b,step) x 6 j-tiles of 64
#define NBLK_HIST ((NEDGES + 255) / 256)
#define NBLK_SCAT ((NEDGES + 255) / 256)

__device__ __forceinline__ float ld(const float* p, size_t i) { return p[i]; }
__device__ __forceinline__ float ld(const bf16* p, size_t i) { return __bfloat162float(p[i]); }
__device__ __forceinline__ void st(float* p, size_t i, float v) { p[i] = v; }
__device__ __forceinline__ void st(bf16* p, size_t i, float v) { p[i] = __float2bfloat16(v); }
__device__ __forceinline__ float relu(float x) { return (x < 0.f) ? 0.f : x; }

struct __align__(8) bf4 { bf16 x, y, z, w; };

// ---------------- workspace layout (float words) ----------------
#define OFF_FLAG  ((size_t)0)                         // 4
#define OFF_GX    (OFF_FLAG + 4)                      // 98304
#define OFF_WHF   (OFF_GX   + 2*NB*TT*G3)             // 98304
#define OFF_QEMB  (OFF_WHF  + 2*HD*G3)                // 1024
#define OFF_QG    (OFF_QEMB + NB*DH)                  // 256
#define OFF_NF    (OFF_QG   + NB*G)                   // pre:bf16 / post:fp32
#define OFF_HB    (OFF_NF   + (size_t)NB*NNODES*G)    // bf16 [n][b][g]
#define OFF_PART  (OFF_HB   + (size_t)NB*NNODES*G)    // 1024*4*66
#define OFF_PART2 (OFF_PART + (size_t)A2BLK*NB*66)    // 64*4*66
#define OFF_DEG   (OFF_PART2+ (size_t)A2MID*NB*66)    // int 20000
#define OFF_OFFS  (OFF_DEG  + NNODES)                 // int 20008
#define OFF_CUR   (OFF_OFFS + NNODES + 8)             // int 20000
#define OFF_SSRC  (OFF_CUR  + NNODES)                 // int 320000
#define OFF_SCO   (OFF_SSRC + NEDGES)                 // float 320000
#define OFF_HID   (OFF_SCO  + NEDGES)                 // 4096

// ---------------- init: dtype sniff + zero deg ----------------
__global__ void k_init(const unsigned* probe, int* flag, int* deg) {
    int i = blockIdx.x * 256 + threadIdx.x;
    if (i < NNODES) deg[i] = 0;
    if (blockIdx.x == 0 && threadIdx.x < 64) {
        int cnt = 0;
        for (int k = threadIdx.x; k < 4096; k += 64) {
            unsigned lo = probe[k] & 0xFFFFu;
            unsigned e = (lo >> 7) & 0xFFu;
            cnt += (e >= 0x66u && e <= 0x7Eu) ? 1 : 0;
        }
#pragma unroll
        for (int off = 1; off < 64; off <<= 1) cnt += __shfl_xor(cnt, off, 64);
        if (threadIdx.x == 0) *flag = (2 * cnt > 4096) ? 1 : 0;   // 1 = bf16
    }
}

// ---------------- fused prep: cvt | gx (K-split) | hist --------------------
template <typename T>
__device__ void cvt_body(int id, const void* Whf_, const void* Whb_, float* whf) {
    if (id >= 2 * HD * G3) return;
    int d = id / (HD * G3), r = id % (HD * G3);
    const T* W = (const T*)(d ? Whb_ : Whf_);
    whf[id] = ld(W, (size_t)r);
}

template <typename T>
__device__ void gx2_body(int bx2, const int* questions, const void* emb_word_,
                         const void* Wxf_, const void* bxf_,
                         const void* Wxb_, const void* bxb_, float* gx,
                         float* xs, float* psum) {
    int tid = threadIdx.x;
    int jt = bx2 % 6;
    int rid = bx2 / 6;                  // 0..255
    int step = rid & 31;
    int b = (rid >> 5) & 3;
    int d = rid >> 7;
    int t = d ? (TT - 1 - step) : step;
    int tok = questions[b * TT + t];
    const T* row = (const T*)emb_word_ + (size_t)tok * DW;
    for (int k = tid; k < DW; k += 256) xs[k] = ld(row, (size_t)k);
    __syncthreads();
    int lane = tid & 63, phase = tid >> 6;
    int j = jt * 64 + lane;
    const T* Wx = (const T*)(d ? Wxb_ : Wxf_);
    float acc = 0.f;
    int k0 = phase * 75;
#pragma unroll 15
    for (int kk = 0; kk < 75; kk++) {
        int k = k0 + kk;
        acc += xs[k] * ld(Wx, (size_t)k * G3 + j);
    }
    psum[tid] = acc;
    __syncthreads();
    if (phase == 0) {
        const T* bx = (const T*)(d ? bxb_ : bxf_);
        float tot = ld(bx, (size_t)j)
                  + psum[lane] + psum[64 + lane] + psum[128 + lane] + psum[192 + lane];
        gx[(size_t)rid * G3 + j] = tot;
    }
}

__global__ void k_prep(const int* flag, const void* Whf, const void* Whb, float* whf,
                       const int* questions, const void* emb_word,
                       const void* Wxf, const void* bxf,
                       const void* Wxb, const void* bxb, float* gx,
                       const int* edge_dst, int* deg) {
    __shared__ float xs[DW];
    __shared__ float psum[256];
    int bx = blockIdx.x;
    int tid = threadIdx.x;
    if (bx < NBLK_CVT) {
        int id = bx * 256 + tid;
        if (*flag) cvt_body<bf16>(id, Whf, Whb, whf);
        else       cvt_body<float>(id, Whf, Whb, whf);
    } else if (bx < NBLK_CVT + NBLK_GX2) {
        int bx2 = bx - NBLK_CVT;
        if (*flag) gx2_body<bf16>(bx2, questions, emb_word, Wxf, bxf, Wxb, bxb, gx, xs, psum);
        else       gx2_body<float>(bx2, questions, emb_word, Wxf, bxf, Wxb, bxb, gx, xs, psum);
    } else {
        int e = (bx - NBLK_CVT - NBLK_GX2) * 256 + tid;
        if (e < NEDGES) atomicAdd(&deg[edge_dst[e]], 1);
    }
}

// ---------------- GRU scan (blocks 0..7) + CSR scan (block 8) --------------
template <typename T>
__device__ void gru_body(const int* questions, const float* gx, const float* whf,
                         const void* bhf_, const void* bhb_, float* qemb,
                         float* hsm, float* ghs) {
    int tid = threadIdx.x;
    int d = blockIdx.x >> 2, b = blockIdx.x & 3;
    int half = tid / G3, j = tid - half * G3;
    const float* wh = whf + (size_t)d * HD * G3 + (size_t)half * 64 * G3 + j;
    float w[64];
#pragma unroll
    for (int m = 0; m < 64; m++) w[m] = wh[(size_t)m * G3];
    const T* bh = (const T*)(d ? bhb_ : bhf_);
    float bhj = (half == 0) ? ld(bh, (size_t)j) : 0.f;
    if (tid < HD) hsm[tid] = 0.f;
    const float* gxb = gx + ((size_t)(d * NB + b)) * TT * G3;
    __syncthreads();
    const float4* h4 = (const float4*)(hsm + half * 64);
    for (int step = 0; step < TT; step++) {
        float acc = bhj;
#pragma unroll
        for (int m4 = 0; m4 < 16; m4++) {
            float4 hp = h4[m4];
            acc = fmaf(hp.x, w[4 * m4 + 0], acc);
            acc = fmaf(hp.y, w[4 * m4 + 1], acc);
            acc = fmaf(hp.z, w[4 * m4 + 2], acc);
            acc = fmaf(hp.w, w[4 * m4 + 3], acc);
        }
        ghs[half * G3 + j] = acc;
        __syncthreads();
        if (tid < HD) {
            const float* gxp = gxb + step * G3;
            int t = d ? (TT - 1 - step) : step;
            bool msk = questions[b * TT + t] != 0;
            float gr = ghs[tid] + ghs[G3 + tid];
            float gz = ghs[HD + tid] + ghs[G3 + HD + tid];
            float gn = ghs[2 * HD + tid] + ghs[G3 + 2 * HD + tid];
            float r = 1.f / (1.f + expf(-(gxp[tid] + gr)));
            float z = 1.f / (1.f + expf(-(gxp[HD + tid] + gz)));
            float n = tanhf(gxp[2 * HD + tid] + r * gn);
            float hn = (1.f - z) * n + z * hsm[tid];
            if (msk) hsm[tid] = hn;
        }
        __syncthreads();
    }
    if (tid < HD) qemb[b * DH + d * HD + tid] = hsm[tid];
}

// exclusive int scan of deg with 768 threads x 27 elems (exact)
__device__ void scan_body(const int* deg, int* offs, int* cur, int* wtot) {
    int t = threadIdx.x;                 // 0..767
    int lane = t & 63, wave = t >> 6;    // 12 waves
    int c[27];
    int base = t * 27;
    int run = 0;
#pragma unroll
    for (int i = 0; i < 27; i++) {
        int v = (base + i < NNODES) ? deg[base + i] : 0;
        c[i] = run;
        run += v;
    }
    int myrun = run, inc = run;
#pragma unroll
    for (int off = 1; off < 64; off <<= 1) {
        int u = __shfl_up(inc, off, 64);
        if (lane >= off) inc += u;
    }
    if (lane == 63) wtot[wave] = inc;
    __syncthreads();
    if (t == 0) {
        int s = 0;
#pragma unroll
        for (int i = 0; i < 12; i++) { int v = wtot[i]; wtot[i] = s; s += v; }
        offs[NNODES] = s;
    }
    __syncthreads();
    int ebase = wtot[wave] + inc - myrun;
#pragma unroll
    for (int i = 0; i < 27; i++) {
        if (base + i < NNODES) {
            offs[base + i] = ebase + c[i];
            cur[base + i] = ebase + c[i];
        }
    }
}

__global__ __launch_bounds__(2 * G3) void k_gru(const int* flag, const int* questions,
                                                const float* gx, const float* whf,
                                                const void* bhf, const void* bhb, float* qemb,
                                                const int* deg, int* offs, int* cur) {
    __shared__ __align__(16) float hsm[HD];
    __shared__ float ghs[2 * G3];
    __shared__ int wtot[12];
    if (blockIdx.x < 8) {
        if (*flag) gru_body<bf16>(questions, gx, whf, bhf, bhb, qemb, hsm, ghs);
        else       gru_body<float>(questions, gx, whf, bhf, bhb, qemb, hsm, ghs);
    } else {
        scan_body(deg, offs, cur, wtot);
    }
}

// ---------------- q_g = q_emb @ W_hg + b_hg (1 block) ----------------
template <typename T>
__device__ void qg_body(const float* qemb, const void* W_hg_, const void* b_hg_, float* qg) {
    int tid = threadIdx.x;
    int b = tid >> 6, g = tid & 63;
    const T* W = (const T*)W_hg_;
    float acc = ld((const T*)b_hg_, (size_t)g);
#pragma unroll 4
    for (int i = 0; i < DH; i++) acc += qemb[b * DH + i] * ld(W, (size_t)i * G + g);
    qg[b * G + g] = acc;
}
__global__ void k_qg(const int* flag, const float* qemb, const void* W_hg,
                     const void* b_hg, float* qg) {
    if (*flag) qg_body<bf16>(qemb, W_hg, b_hg, qg);
    else       qg_body<float>(qemb, W_hg, b_hg, qg);
}

// ---------------- fused: scatter (blocks 0..1249) | attn1 (rest) -----------
template <typename T>
__device__ void scatter_body(int e, const int* src, const int* dst, const int* typ,
                             const void* w_comp_, int* cur, int* ssrc, float* sco) {
    if (e < NEDGES) {
        int dd = dst[e];
        int pos = atomicAdd(&cur[dd], 1);
        ssrc[pos] = src[e];
        sco[pos] = ld((const T*)w_comp_, (size_t)typ[e]);
    }
}

template <typename T>
__device__ void attn1_body(int nb4, const int* node_descs, const void* emb_desc_,
                           const float* qg, bf16* nf16,
                           float* dsm, float* attn_s, float* qgs) {
    int tid = threadIdx.x;
    if (tid < NB * G) qgs[tid] = qg[tid];
    __syncthreads();
    const T* emb_desc = (const T*)emb_desc_;
    int w = tid >> 6, lane = tid & 63;
    int n = nb4 * 4 + w;
    float dreg[DLEN];
    const int* nd = node_descs + n * DLEN;
    float* dw = dsm + (size_t)w * DLEN * 68;
#pragma unroll
    for (int l = 0; l < DLEN; l++) {
        int idx = nd[l];
        float v = ld(emb_desc, (size_t)idx * G + lane);
        dreg[l] = v;
        dw[l * 68 + lane] = v;
    }
    int lb = lane >> 4, ll = lane & 15;
    float acc = 0.f;
#pragma unroll
    for (int i = 0; i < 16; i++) {
        float4 a = *(const float4*)&dw[ll * 68 + 4 * i];
        float4 q = *(const float4*)&qgs[lb * G + 4 * i];
        acc = fmaf(a.x, q.x, acc);
        acc = fmaf(a.y, q.y, acc);
        acc = fmaf(a.z, q.z, acc);
        acc = fmaf(a.w, q.w, acc);
    }
    float mx = acc;
#pragma unroll
    for (int off = 1; off < 16; off <<= 1) mx = fmaxf(mx, __shfl_xor(mx, off, 64));
    float e = expf(acc - mx);
    float s = e;
#pragma unroll
    for (int off = 1; off < 16; off <<= 1) s += __shfl_xor(s, off, 64);
    attn_s[w * 64 + lane] = e / s;
#pragma unroll
    for (int b = 0; b < NB; b++) {
        float a = 0.f;
#pragma unroll
        for (int l = 0; l < DLEN; l++) a += attn_s[w * 64 + b * 16 + l] * dreg[l];
        nf16[((size_t)b * NNODES + n) * G + lane] = __float2bfloat16(a);
    }
}

__global__ __launch_bounds__(256) void k_sc_attn1(const int* flag,
                                                  const int* src, const int* dst, const int* typ,
                                                  const void* w_comp, int* cur,
                                                  int* ssrc, float* sco,
                                                  const int* node_descs, const void* emb_desc,
                                                  const float* qg, bf16* nf16) {
    __shared__ __align__(16) float dsm[4 * DLEN * 68];
    __shared__ float attn_s[4 * 64];
    __shared__ __align__(16) float qgs[NB * G];
    int bx = blockIdx.x;
    if (bx < NBLK_SCAT) {
        int e = bx * 256 + threadIdx.x;
        if (*flag) scatter_body<bf16>(e, src, dst, typ, w_comp, cur, ssrc, sco);
        else       scatter_body<float>(e, src, dst, typ, w_comp, cur, ssrc, sco);
    } else {
        int nb4 = bx - NBLK_SCAT;
        if (*flag) attn1_body<bf16>(nb4, node_descs, emb_desc, qg, nf16, dsm, attn_s, qgs);
        else       attn1_body<float>(nb4, node_descs, emb_desc, qg, nf16, dsm, attn_s, qgs);
    }
}

// ---------------- hb = nf16 @ bases[0] : tiled register GEMM, bf16 out -----
template <typename T>
__device__ void hbg_body(const bf16* nf16, const void* bases_, bf16* hb16,
                         float* as, float* bs) {
    int tid = threadIdx.x;
    const T* bases = (const T*)bases_;
    for (int i = tid; i < G * G; i += 256) bs[(i >> 6) * 68 + (i & 63)] = ld(bases, (size_t)i);
    size_t r0 = (size_t)blockIdx.x * 64;
    const bf4* gA = (const bf4*)(nf16 + r0 * G);
#pragma unroll
    for (int i = 0; i < 4; i++) {
        int c = tid + i * 256;
        int row = c >> 4, col4 = c & 15;
        bf4 v = gA[c];
        float4 f;
        f.x = __bfloat162float(v.x);
        f.y = __bfloat162float(v.y);
        f.z = __bfloat162float(v.z);
        f.w = __bfloat162float(v.w);
        *(float4*)&as[row * 68 + col4 * 4] = f;
    }
    __syncthreads();
    int tx = tid & 15, ty = tid >> 4;
    float acc[4][4];
#pragma unroll
    for (int i = 0; i < 4; i++)
#pragma unroll
        for (int j = 0; j < 4; j++) acc[i][j] = 0.f;
#pragma unroll 4
    for (int g4 = 0; g4 < 16; g4++) {
        float4 b0 = *(const float4*)&bs[(4 * g4 + 0) * 68 + tx * 4];
        float4 b1 = *(const float4*)&bs[(4 * g4 + 1) * 68 + tx * 4];
        float4 b2 = *(const float4*)&bs[(4 * g4 + 2) * 68 + tx * 4];
        float4 b3 = *(const float4*)&bs[(4 * g4 + 3) * 68 + tx * 4];
#pragma unroll
        for (int i = 0; i < 4; i++) {
            float4 a = *(const float4*)&as[(ty * 4 + i) * 68 + g4 * 4];
            acc[i][0] = fmaf(a.x, b0.x, acc[i][0]);
            acc[i][0] = fmaf(a.y, b1.x, acc[i][0]);
            acc[i][0] = fmaf(a.z, b2.x, acc[i][0]);
            acc[i][0] = fmaf(a.w, b3.x, acc[i][0]);
            acc[i][1] = fmaf(a.x, b0.y, acc[i][1]);
            acc[i][1] = fmaf(a.y, b1.y, acc[i][1]);
            acc[i][1] = fmaf(a.z, b2.y, acc[i][1]);
            acc[i][1] = fmaf(a.w, b3.y, acc[i][1]);
            acc[i][2] = fmaf(a.x, b0.z, acc[i][2]);
            acc[i][2] = fmaf(a.y, b1.z, acc[i][2]);
            acc[i][2] = fmaf(a.z, b2.z, acc[i][2]);
            acc[i][2] = fmaf(a.w, b3.z, acc[i][2]);
            acc[i][3] = fmaf(a.x, b0.w, acc[i][3]);
            acc[i][3] = fmaf(a.y, b1.w, acc[i][3]);
            acc[i][3] = fmaf(a.z, b2.w, acc[i][3]);
            acc[i][3] = fmaf(a.w, b3.w, acc[i][3]);
        }
    }
#pragma unroll
    for (int i = 0; i < 4; i++) {
        size_t r = r0 + ty * 4 + i;
        int b = (int)(r / NNODES);
        int n = (int)(r - (size_t)b * NNODES);
        bf4 o;
        o.x = __float2bfloat16(acc[i][0]);
        o.y = __float2bfloat16(acc[i][1]);
        o.z = __float2bfloat16(acc[i][2]);
        o.w = __float2bfloat16(acc[i][3]);
        *(bf4*)&hb16[((size_t)n * NB + b) * G + tx * 4] = o;
    }
}
__global__ __launch_bounds__(256) void k_hbg(const int* flag, const bf16* nf16,
                                             const void* bases, bf16* hb16) {
    __shared__ __align__(16) float as[64 * 68];
    __shared__ __align__(16) float bs[64 * 68];
    if (*flag) hbg_body<bf16>(nf16, bases, hb16, as, bs);
    else       hbg_body<float>(nf16, bases, hb16, as, bs);
}

// ---------------- RGCN aggregate: 16/8/4/1 unroll cascade ------------------
template <typename T>
__device__ void agg_body(const bf16* hb16, const int* offs, const int* ssrc,
                         const float* sco, const void* bias_, float* out_nf) {
    int tid = threadIdx.x;
    int b = tid >> 6, g = tid & 63;
    int dn = blockIdx.x;
    int s0 = offs[dn], s1 = offs[dn + 1];
    int boff = b * G + g;
    float acc = 0.f;
    int p = s0;
    for (; p + 15 < s1; p += 16) {
        int ix[16]; float co[16]; float x[16];
#pragma unroll
        for (int k = 0; k < 16; k++) { ix[k] = ssrc[p + k]; co[k] = sco[p + k]; }
#pragma unroll
        for (int k = 0; k < 16; k++) x[k] = __bfloat162float(hb16[(size_t)ix[k] * (NB * G) + boff]);
#pragma unroll
        for (int k = 0; k < 16; k++) acc += co[k] * x[k];
    }
    for (; p + 7 < s1; p += 8) {
        int ix[8]; float co[8]; float x[8];
#pragma unroll
        for (int k = 0; k < 8; k++) { ix[k] = ssrc[p + k]; co[k] = sco[p + k]; }
#pragma unroll
        for (int k = 0; k < 8; k++) x[k] = __bfloat162float(hb16[(size_t)ix[k] * (NB * G) + boff]);
#pragma unroll
        for (int k = 0; k < 8; k++) acc += co[k] * x[k];
    }
    for (; p + 3 < s1; p += 4) {
        int ix[4]; float co[4]; float x[4];
#pragma unroll
        for (int k = 0; k < 4; k++) { ix[k] = ssrc[p + k]; co[k] = sco[p + k]; }
#pragma unroll
        for (int k = 0; k < 4; k++) x[k] = __bfloat162float(hb16[(size_t)ix[k] * (NB * G) + boff]);
#pragma unroll
        for (int k = 0; k < 4; k++) acc += co[k] * x[k];
    }
    for (; p < s1; p++)
        acc += sco[p] * __bfloat162float(hb16[(size_t)ssrc[p] * (NB * G) + boff]);
    out_nf[((size_t)b * NNODES + dn) * G + g] = relu(acc + ld((const T*)bias_, (size_t)g));
}
__global__ __launch_bounds__(256) void k_agg(const int* flag, const bf16* hb16, const int* offs,
                                             const int* ssrc, const float* sco,
                                             const void* bias, float* out_nf) {
    if (*flag) agg_body<bf16>(hb16, offs, ssrc, sco, bias, out_nf);
    else       agg_body<float>(hb16, offs, ssrc, sco, bias, out_nf);
}

// ---------------- attn2: single-pass online softmax, NO atomics ------------
__device__ __forceinline__ void a2_update(float& M, float& L, float& A, float p, float v) {
    if (p > M) {
        float s = expf(M - p);
        A *= s; L *= s; M = p;
    }
    float e = expf(p - M);
    L += e;
    A = fmaf(e, v, A);
}

__global__ __launch_bounds__(256) void k_attn2(const float* rg, const float* qg, float* part) {
    int tid = threadIdx.x;
    int b = tid >> 6, lane = tid & 63;
    float q = qg[b * G + lane];
    int chunk = (NNODES + A2BLK - 1) / A2BLK;
    int n0 = blockIdx.x * chunk;
    int n1 = min(n0 + chunk, NNODES);
    const float* base = rg + (size_t)b * NNODES * G + lane;
    float M = -3.4e38f, L = 0.f, A = 0.f;
    int n = n0;
    for (; n + 3 < n1; n += 4) {
        float v0 = base[(size_t)(n + 0) * G];
        float v1 = base[(size_t)(n + 1) * G];
        float v2 = base[(size_t)(n + 2) * G];
        float v3 = base[(size_t)(n + 3) * G];
        float p0 = v0 * q, p1 = v1 * q, p2 = v2 * q, p3 = v3 * q;
#pragma unroll
        for (int off = 32; off >= 1; off >>= 1) {
            p0 += __shfl_xor(p0, off, 64);
            p1 += __shfl_xor(p1, off, 64);
            p2 += __shfl_xor(p2, off, 64);
            p3 += __shfl_xor(p3, off, 64);
        }
        a2_update(M, L, A, p0, v0);
        a2_update(M, L, A, p1, v1);
        a2_update(M, L, A, p2, v2);
        a2_update(M, L, A, p3, v3);
    }
    for (; n < n1; n++) {
        float v = base[(size_t)n * G];
        float p = v * q;
#pragma unroll
        for (int off = 32; off >= 1; off >>= 1) p += __shfl_xor(p, off, 64);
        a2_update(M, L, A, p, v);
    }
    float* pp = part + ((size_t)blockIdx.x * NB + b) * 66;
    if (lane == 0) { pp[0] = M; pp[1] = L; }
    pp[2 + lane] = A;
}

// stage-1 merge: A2BLK -> A2MID partials
__global__ void k_attn2m(const float* part, float* part2) {
    int tid = threadIdx.x;
    int b = tid >> 6, lane = tid & 63;
    int grp = blockIdx.x;
    float M = -3.4e38f, L = 0.f, A = 0.f;
    for (int i = 0; i < A2BLK / A2MID; i++) {
        const float* pp = part + ((size_t)(grp * (A2BLK / A2MID) + i) * NB + b) * 66;
        float m = pp[0], l = pp[1], a = pp[2 + lane];
        float mn = fmaxf(M, m);
        float e1 = expf(M - mn), e2 = expf(m - mn);
        A = A * e1 + a * e2;
        L = L * e1 + l * e2;
        M = mn;
    }
    float* pq = part2 + ((size_t)grp * NB + b) * 66;
    if (lane == 0) { pq[0] = M; pq[1] = L; }
    pq[2 + lane] = A;
}

// ---------------- fc1 with inline final attn2 merge ----------------
template <typename T>
__device__ void fc1_body(const float* part2, const float* qemb,
                         const void* W1_, const void* b1_, float* hid,
                         float* feat, float* psum) {
    int tid = threadIdx.x;
    int b = blockIdx.x >> 4, tile = blockIdx.x & 15;
    if (tid < 64) {
        float M = -3.4e38f, L = 0.f, A = 0.f;
        for (int p = 0; p < A2MID; p++) {
            const float* pp = part2 + ((size_t)p * NB + b) * 66;
            float m = pp[0], l = pp[1], a = pp[2 + tid];
            float mn = fmaxf(M, m);
            float e1 = expf(M - mn), e2 = expf(m - mn);
            A = A * e1 + a * e2;
            L = L * e1 + l * e2;
            M = mn;
        }
        feat[tid] = A / L;
        feat[tid + 256] = qemb[b * DH + tid + 192];
    } else {
        feat[tid] = qemb[b * DH + tid - G];
    }
    __syncthreads();
    int lane = tid & 63, phase = tid >> 6;
    int u = tile * 64 + lane;
    const T* W1 = (const T*)W1_;
    float acc = 0.f;
#pragma unroll 8
    for (int kk = 0; kk < 80; kk++) {
        int k = phase * 80 + kk;
        acc += feat[k] * ld(W1, (size_t)k * 1024 + u);
    }
    psum[tid] = acc;
    __syncthreads();
    if (phase == 0) {
        float tot = psum[lane] + psum[64 + lane] + psum[128 + lane] + psum[192 + lane]
                  + ld((const T*)b1_, (size_t)u);
        hid[b * 1024 + u] = relu(tot);
    }
}
__global__ __launch_bounds__(256) void k_fc1(const int* flag, const float* part2,
                                             const float* qemb, const void* W1, const void* b1,
                                             float* hid) {
    __shared__ float feat[320];
    __shared__ float psum[256];
    if (*flag) fc1_body<bf16>(part2, qemb, W1, b1, hid, feat, psum);
    else       fc1_body<float>(part2, qemb, W1, b1, hid, feat, psum);
}

// ---------------- classifier: fc2, parallel k-reduction ----------------
template <typename T>
__device__ void fc2_body(const float* hid, const void* W2_, const void* b2_, void* out_,
                         float* hs, float* psum) {
    int tid = threadIdx.x;
    int b = blockIdx.x >> 5, tile = blockIdx.x & 31;
#pragma unroll
    for (int i = 0; i < 4; i++) hs[tid + 256 * i] = hid[b * 1024 + tid + 256 * i];
    __syncthreads();
    int lane = tid & 63, phase = tid >> 6;
    int c = tile * 64 + lane;
    bool ok = (c < NCLS);
    const T* W2 = (const T*)W2_;
    float acc = 0.f;
    if (ok) {
#pragma unroll 8
        for (int uu = 0; uu < 256; uu++) {
            int u = phase * 256 + uu;
            acc += hs[u] * ld(W2, (size_t)u * NCLS + c);
        }
    }
    psum[tid] = acc;
    __syncthreads();
    if (phase == 0 && ok) {
        float tot = psum[lane] + psum[64 + lane] + psum[128 + lane] + psum[192 + lane]
                  + ld((const T*)b2_, (size_t)c);
        st((T*)out_, (size_t)b * NCLS + c, tot);
    }
}
__global__ __launch_bounds__(256) void k_fc2(const int* flag, const float* hid,
                                             const void* W2, const void* b2v, void* out) {
    __shared__ float hs[1024];
    __shared__ float psum[256];
    if (*flag) fc2_body<bf16>(hid, W2, b2v, out, hs, psum);
    else       fc2_body<float>(hid, W2, b2v, out, hs, psum);
}

extern "C" void kernel_launch(void* const* d_in, const int* in_sizes, int n_in,
                              void* d_out, int out_size, void* d_ws, size_t ws_size,
                              hipStream_t stream) {
    const int* questions  = (const int*)d_in[0];
    const int* node_descs = (const int*)d_in[1];
    const int* edge_src   = (const int*)d_in[2];
    const int* edge_dst   = (const int*)d_in[3];
    const int* edge_type  = (const int*)d_in[4];
    const void* emb_word  = d_in[5];
    const void* emb_desc  = d_in[6];
    const void* Wx_f = d_in[7];
    const void* Wh_f = d_in[8];
    const void* bx_f = d_in[9];
    const void* bh_f = d_in[10];
    const void* Wx_b = d_in[11];
    const void* Wh_b = d_in[12];
    const void* bx_b = d_in[13];
    const void* bh_b = d_in[14];
    const void* W_hg = d_in[15];
    const void* b_hg = d_in[16];
    const void* bases = d_in[17];
    const void* w_comp = d_in[18];
    const void* rgcn_bias = d_in[19];
    const void* W1 = d_in[20];
    const void* b1 = d_in[21];
    const void* W2 = d_in[22];
    const void* b2 = d_in[23];

    float* ws = (float*)d_ws;
    int*      flag  = (int*)(ws + OFF_FLAG);
    float*    gx    = ws + OFF_GX;
    float*    whf   = ws + OFF_WHF;
    float*    qemb  = ws + OFF_QEMB;
    float*    qg    = ws + OFF_QG;
    float*    nf    = ws + OFF_NF;
    bf16*     nf16  = (bf16*)(ws + OFF_NF);
    bf16*     hb16  = (bf16*)(ws + OFF_HB);
    float*    part  = ws + OFF_PART;
    float*    part2 = ws + OFF_PART2;
    int*      deg   = (int*)(ws + OFF_DEG);
    int*      offs  = (int*)(ws + OFF_OFFS);
    int*      cur   = (int*)(ws + OFF_CUR);
    int*      ssrc  = (int*)(ws + OFF_SSRC);
    float*    sco   = ws + OFF_SCO;
    float*    hid   = ws + OFF_HID;

    hipLaunchKernelGGL(k_init, dim3(80), dim3(256), 0, stream,
                       (const unsigned*)emb_word, flag, deg);
    hipLaunchKernelGGL(k_prep, dim3(NBLK_CVT + NBLK_GX2 + NBLK_HIST), dim3(256), 0, stream,
                       flag, Wh_f, Wh_b, whf,
                       questions, emb_word, Wx_f, bx_f, Wx_b, bx_b, gx,
                       edge_dst, deg);
    hipLaunchKernelGGL(k_gru, dim3(9), dim3(2 * G3), 0, stream,
                       flag, questions, gx, whf, bh_f, bh_b, qemb, deg, offs, cur);
    hipLaunchKernelGGL(k_qg, dim3(1), dim3(256), 0, stream, flag, qemb, W_hg, b_hg, qg);
    hipLaunchKernelGGL(k_sc_attn1, dim3(NBLK_SCAT + NNODES / 4), dim3(256), 0, stream,
                       flag, edge_src, edge_dst, edge_type, w_comp, cur, ssrc, sco,
                       node_descs, emb_desc, qg, nf16);
    hipLaunchKernelGGL(k_hbg, dim3(NB * NNODES / 64), dim3(256), 0, stream,
                       flag, nf16, bases, hb16);
    hipLaunchKernelGGL(k_agg, dim3(NNODES), dim3(256), 0, stream,
                       flag, hb16, offs, ssrc, sco, rgcn_bias, nf);
    hipLaunchKernelGGL(k_attn2, dim3(A2BLK), dim3(256), 0, stream, nf, qg, part);
    hipLaunchKernelGGL(k_attn2m, dim3(A2MID), dim3(256), 0, stream, part, part2);
    hipLaunchKernelGGL(k_fc1, dim3(NB * 16), dim3(256), 0, stream,
                       flag, part2, qemb, W1, b1, hid);
    hipLaunchKernelGGL(k_fc2, dim3(NB * 32), dim3(256), 0, stream,
                       flag, hid, W2, b2, d_out);
}